// Round 2
// baseline (1685.779 us; speedup 1.0000x reference)
//
#include <hip/hip_runtime.h>
#include <hip/hip_bf16.h>
#include <cstdint>

typedef __hip_bfloat16 bf16;

static __device__ __forceinline__ float b2f(bf16 v) { return __bfloat162float(v); }

// dual-dtype load: f32!=0 -> buffer is float32, else packed bf16
static __device__ __forceinline__ float ldf(const void* p, size_t i, int f32) {
  return f32 ? ((const float*)p)[i] : __bfloat162float(((const bf16*)p)[i]);
}

// ---------------------------------------------------------------------------
// dtype detection: interpret x as u16; exponent==0xFF is impossible for true
// bf16 N(0,1) data but ~0.4% likely per low-half word of fp32 data.
// flag=1 -> inputs are fp32.
// ---------------------------------------------------------------------------
__global__ __launch_bounds__(256) void detect_dtype(const unsigned short* __restrict__ xs,
                                                    int* __restrict__ flag) {
  int i = blockIdx.x * 256 + threadIdx.x;
  unsigned short u = xs[i];
  if (((u >> 7) & 0xFF) == 0xFF) atomicOr(flag, 1);
}

// ---------------------------------------------------------------------------
// conv1x1 GEMM: out[m,o] = sum_k A[b,k,m] * W[o,k] + bias[o];  K=512
// MODE 0: q     -> o0[bh][m][d]                     (M=4096, O=512)
// MODE 1: kv_up -> k/v split into o0/o1[bh][m][d]   (M=1024, O=1024)
// MODE 3: proj  -> out (dual dtype), A is fp32 xsum (M=4096, O=512)
// ---------------------------------------------------------------------------
template<int MODE>
__global__ __launch_bounds__(256) void gemm_conv(
    const void* __restrict__ A, const void* __restrict__ Wt,
    const void* __restrict__ bias, float* __restrict__ o0,
    float* __restrict__ o1, void* __restrict__ ob, int M,
    const int* __restrict__ dtf) {
  const int K = 512;
  const int f32 = *dtf;
  const int b  = blockIdx.z;
  const int mt = blockIdx.x * 64, ot = blockIdx.y * 64;
  const int t  = threadIdx.x;
  __shared__ __align__(16) float As[16][64];
  __shared__ __align__(16) float Ws[16][64];
  float acc[4][4] = {};
  const int tx = t & 15, ty = t >> 4;
  const int mq = (MODE == 3) ? tx : ty;
  const int oq = (MODE == 3) ? ty : tx;

  for (int k0 = 0; k0 < K; k0 += 16) {
    __syncthreads();
#pragma unroll
    for (int j = 0; j < 4; ++j) {
      int i = t + j * 256;
      int kl = i >> 6, ml = i & 63;
      size_t ai = ((size_t)(b * K + k0 + kl)) * M + mt + ml;
      As[kl][ml] = (MODE == 3) ? ((const float*)A)[ai] : ldf(A, ai, f32);
      int ol = i >> 4, kl2 = i & 15;
      Ws[kl2][ol] = ldf(Wt, (size_t)(ot + ol) * K + k0 + kl2, f32);
    }
    __syncthreads();
    const float4* As4 = reinterpret_cast<const float4*>(&As[0][0]);
    const float4* Ws4 = reinterpret_cast<const float4*>(&Ws[0][0]);
#pragma unroll
    for (int kk = 0; kk < 16; ++kk) {
      float4 a4 = As4[kk * 16 + mq];
      float4 w4 = Ws4[kk * 16 + oq];
      float av[4] = {a4.x, a4.y, a4.z, a4.w};
      float wv[4] = {w4.x, w4.y, w4.z, w4.w};
#pragma unroll
      for (int mi = 0; mi < 4; ++mi)
#pragma unroll
        for (int oi = 0; oi < 4; ++oi)
          acc[mi][oi] += av[mi] * wv[oi];
    }
  }
#pragma unroll
  for (int mi = 0; mi < 4; ++mi) {
    int m = mt + mq * 4 + mi;
#pragma unroll
    for (int oi = 0; oi < 4; ++oi) {
      int o = ot + oq * 4 + oi;
      float val = acc[mi][oi] + ldf(bias, o, f32);
      if (MODE == 0) {
        o0[((size_t)(b * 8 + (o >> 6)) * M + m) * 64 + (o & 63)] = val;
      } else if (MODE == 1) {
        int hh = o >> 7, jj = o & 127;
        float* tgt = (jj < 64) ? o0 : o1;
        tgt[((size_t)(b * 8 + hh) * M + m) * 64 + (jj & 63)] = val;
      } else {
        size_t oi_ = ((size_t)(b * 512 + o)) * M + m;
        if (f32) ((float*)ob)[oi_] = val;
        else     ((bf16*)ob)[oi_] = __float2bfloat16(val);
      }
    }
  }
}

// heat[b,mu] = mean over C and 2x2 block of x
__global__ __launch_bounds__(256) void heat_kernel(const void* __restrict__ x,
                                                   float* __restrict__ heat,
                                                   const int* __restrict__ dtf) {
  const int f32 = *dtf;
  int bm = blockIdx.x;
  int b = bm >> 10, mu = bm & 1023;
  int hu = mu >> 5, wu = mu & 31;
  int t = threadIdx.x;
  float s = 0.f;
  for (int c = t; c < 512; c += 256) {
    size_t base = ((size_t)(b * 512 + c) * 64 + hu * 2) * 64 + wu * 2;
    s += ldf(x, base, f32) + ldf(x, base + 1, f32) + ldf(x, base + 64, f32) + ldf(x, base + 65, f32);
  }
  __shared__ float r[256];
  r[t] = s; __syncthreads();
  for (int off = 128; off; off >>= 1) { if (t < off) r[t] += r[t + off]; __syncthreads(); }
  if (t == 0) heat[bm] = r[0] * (1.0f / 2048.0f);
}

// qsum[bh,d] = sum_n q[bh,n,d]
__global__ __launch_bounds__(256) void qsum_kernel(const float* __restrict__ q,
                                                   float* __restrict__ qsum) {
  int bh = blockIdx.x, t = threadIdx.x;
  int d = t & 63, g = t >> 6;
  float s = 0.f;
  for (int n = g * 1024; n < (g + 1) * 1024; ++n)
    s += q[((size_t)bh * 4096 + n) * 64 + d];
  __shared__ float r[256];
  r[t] = s; __syncthreads();
  if (t < 64) qsum[bh * 64 + t] = r[t] + r[t + 64] + r[t + 128] + r[t + 192];
}

// scores -> top-16 coarse cells -> 64 full-res positions into posb
__global__ __launch_bounds__(256) void topk_kernel(
    const float* __restrict__ qsum, const float* __restrict__ k,
    const float* __restrict__ heat, const void* __restrict__ gumbel,
    int* __restrict__ posb, const int* __restrict__ dtf) {
  const int f32 = *dtf;
  int bh = blockIdx.x, b = bh >> 3, t = threadIdx.x;
  __shared__ float qs[64];
  __shared__ float s[1024];
  __shared__ float rv[256];
  __shared__ int   ri[256];
  if (t < 64) qs[t] = qsum[bh * 64 + t];
  __syncthreads();
  for (int j = 0; j < 4; ++j) {
    int m = t + j * 256;
    const float* kr = k + ((size_t)bh * 1024 + m) * 64;
    float dot = 0.f;
    for (int d = 0; d < 64; ++d) dot += qs[d] * kr[d];
    s[m] = dot * (0.125f / 4096.0f) * heat[b * 1024 + m] + ldf(gumbel, (size_t)bh * 1024 + m, f32);
  }
  __syncthreads();
  for (int it = 0; it < 16; ++it) {
    float bv = -1e30f; int bi = 0x7fffffff;
    for (int j = 0; j < 4; ++j) {
      int m = t + j * 256; float vv = s[m];
      if (vv > bv || (vv == bv && m < bi)) { bv = vv; bi = m; }
    }
    rv[t] = bv; ri[t] = bi; __syncthreads();
    for (int off = 128; off; off >>= 1) {
      if (t < off) {
        if (rv[t + off] > rv[t] || (rv[t + off] == rv[t] && ri[t + off] < ri[t])) {
          rv[t] = rv[t + off]; ri[t] = ri[t + off];
        }
      }
      __syncthreads();
    }
    if (t == 0) {
      int mi = ri[0]; s[mi] = -1e30f;
      int hy = (mi >> 5) * 2, wx = (mi & 31) * 2;
      posb[bh * 64 + it]      = hy * 64 + wx;
      posb[bh * 64 + 16 + it] = hy * 64 + wx + 1;
      posb[bh * 64 + 32 + it] = (hy + 1) * 64 + wx;
      posb[bh * 64 + 48 + it] = (hy + 1) * 64 + wx + 1;
    }
    __syncthreads();
  }
}

// tk/tv[bh][m][d] = sum_c x[b,c,pos[m]] * kv_w[h*128 + half*64 + d, c] + kv_b
__global__ __launch_bounds__(256) void gather_kv(
    const void* __restrict__ x, const void* __restrict__ kv_w,
    const void* __restrict__ kv_b, const int* __restrict__ posb,
    float* __restrict__ tk, float* __restrict__ tv,
    const int* __restrict__ dtf) {
  const int f32 = *dtf;
  const int bh = blockIdx.x, b = bh >> 3, h = bh & 7;
  const int half = blockIdx.y;
  const int t = threadIdx.x;
  const int m = t & 63, dg = t >> 6;
  __shared__ int pos[64];
  __shared__ float xcol[32][64];
  __shared__ float wch[64][32];
  if (t < 64) pos[t] = posb[bh * 64 + t];
  __syncthreads();
  float acc[16];
#pragma unroll
  for (int i = 0; i < 16; ++i) acc[i] = 0.f;
  const int obase = h * 128 + half * 64;
  for (int c0 = 0; c0 < 512; c0 += 32) {
    __syncthreads();
    for (int i = t; i < 2048; i += 256) {
      int cc = i >> 6, mm = i & 63;
      xcol[cc][mm] = ldf(x, ((size_t)(b * 512 + c0 + cc)) * 4096 + pos[mm], f32);
    }
    for (int i = t; i < 2048; i += 256) {
      int d = i >> 5, cc = i & 31;
      wch[d][cc] = ldf(kv_w, (size_t)(obase + d) * 512 + c0 + cc, f32);
    }
    __syncthreads();
    for (int cc = 0; cc < 32; ++cc) {
      float xv = xcol[cc][m];
#pragma unroll
      for (int dd = 0; dd < 16; ++dd)
        acc[dd] += xv * wch[dg * 16 + dd][cc];
    }
  }
  float* tgt = half ? tv : tk;
  for (int dd = 0; dd < 16; ++dd) {
    int d = dg * 16 + dd;
    tgt[((size_t)bh * 64 + m) * 64 + d] = acc[dd] + ldf(kv_b, obase + d, f32);
  }
}

// coarse attention: per (bh, 8-row tile): sim -> softmax -> PV
__global__ __launch_bounds__(256) void coarse_attn(
    const float* __restrict__ q, const float* __restrict__ k,
    const float* __restrict__ v, float* __restrict__ coarse) {
  const int bh = blockIdx.y;
  const int n0 = blockIdx.x * 8;
  const int t = threadIdx.x;
  const int lane = t & 63, wv = t >> 6;
  __shared__ __align__(16) float qs[8][64];
  __shared__ __align__(16) float sim[8][1024];
  __shared__ __align__(16) float red[4][8][64];
  for (int i = t; i < 512; i += 256) {
    int n = i >> 6, d = i & 63;
    qs[n][d] = q[((size_t)bh * 4096 + n0 + n) * 64 + d];
  }
  __syncthreads();
  {
    float acc[4][8] = {};
    const float4* qs4 = reinterpret_cast<const float4*>(&qs[0][0]);
    for (int d4 = 0; d4 < 16; ++d4) {
      float4 qv[8];
#pragma unroll
      for (int n = 0; n < 8; ++n) qv[n] = qs4[n * 16 + d4];
#pragma unroll
      for (int j = 0; j < 4; ++j) {
        int m = t + j * 256;
        float4 kv = *reinterpret_cast<const float4*>(&k[((size_t)bh * 1024 + m) * 64 + d4 * 4]);
#pragma unroll
        for (int n = 0; n < 8; ++n)
          acc[j][n] += kv.x * qv[n].x + kv.y * qv[n].y + kv.z * qv[n].z + kv.w * qv[n].w;
      }
    }
#pragma unroll
    for (int j = 0; j < 4; ++j)
#pragma unroll
      for (int n = 0; n < 8; ++n)
        sim[n][t + j * 256] = acc[j][n] * 0.125f;
  }
  __syncthreads();
  for (int rr = 0; rr < 2; ++rr) {
    int rrow = wv * 2 + rr;
    float mx = -1e30f;
    for (int i = lane; i < 1024; i += 64) mx = fmaxf(mx, sim[rrow][i]);
    for (int off = 32; off; off >>= 1) mx = fmaxf(mx, __shfl_xor(mx, off, 64));
    float sum = 0.f;
    for (int i = lane; i < 1024; i += 64) {
      float e = __expf(sim[rrow][i] - mx);
      sim[rrow][i] = e; sum += e;
    }
    for (int off = 32; off; off >>= 1) sum += __shfl_xor(sum, off, 64);
    float inv = 1.0f / sum;
    for (int i = lane; i < 1024; i += 64) sim[rrow][i] *= inv;
  }
  __syncthreads();
  {
    const int d = lane, r4 = wv;
    float racc[8] = {};
    for (int mi = 0; mi < 256; mi += 4) {
      int m = r4 * 256 + mi;
      float v0 = v[((size_t)bh * 1024 + m) * 64 + d];
      float v1 = v[((size_t)bh * 1024 + m + 1) * 64 + d];
      float v2 = v[((size_t)bh * 1024 + m + 2) * 64 + d];
      float v3 = v[((size_t)bh * 1024 + m + 3) * 64 + d];
#pragma unroll
      for (int n = 0; n < 8; ++n) {
        float4 wn = *reinterpret_cast<const float4*>(&sim[n][m]);
        racc[n] += wn.x * v0 + wn.y * v1 + wn.z * v2 + wn.w * v3;
      }
    }
#pragma unroll
    for (int n = 0; n < 8; ++n) red[r4][n][d] = racc[n];
  }
  __syncthreads();
  for (int i = t; i < 512; i += 256) {
    int n = i >> 6, dd = i & 63;
    float sres = red[0][n][dd] + red[1][n][dd] + red[2][n][dd] + red[3][n][dd];
    coarse[((size_t)bh * 4096 + n0 + n) * 64 + dd] = sres;
  }
}

// fine attention + gate + combine -> xsum[b][c][n]
__global__ __launch_bounds__(256) void fine_kernel(
    const float* __restrict__ q, const float* __restrict__ tk,
    const float* __restrict__ tv, const float* __restrict__ coarse,
    const void* __restrict__ gate_w, const void* __restrict__ gate_b,
    float* __restrict__ xsum, const int* __restrict__ dtf) {
  const int f32 = *dtf;
  const int bh = blockIdx.y, b = bh >> 3, h = bh & 7;
  const int n0 = blockIdx.x * 64;
  const int t = threadIdx.x, lane = t & 63, w = t >> 6;
  __shared__ float tks_t[64][64];
  __shared__ float tvs[64][64];
  __shared__ bf16  gwsh[128][64];
  __shared__ float qrow[4][64], wrow[4][64], crow[4][64], rrow[4][64];
  for (int i = t; i < 4096; i += 256) {
    int m = i >> 6, d = i & 63;
    tks_t[d][m] = tk[(size_t)bh * 4096 + i];
    tvs[m][d] = tv[(size_t)bh * 4096 + i];
  }
  for (int i = t; i < 8192; i += 256)
    gwsh[i & 127][i >> 7] = f32 ? __float2bfloat16(((const float*)gate_w)[i])
                                : ((const bf16*)gate_w)[i];
  float gb = ldf(gate_b, lane, f32);
  __syncthreads();

  for (int it = 0; it < 16; ++it) {
    int n = n0 + w + it * 4;
    float qv = q[((size_t)bh * 4096 + n) * 64 + lane];
    float cv = coarse[((size_t)bh * 4096 + n) * 64 + lane];
    qrow[w][lane] = qv;
    crow[w][lane] = cv;
    __syncthreads();
    float sm = 0.f;
#pragma unroll
    for (int d = 0; d < 64; ++d) sm += qrow[w][d] * tks_t[d][lane];
    sm *= 0.125f;
    float mx = sm;
    for (int off = 32; off; off >>= 1) mx = fmaxf(mx, __shfl_xor(mx, off, 64));
    float e = __expf(sm - mx);
    float se = e;
    for (int off = 32; off; off >>= 1) se += __shfl_xor(se, off, 64);
    wrow[w][lane] = e / se;
    __syncthreads();
    float r = 0.f;
#pragma unroll
    for (int m = 0; m < 64; ++m) r += wrow[w][m] * tvs[m][lane];
    rrow[w][lane] = r;
    __syncthreads();
    float g = gb;
#pragma unroll
    for (int c = 0; c < 64; ++c)
      g += crow[w][c] * b2f(gwsh[c][lane]) + rrow[w][c] * b2f(gwsh[64 + c][lane]);
    g = 1.0f / (1.0f + __expf(-g));
    float outv = g * r + (1.0f - g) * cv;
    xsum[((size_t)(b * 512 + h * 64 + lane)) * 4096 + n] = outv;
    __syncthreads();
  }
}

// depthwise 7x7 conv on v -> vpe
__global__ __launch_bounds__(256) void dwconv_kernel(
    const float* __restrict__ v, const void* __restrict__ pe_w,
    const void* __restrict__ pe_b, float* __restrict__ vpe,
    const int* __restrict__ dtf) {
  const int f32 = *dtf;
  int bc = blockIdx.x;
  int b = bc >> 9, c = bc & 511;
  int h = c >> 6, d = c & 63;
  int t = threadIdx.x;
  __shared__ float img[1024];
  __shared__ float wts[49];
  for (int i = t; i < 1024; i += 256)
    img[i] = v[((size_t)(b * 8 + h) * 1024 + i) * 64 + d];
  if (t < 49) wts[t] = ldf(pe_w, c * 49 + t, f32);
  float bias = ldf(pe_b, c, f32);
  __syncthreads();
  for (int i = t; i < 1024; i += 256) {
    int y = i >> 5, xx = i & 31;
    float a = 0.f;
#pragma unroll
    for (int ky = 0; ky < 7; ++ky) {
      int yy = y + ky - 3;
      if ((unsigned)yy >= 32u) continue;
#pragma unroll
      for (int kx = 0; kx < 7; ++kx) {
        int xc = xx + kx - 3;
        if ((unsigned)xc >= 32u) continue;
        a += img[yy * 32 + xc] * wts[ky * 7 + kx];
      }
    }
    vpe[(size_t)bc * 1024 + i] = a + bias;
  }
}

// bilinear 2x upsample of vpe added into xsum
__global__ __launch_bounds__(256) void resize_add_kernel(
    const float* __restrict__ vpe, float* __restrict__ xsum) {
  size_t idx = (size_t)blockIdx.x * 256 + threadIdx.x;
  int nx = idx & 63;
  int rest = (int)(idx >> 6);
  int ny = rest & 63;
  int bc = rest >> 6;
  int jy = ny >> 1, jx = nx >> 1;
  int y0, y1, x0, x1; float wy0, wy1, wx0, wx1;
  if ((ny & 1) == 0) { y0 = (jy > 0) ? jy - 1 : 0; y1 = jy; wy0 = 0.25f; wy1 = 0.75f; }
  else               { y0 = jy; y1 = (jy < 31) ? jy + 1 : 31; wy0 = 0.75f; wy1 = 0.25f; }
  if ((nx & 1) == 0) { x0 = (jx > 0) ? jx - 1 : 0; x1 = jx; wx0 = 0.25f; wx1 = 0.75f; }
  else               { x0 = jx; x1 = (jx < 31) ? jx + 1 : 31; wx0 = 0.75f; wx1 = 0.25f; }
  const float* p = vpe + (size_t)bc * 1024;
  float val = wy0 * (wx0 * p[y0 * 32 + x0] + wx1 * p[y0 * 32 + x1]) +
              wy1 * (wx0 * p[y1 * 32 + x0] + wx1 * p[y1 * 32 + x1]);
  xsum[idx] += val;
}

extern "C" void kernel_launch(void* const* d_in, const int* in_sizes, int n_in,
                              void* d_out, int out_size, void* d_ws, size_t ws_size,
                              hipStream_t stream) {
  const void* x    = d_in[0];
  const void* up   = d_in[1];
  const void* gum  = d_in[2];
  const void* q_w  = d_in[3];
  const void* q_b  = d_in[4];
  const void* kv_w = d_in[5];
  const void* kv_b = d_in[6];
  const void* p_w  = d_in[7];
  const void* p_b  = d_in[8];
  const void* pe_w = d_in[9];
  const void* pe_b = d_in[10];
  const void* g_w  = d_in[11];
  const void* g_b  = d_in[12];

  float* ws   = (float*)d_ws;
  int*   dtf  = (int*)ws;            // 16 floats reserved
  float* qsum = ws + 16;             // 1024
  float* heat = qsum + 1024;         // 2048
  int*   posb = (int*)(heat + 2048); // 1024 ints
  float* tk   = heat + 2048 + 1024;  // 65536
  float* tv   = tk + 65536;          // 65536
  float* qb   = tv + 65536;          // 4,194,304
  float* kb   = qb + 4194304;        // 1,048,576
  float* vb   = kb + 1048576;        // 1,048,576
  float* co   = vb + 1048576;        // 4,194,304
  float* xs   = co + 4194304;        // 4,194,304
  float* vpe  = xs + 4194304;        // 1,048,576  (total ~63.5 MB)

  dim3 blk(256);
  hipMemsetAsync(dtf, 0, 4, stream);
  detect_dtype<<<dim3(16384), blk, 0, stream>>>((const unsigned short*)x, dtf);
  gemm_conv<0><<<dim3(64, 8, 2), blk, 0, stream>>>(x, q_w, q_b, qb, nullptr, nullptr, 4096, dtf);
  gemm_conv<1><<<dim3(16, 16, 2), blk, 0, stream>>>(up, kv_w, kv_b, kb, vb, nullptr, 1024, dtf);
  heat_kernel<<<dim3(2048), blk, 0, stream>>>(x, heat, dtf);
  qsum_kernel<<<dim3(16), blk, 0, stream>>>(qb, qsum);
  topk_kernel<<<dim3(16), blk, 0, stream>>>(qsum, kb, heat, gum, posb, dtf);
  gather_kv<<<dim3(16, 2), blk, 0, stream>>>(x, kv_w, kv_b, posb, tk, tv, dtf);
  coarse_attn<<<dim3(512, 16), blk, 0, stream>>>(qb, kb, vb, co);
  fine_kernel<<<dim3(64, 16), blk, 0, stream>>>(qb, tk, tv, co, g_w, g_b, xs, dtf);
  dwconv_kernel<<<dim3(1024), blk, 0, stream>>>(vb, pe_w, pe_b, vpe, dtf);
  resize_add_kernel<<<dim3(16384), blk, 0, stream>>>(vpe, xs);
  gemm_conv<3><<<dim3(64, 8, 2), blk, 0, stream>>>(xs, p_w, p_b, nullptr, nullptr, d_out, 4096, dtf);
}

// Round 3
// 1171.518 us; speedup vs baseline: 1.4390x; 1.4390x over previous
//
#include <hip/hip_runtime.h>
#include <hip/hip_bf16.h>
#include <cstdint>

typedef __hip_bfloat16 bf16;
typedef __attribute__((ext_vector_type(8))) short bf16x8;
typedef __attribute__((ext_vector_type(4))) float f32x4;

static __device__ __forceinline__ float b2f(bf16 v) { return __bfloat162float(v); }

static __device__ __forceinline__ unsigned short f2bs(float f) {
  bf16 h = __float2bfloat16(f);
  unsigned short s;
  __builtin_memcpy(&s, &h, 2);
  return s;
}

// dual-dtype load: f32!=0 -> buffer is float32, else packed bf16
static __device__ __forceinline__ float ldf(const void* p, size_t i, int f32) {
  return f32 ? ((const float*)p)[i] : __bfloat162float(((const bf16*)p)[i]);
}

// ---------------------------------------------------------------------------
// dtype detection: exponent==0xFF impossible for true bf16 N(0,1) data.
// ---------------------------------------------------------------------------
__global__ __launch_bounds__(256) void detect_dtype(const unsigned short* __restrict__ xs,
                                                    int* __restrict__ flag) {
  int i = blockIdx.x * 256 + threadIdx.x;
  unsigned short u = xs[i];
  if (((u >> 7) & 0xFF) == 0xFF) atomicOr(flag, 1);
}

// ---------------------------------------------------------------------------
// conv1x1 GEMM: out[m,o] = sum_k A[b,k,m] * W[o,k] + bias[o];  K=512
// MODE 0: q     -> o0[bh][m][d]                     (M=4096, O=512)
// MODE 1: kv_up -> k/v split into o0/o1[bh][m][d]   (M=1024, O=1024)
// MODE 3: proj  -> out (dual dtype), A is fp32 xsum (M=4096, O=512)
// ---------------------------------------------------------------------------
template<int MODE>
__global__ __launch_bounds__(256) void gemm_conv(
    const void* __restrict__ A, const void* __restrict__ Wt,
    const void* __restrict__ bias, float* __restrict__ o0,
    float* __restrict__ o1, void* __restrict__ ob, int M,
    const int* __restrict__ dtf) {
  const int K = 512;
  const int f32 = *dtf;
  const int b  = blockIdx.z;
  const int mt = blockIdx.x * 64, ot = blockIdx.y * 64;
  const int t  = threadIdx.x;
  __shared__ __align__(16) float As[16][64];
  __shared__ __align__(16) float Ws[16][64];
  float acc[4][4] = {};
  const int tx = t & 15, ty = t >> 4;
  const int mq = (MODE == 3) ? tx : ty;
  const int oq = (MODE == 3) ? ty : tx;

  for (int k0 = 0; k0 < K; k0 += 16) {
    __syncthreads();
#pragma unroll
    for (int j = 0; j < 4; ++j) {
      int i = t + j * 256;
      int kl = i >> 6, ml = i & 63;
      size_t ai = ((size_t)(b * K + k0 + kl)) * M + mt + ml;
      As[kl][ml] = (MODE == 3) ? ((const float*)A)[ai] : ldf(A, ai, f32);
      int ol = i >> 4, kl2 = i & 15;
      Ws[kl2][ol] = ldf(Wt, (size_t)(ot + ol) * K + k0 + kl2, f32);
    }
    __syncthreads();
    const float4* As4 = reinterpret_cast<const float4*>(&As[0][0]);
    const float4* Ws4 = reinterpret_cast<const float4*>(&Ws[0][0]);
#pragma unroll
    for (int kk = 0; kk < 16; ++kk) {
      float4 a4 = As4[kk * 16 + mq];
      float4 w4 = Ws4[kk * 16 + oq];
      float av[4] = {a4.x, a4.y, a4.z, a4.w};
      float wv[4] = {w4.x, w4.y, w4.z, w4.w};
#pragma unroll
      for (int mi = 0; mi < 4; ++mi)
#pragma unroll
        for (int oi = 0; oi < 4; ++oi)
          acc[mi][oi] += av[mi] * wv[oi];
    }
  }
#pragma unroll
  for (int mi = 0; mi < 4; ++mi) {
    int m = mt + mq * 4 + mi;
#pragma unroll
    for (int oi = 0; oi < 4; ++oi) {
      int o = ot + oq * 4 + oi;
      float val = acc[mi][oi] + ldf(bias, o, f32);
      if (MODE == 0) {
        o0[((size_t)(b * 8 + (o >> 6)) * M + m) * 64 + (o & 63)] = val;
      } else if (MODE == 1) {
        int hh = o >> 7, jj = o & 127;
        float* tgt = (jj < 64) ? o0 : o1;
        tgt[((size_t)(b * 8 + hh) * M + m) * 64 + (jj & 63)] = val;
      } else {
        size_t oi_ = ((size_t)(b * 512 + o)) * M + m;
        if (f32) ((float*)ob)[oi_] = val;
        else     ((bf16*)ob)[oi_] = __float2bfloat16(val);
      }
    }
  }
}

// heat[b,mu] = mean over C and 2x2 block of x
__global__ __launch_bounds__(256) void heat_kernel(const void* __restrict__ x,
                                                   float* __restrict__ heat,
                                                   const int* __restrict__ dtf) {
  const int f32 = *dtf;
  int bm = blockIdx.x;
  int b = bm >> 10, mu = bm & 1023;
  int hu = mu >> 5, wu = mu & 31;
  int t = threadIdx.x;
  float s = 0.f;
  for (int c = t; c < 512; c += 256) {
    size_t base = ((size_t)(b * 512 + c) * 64 + hu * 2) * 64 + wu * 2;
    s += ldf(x, base, f32) + ldf(x, base + 1, f32) + ldf(x, base + 64, f32) + ldf(x, base + 65, f32);
  }
  __shared__ float r[256];
  r[t] = s; __syncthreads();
  for (int off = 128; off; off >>= 1) { if (t < off) r[t] += r[t + off]; __syncthreads(); }
  if (t == 0) heat[bm] = r[0] * (1.0f / 2048.0f);
}

// qsum[bh,d] = sum_n q[bh,n,d]
__global__ __launch_bounds__(256) void qsum_kernel(const float* __restrict__ q,
                                                   float* __restrict__ qsum) {
  int bh = blockIdx.x, t = threadIdx.x;
  int d = t & 63, g = t >> 6;
  float s = 0.f;
  for (int n = g * 1024; n < (g + 1) * 1024; ++n)
    s += q[((size_t)bh * 4096 + n) * 64 + d];
  __shared__ float r[256];
  r[t] = s; __syncthreads();
  if (t < 64) qsum[bh * 64 + t] = r[t] + r[t + 64] + r[t + 128] + r[t + 192];
}

// scores -> top-16 coarse cells -> 64 full-res positions into posb
__global__ __launch_bounds__(256) void topk_kernel(
    const float* __restrict__ qsum, const float* __restrict__ k,
    const float* __restrict__ heat, const void* __restrict__ gumbel,
    int* __restrict__ posb, const int* __restrict__ dtf) {
  const int f32 = *dtf;
  int bh = blockIdx.x, b = bh >> 3, t = threadIdx.x;
  __shared__ float qs[64];
  __shared__ float s[1024];
  __shared__ float rv[256];
  __shared__ int   ri[256];
  if (t < 64) qs[t] = qsum[bh * 64 + t];
  __syncthreads();
  for (int j = 0; j < 4; ++j) {
    int m = t + j * 256;
    const float* kr = k + ((size_t)bh * 1024 + m) * 64;
    float dot = 0.f;
    for (int d = 0; d < 64; ++d) dot += qs[d] * kr[d];
    s[m] = dot * (0.125f / 4096.0f) * heat[b * 1024 + m] + ldf(gumbel, (size_t)bh * 1024 + m, f32);
  }
  __syncthreads();
  for (int it = 0; it < 16; ++it) {
    float bv = -1e30f; int bi = 0x7fffffff;
    for (int j = 0; j < 4; ++j) {
      int m = t + j * 256; float vv = s[m];
      if (vv > bv || (vv == bv && m < bi)) { bv = vv; bi = m; }
    }
    rv[t] = bv; ri[t] = bi; __syncthreads();
    for (int off = 128; off; off >>= 1) {
      if (t < off) {
        if (rv[t + off] > rv[t] || (rv[t + off] == rv[t] && ri[t + off] < ri[t])) {
          rv[t] = rv[t + off]; ri[t] = ri[t + off];
        }
      }
      __syncthreads();
    }
    if (t == 0) {
      int mi = ri[0]; s[mi] = -1e30f;
      int hy = (mi >> 5) * 2, wx = (mi & 31) * 2;
      posb[bh * 64 + it]      = hy * 64 + wx;
      posb[bh * 64 + 16 + it] = hy * 64 + wx + 1;
      posb[bh * 64 + 32 + it] = (hy + 1) * 64 + wx;
      posb[bh * 64 + 48 + it] = (hy + 1) * 64 + wx + 1;
    }
    __syncthreads();
  }
}

// tk/tv[bh][m][d] = sum_c x[b,c,pos[m]] * kv_w[h*128 + half*64 + d, c] + kv_b
__global__ __launch_bounds__(256) void gather_kv(
    const void* __restrict__ x, const void* __restrict__ kv_w,
    const void* __restrict__ kv_b, const int* __restrict__ posb,
    float* __restrict__ tk, float* __restrict__ tv,
    const int* __restrict__ dtf) {
  const int f32 = *dtf;
  const int bh = blockIdx.x, b = bh >> 3, h = bh & 7;
  const int half = blockIdx.y;
  const int t = threadIdx.x;
  const int m = t & 63, dg = t >> 6;
  __shared__ int pos[64];
  __shared__ float xcol[32][64];
  __shared__ float wch[64][32];
  if (t < 64) pos[t] = posb[bh * 64 + t];
  __syncthreads();
  float acc[16];
#pragma unroll
  for (int i = 0; i < 16; ++i) acc[i] = 0.f;
  const int obase = h * 128 + half * 64;
  for (int c0 = 0; c0 < 512; c0 += 32) {
    __syncthreads();
    for (int i = t; i < 2048; i += 256) {
      int cc = i >> 6, mm = i & 63;
      xcol[cc][mm] = ldf(x, ((size_t)(b * 512 + c0 + cc)) * 4096 + pos[mm], f32);
    }
    for (int i = t; i < 2048; i += 256) {
      int d = i >> 5, cc = i & 31;
      wch[d][cc] = ldf(kv_w, (size_t)(obase + d) * 512 + c0 + cc, f32);
    }
    __syncthreads();
    for (int cc = 0; cc < 32; ++cc) {
      float xv = xcol[cc][m];
#pragma unroll
      for (int dd = 0; dd < 16; ++dd)
        acc[dd] += xv * wch[dg * 16 + dd][cc];
    }
  }
  float* tgt = half ? tv : tk;
  for (int dd = 0; dd < 16; ++dd) {
    int d = dg * 16 + dd;
    tgt[((size_t)bh * 64 + m) * 64 + d] = acc[dd] + ldf(kv_b, obase + d, f32);
  }
}

// ---------------------------------------------------------------------------
// coarse attention via bf16 MFMA 16x16x32.
// Block: 256 thr = 4 waves; wave w owns 16 q-rows (n = n0 + w*16 + (lane&15)).
// Computes S^T = K.Q^T (C layout: col=n, row=m), exp (no max shift: |sim|<~5),
// P^T -> per-wave LDS [n][m] -> B-frags; O^T = V^T.P^T; divide by sum at end.
// ---------------------------------------------------------------------------
__global__ __launch_bounds__(256) void coarse_attn_mfma(
    const float* __restrict__ q, const float* __restrict__ k,
    const float* __restrict__ v, float* __restrict__ coarse) {
  const int bh = blockIdx.y;
  const int n0 = blockIdx.x * 64;
  const int t = threadIdx.x;
  const int w = t >> 6, lane = t & 63;
  const int quad = lane >> 4, c = lane & 15;

  __shared__ __align__(16) unsigned short Ks[64][72];     // K[m][d] bf16
  __shared__ __align__(16) unsigned short Vt[64][72];     // V^T[d][m] bf16
  __shared__ __align__(16) unsigned short Ps[4][16][72];  // per-wave P^T as [n][m]

  const int n = n0 + w * 16 + c;
  // Q row -> B-frags: bq[s] holds Q[n][s*32 + quad*8 + j], j=0..7
  bf16x8 bq[2];
  {
    const float* qr = q + ((size_t)bh * 4096 + n) * 64;
#pragma unroll
    for (int s = 0; s < 2; ++s) {
      int db = s * 32 + quad * 8;
#pragma unroll
      for (int j = 0; j < 8; ++j) bq[s][j] = (short)f2bs(qr[db + j]);
    }
  }

  f32x4 po[4];  // O^T acc: dtile 0..3 (col=n, row=d=dt*16+quad*4+reg)
#pragma unroll
  for (int dt = 0; dt < 4; ++dt) po[dt] = (f32x4){0.f, 0.f, 0.f, 0.f};
  float sume = 0.f;

  for (int m0 = 0; m0 < 1024; m0 += 64) {
    __syncthreads();
    // stage K chunk row-major, V chunk transposed (both bf16)
    for (int i = t; i < 4096; i += 256) {
      int mm = i >> 6, dd = i & 63;
      size_t gi = ((size_t)bh * 1024 + m0 + mm) * 64 + dd;
      Ks[mm][dd] = f2bs(k[gi]);
      Vt[dd][mm] = f2bs(v[gi]);
    }
    __syncthreads();

    // S^T tiles: A = K (A[m=lane&15][d=quad*8+j]), B = bq
    f32x4 st[4];
#pragma unroll
    for (int mt = 0; mt < 4; ++mt) {
      f32x4 acc = (f32x4){0.f, 0.f, 0.f, 0.f};
#pragma unroll
      for (int s = 0; s < 2; ++s) {
        bf16x8 ak = *reinterpret_cast<const bf16x8*>(&Ks[mt * 16 + c][s * 32 + quad * 8]);
        acc = __builtin_amdgcn_mfma_f32_16x16x32_bf16(ak, bq[s], acc, 0, 0, 0);
      }
      st[mt] = acc;
    }

    // exp + row-sum + pack P^T into LDS [n][m]
    float chunksum = 0.f;
#pragma unroll
    for (int mt = 0; mt < 4; ++mt) {
      float e0 = __expf(st[mt][0] * 0.125f);
      float e1 = __expf(st[mt][1] * 0.125f);
      float e2 = __expf(st[mt][2] * 0.125f);
      float e3 = __expf(st[mt][3] * 0.125f);
      chunksum += (e0 + e1) + (e2 + e3);
      short4 pw;
      pw.x = (short)f2bs(e0); pw.y = (short)f2bs(e1);
      pw.z = (short)f2bs(e2); pw.w = (short)f2bs(e3);
      *reinterpret_cast<short4*>(&Ps[w][c][mt * 16 + quad * 4]) = pw;
    }
    // reduce row-sum across quads (lanes sharing col n)
    chunksum += __shfl_xor(chunksum, 16, 64);
    chunksum += __shfl_xor(chunksum, 32, 64);
    sume += chunksum;

    // PV: O^T += V^T . P^T
#pragma unroll
    for (int s = 0; s < 2; ++s) {
      bf16x8 bp = *reinterpret_cast<const bf16x8*>(&Ps[w][c][s * 32 + quad * 8]);
#pragma unroll
      for (int dt = 0; dt < 4; ++dt) {
        bf16x8 av = *reinterpret_cast<const bf16x8*>(&Vt[dt * 16 + c][s * 32 + quad * 8]);
        po[dt] = __builtin_amdgcn_mfma_f32_16x16x32_bf16(av, bp, po[dt], 0, 0, 0);
      }
    }
  }

  float inv = 1.0f / sume;
  float* orow = coarse + ((size_t)bh * 4096 + n) * 64;
#pragma unroll
  for (int dt = 0; dt < 4; ++dt) {
    float4 r;
    r.x = po[dt][0] * inv; r.y = po[dt][1] * inv;
    r.z = po[dt][2] * inv; r.w = po[dt][3] * inv;
    *reinterpret_cast<float4*>(&orow[dt * 16 + quad * 4]) = r;
  }
}

// fine attention + gate + combine -> xsum[b][c][n]
__global__ __launch_bounds__(256) void fine_kernel(
    const float* __restrict__ q, const float* __restrict__ tk,
    const float* __restrict__ tv, const float* __restrict__ coarse,
    const void* __restrict__ gate_w, const void* __restrict__ gate_b,
    float* __restrict__ xsum, const int* __restrict__ dtf) {
  const int f32 = *dtf;
  const int bh = blockIdx.y, b = bh >> 3, h = bh & 7;
  const int n0 = blockIdx.x * 64;
  const int t = threadIdx.x, lane = t & 63, w = t >> 6;
  __shared__ float tks_t[64][64];
  __shared__ float tvs[64][64];
  __shared__ bf16  gwsh[128][64];
  __shared__ float qrow[4][64], wrow[4][64], crow[4][64], rrow[4][64];
  for (int i = t; i < 4096; i += 256) {
    int m = i >> 6, d = i & 63;
    tks_t[d][m] = tk[(size_t)bh * 4096 + i];
    tvs[m][d] = tv[(size_t)bh * 4096 + i];
  }
  for (int i = t; i < 8192; i += 256)
    gwsh[i & 127][i >> 7] = f32 ? __float2bfloat16(((const float*)gate_w)[i])
                                : ((const bf16*)gate_w)[i];
  float gb = ldf(gate_b, lane, f32);
  __syncthreads();

  for (int it = 0; it < 16; ++it) {
    int n = n0 + w + it * 4;
    float qv = q[((size_t)bh * 4096 + n) * 64 + lane];
    float cv = coarse[((size_t)bh * 4096 + n) * 64 + lane];
    qrow[w][lane] = qv;
    crow[w][lane] = cv;
    __syncthreads();
    float sm = 0.f;
#pragma unroll
    for (int d = 0; d < 64; ++d) sm += qrow[w][d] * tks_t[d][lane];
    sm *= 0.125f;
    float mx = sm;
    for (int off = 32; off; off >>= 1) mx = fmaxf(mx, __shfl_xor(mx, off, 64));
    float e = __expf(sm - mx);
    float se = e;
    for (int off = 32; off; off >>= 1) se += __shfl_xor(se, off, 64);
    wrow[w][lane] = e / se;
    __syncthreads();
    float r = 0.f;
#pragma unroll
    for (int m = 0; m < 64; ++m) r += wrow[w][m] * tvs[m][lane];
    rrow[w][lane] = r;
    __syncthreads();
    float g = gb;
#pragma unroll
    for (int c = 0; c < 64; ++c)
      g += crow[w][c] * b2f(gwsh[c][lane]) + rrow[w][c] * b2f(gwsh[64 + c][lane]);
    g = 1.0f / (1.0f + __expf(-g));
    float outv = g * r + (1.0f - g) * cv;
    xsum[((size_t)(b * 512 + h * 64 + lane)) * 4096 + n] = outv;
    __syncthreads();
  }
}

// depthwise 7x7 conv on v -> vpe
__global__ __launch_bounds__(256) void dwconv_kernel(
    const float* __restrict__ v, const void* __restrict__ pe_w,
    const void* __restrict__ pe_b, float* __restrict__ vpe,
    const int* __restrict__ dtf) {
  const int f32 = *dtf;
  int bc = blockIdx.x;
  int b = bc >> 9, c = bc & 511;
  int h = c >> 6, d = c & 63;
  int t = threadIdx.x;
  __shared__ float img[1024];
  __shared__ float wts[49];
  for (int i = t; i < 1024; i += 256)
    img[i] = v[((size_t)(b * 8 + h) * 1024 + i) * 64 + d];
  if (t < 49) wts[t] = ldf(pe_w, c * 49 + t, f32);
  float bias = ldf(pe_b, c, f32);
  __syncthreads();
  for (int i = t; i < 1024; i += 256) {
    int y = i >> 5, xx = i & 31;
    float a = 0.f;
#pragma unroll
    for (int ky = 0; ky < 7; ++ky) {
      int yy = y + ky - 3;
      if ((unsigned)yy >= 32u) continue;
#pragma unroll
      for (int kx = 0; kx < 7; ++kx) {
        int xc = xx + kx - 3;
        if ((unsigned)xc >= 32u) continue;
        a += img[yy * 32 + xc] * wts[ky * 7 + kx];
      }
    }
    vpe[(size_t)bc * 1024 + i] = a + bias;
  }
}

// bilinear 2x upsample of vpe added into xsum
__global__ __launch_bounds__(256) void resize_add_kernel(
    const float* __restrict__ vpe, float* __restrict__ xsum) {
  size_t idx = (size_t)blockIdx.x * 256 + threadIdx.x;
  int nx = idx & 63;
  int rest = (int)(idx >> 6);
  int ny = rest & 63;
  int bc = rest >> 6;
  int jy = ny >> 1, jx = nx >> 1;
  int y0, y1, x0, x1; float wy0, wy1, wx0, wx1;
  if ((ny & 1) == 0) { y0 = (jy > 0) ? jy - 1 : 0; y1 = jy; wy0 = 0.25f; wy1 = 0.75f; }
  else               { y0 = jy; y1 = (jy < 31) ? jy + 1 : 31; wy0 = 0.75f; wy1 = 0.25f; }
  if ((nx & 1) == 0) { x0 = (jx > 0) ? jx - 1 : 0; x1 = jx; wx0 = 0.25f; wx1 = 0.75f; }
  else               { x0 = jx; x1 = (jx < 31) ? jx + 1 : 31; wx0 = 0.75f; wx1 = 0.25f; }
  const float* p = vpe + (size_t)bc * 1024;
  float val = wy0 * (wx0 * p[y0 * 32 + x0] + wx1 * p[y0 * 32 + x1]) +
              wy1 * (wx0 * p[y1 * 32 + x0] + wx1 * p[y1 * 32 + x1]);
  xsum[idx] += val;
}

extern "C" void kernel_launch(void* const* d_in, const int* in_sizes, int n_in,
                              void* d_out, int out_size, void* d_ws, size_t ws_size,
                              hipStream_t stream) {
  const void* x    = d_in[0];
  const void* up   = d_in[1];
  const void* gum  = d_in[2];
  const void* q_w  = d_in[3];
  const void* q_b  = d_in[4];
  const void* kv_w = d_in[5];
  const void* kv_b = d_in[6];
  const void* p_w  = d_in[7];
  const void* p_b  = d_in[8];
  const void* pe_w = d_in[9];
  const void* pe_b = d_in[10];
  const void* g_w  = d_in[11];
  const void* g_b  = d_in[12];

  float* ws   = (float*)d_ws;
  int*   dtf  = (int*)ws;            // 16 floats reserved
  float* qsum = ws + 16;             // 1024
  float* heat = qsum + 1024;         // 2048
  int*   posb = (int*)(heat + 2048); // 1024 ints
  float* tk   = heat + 2048 + 1024;  // 65536
  float* tv   = tk + 65536;          // 65536
  float* qb   = tv + 65536;          // 4,194,304
  float* kb   = qb + 4194304;        // 1,048,576
  float* vb   = kb + 1048576;        // 1,048,576
  float* co   = vb + 1048576;        // 4,194,304
  float* xs   = co + 4194304;        // 4,194,304
  float* vpe  = xs + 4194304;        // 1,048,576  (total ~63.5 MB)

  dim3 blk(256);
  hipMemsetAsync(dtf, 0, 4, stream);
  detect_dtype<<<dim3(16384), blk, 0, stream>>>((const unsigned short*)x, dtf);
  gemm_conv<0><<<dim3(64, 8, 2), blk, 0, stream>>>(x, q_w, q_b, qb, nullptr, nullptr, 4096, dtf);
  gemm_conv<1><<<dim3(16, 16, 2), blk, 0, stream>>>(up, kv_w, kv_b, kb, vb, nullptr, 1024, dtf);
  heat_kernel<<<dim3(2048), blk, 0, stream>>>(x, heat, dtf);
  qsum_kernel<<<dim3(16), blk, 0, stream>>>(qb, qsum);
  topk_kernel<<<dim3(16), blk, 0, stream>>>(qsum, kb, heat, gum, posb, dtf);
  gather_kv<<<dim3(16, 2), blk, 0, stream>>>(x, kv_w, kv_b, posb, tk, tv, dtf);
  coarse_attn_mfma<<<dim3(64, 16), blk, 0, stream>>>(qb, kb, vb, co);
  fine_kernel<<<dim3(64, 16), blk, 0, stream>>>(qb, tk, tv, co, g_w, g_b, xs, dtf);
  dwconv_kernel<<<dim3(1024), blk, 0, stream>>>(vb, pe_w, pe_b, vpe, dtf);
  resize_add_kernel<<<dim3(16384), blk, 0, stream>>>(vpe, xs);
  gemm_conv<3><<<dim3(64, 8, 2), blk, 0, stream>>>(xs, p_w, p_b, nullptr, nullptr, d_out, 4096, dtf);
}

// Round 4
// 621.556 us; speedup vs baseline: 2.7122x; 1.8848x over previous
//
#include <hip/hip_runtime.h>
#include <hip/hip_bf16.h>
#include <cstdint>

typedef __hip_bfloat16 bf16;
typedef unsigned short u16;
typedef __attribute__((ext_vector_type(8))) short bf16x8;
typedef __attribute__((ext_vector_type(4))) float f32x4;

static __device__ __forceinline__ float b2f(bf16 v) { return __bfloat162float(v); }
static __device__ __forceinline__ float bs2f(u16 s) {
  unsigned int u = ((unsigned int)s) << 16;
  float f;
  __builtin_memcpy(&f, &u, 4);
  return f;
}
static __device__ __forceinline__ u16 f2bs(float f) {
  bf16 h = __float2bfloat16(f);
  u16 s;
  __builtin_memcpy(&s, &h, 2);
  return s;
}
// dual-dtype load: f32!=0 -> buffer is float32, else packed bf16
static __device__ __forceinline__ float ldf(const void* p, size_t i, int f32) {
  return f32 ? ((const float*)p)[i] : bs2f(((const u16*)p)[i]);
}

// ---------------------------------------------------------------------------
// dtype detection: exponent==0xFF impossible for true bf16 N(0,1) data.
// ---------------------------------------------------------------------------
__global__ __launch_bounds__(256) void detect_dtype(const u16* __restrict__ xs,
                                                    int* __restrict__ flag) {
  int i = blockIdx.x * 256 + threadIdx.x;
  u16 u = xs[i];
  if (((u >> 7) & 0xFF) == 0xFF) atomicOr(flag, 1);
}

// ---------------------------------------------------------------------------
// transpose [b][c=512][N] (dual dtype, or forced f32) -> [b][N][512] bf16
// grid (N/64, 8, B), 256 thr
// ---------------------------------------------------------------------------
template<int ALWAYS_F32>
__global__ __launch_bounds__(256) void transpose_bf16(
    const void* __restrict__ src, u16* __restrict__ dst, int N,
    const int* __restrict__ dtf) {
  const int f32 = ALWAYS_F32 ? 1 : *dtf;
  const int b = blockIdx.z, n0 = blockIdx.x * 64, c0 = blockIdx.y * 64;
  const int t = threadIdx.x;
  __shared__ __align__(16) u16 tile[64][72];
#pragma unroll
  for (int j = 0; j < 2; ++j) {
    int cc = (t >> 3) + j * 32;
    int nn = (t & 7) * 8;
    u16 tmp[8];
    if (f32) {
      const float* s4 = (const float*)src + ((size_t)(b * 512 + c0 + cc)) * N + n0 + nn;
#pragma unroll
      for (int u = 0; u < 8; ++u) tmp[u] = f2bs(s4[u]);
    } else {
      *reinterpret_cast<uint4*>(tmp) = *reinterpret_cast<const uint4*>(
          (const u16*)src + ((size_t)(b * 512 + c0 + cc)) * N + n0 + nn);
    }
    *reinterpret_cast<uint4*>(&tile[cc][nn]) = *reinterpret_cast<const uint4*>(tmp);
  }
  __syncthreads();
#pragma unroll
  for (int j = 0; j < 2; ++j) {
    int nn = (t >> 3) + j * 32;
    int cc0 = (t & 7) * 8;
    u16 tmp[8];
#pragma unroll
    for (int u = 0; u < 8; ++u) tmp[u] = tile[cc0 + u][nn];
    *reinterpret_cast<uint4*>(&dst[((size_t)b * N + n0 + nn) * 512 + c0 + cc0]) =
        *reinterpret_cast<const uint4*>(tmp);
  }
}

// ---------------------------------------------------------------------------
// MFMA conv1x1 GEMM: OUT[m,o] = sum_k AT[b][m][k]*W[o][k] + bias[o]; K=512.
// AT bf16 [B][M][512]. Tile 64m x 64o, 4 waves; wave w owns m-rows w*16..+15.
// MODE 0: q    -> o0 bf16 [bh][m][64]          (M=4096, O=512)
// MODE 1: kv   -> kb/vb bf16 [bh][mu][64]      (M=1024, O=1024)
// MODE 3: proj -> ob dual-dtype [b][o][m], operands swapped for coalesced store
// ---------------------------------------------------------------------------
template<int MODE>
__global__ __launch_bounds__(256) void gemm_mfma(
    const u16* __restrict__ A, const void* __restrict__ W,
    const void* __restrict__ bias, u16* __restrict__ o0, u16* __restrict__ o1,
    void* __restrict__ ob, int M, const int* __restrict__ dtf) {
  const int f32 = *dtf;
  const int b = blockIdx.z, m0 = blockIdx.x * 64, oo0 = blockIdx.y * 64;
  const int t = threadIdx.x, w = t >> 6, lane = t & 63;
  const int quad = lane >> 4, c = lane & 15;
  __shared__ __align__(16) u16 As[64][72];
  __shared__ __align__(16) u16 Ws[64][72];
  f32x4 acc[4];
#pragma unroll
  for (int ot = 0; ot < 4; ++ot) acc[ot] = (f32x4){0.f, 0.f, 0.f, 0.f};
  const u16* Ab = A + (size_t)b * M * 512;
  const int srow = t >> 2, scol = (t & 3) * 16;

  for (int k0 = 0; k0 < 512; k0 += 64) {
    __syncthreads();
    {
      const u16* ga = Ab + (size_t)(m0 + srow) * 512 + k0 + scol;
      *reinterpret_cast<uint4*>(&As[srow][scol])     = *reinterpret_cast<const uint4*>(ga);
      *reinterpret_cast<uint4*>(&As[srow][scol + 8]) = *reinterpret_cast<const uint4*>(ga + 8);
      if (f32) {
        const float* gw = (const float*)W + (size_t)(oo0 + srow) * 512 + k0 + scol;
#pragma unroll
        for (int e = 0; e < 16; ++e) Ws[srow][scol + e] = f2bs(gw[e]);
      } else {
        const u16* gw = (const u16*)W + (size_t)(oo0 + srow) * 512 + k0 + scol;
        *reinterpret_cast<uint4*>(&Ws[srow][scol])     = *reinterpret_cast<const uint4*>(gw);
        *reinterpret_cast<uint4*>(&Ws[srow][scol + 8]) = *reinterpret_cast<const uint4*>(gw + 8);
      }
    }
    __syncthreads();
#pragma unroll
    for (int ks = 0; ks < 2; ++ks) {
      bf16x8 av = *reinterpret_cast<const bf16x8*>(&As[w * 16 + c][ks * 32 + quad * 8]);
#pragma unroll
      for (int ot = 0; ot < 4; ++ot) {
        bf16x8 wv = *reinterpret_cast<const bf16x8*>(&Ws[ot * 16 + c][ks * 32 + quad * 8]);
        if (MODE == 3)
          acc[ot] = __builtin_amdgcn_mfma_f32_16x16x32_bf16(wv, av, acc[ot], 0, 0, 0);
        else
          acc[ot] = __builtin_amdgcn_mfma_f32_16x16x32_bf16(av, wv, acc[ot], 0, 0, 0);
      }
    }
  }

  if (MODE == 0) {
#pragma unroll
    for (int ot = 0; ot < 4; ++ot) {
      int o = oo0 + ot * 16 + c;
      float bv = ldf(bias, o, f32);
      int h = o >> 6, d = o & 63;
#pragma unroll
      for (int r = 0; r < 4; ++r) {
        int m = m0 + w * 16 + quad * 4 + r;
        o0[((size_t)(b * 8 + h) * M + m) * 64 + d] = f2bs(acc[ot][r] + bv);
      }
    }
  } else if (MODE == 1) {
#pragma unroll
    for (int ot = 0; ot < 4; ++ot) {
      int o = oo0 + ot * 16 + c;
      float bv = ldf(bias, o, f32);
      int hh = o >> 7, jj = o & 127;
      u16* tgt = (jj < 64) ? o0 : o1;
#pragma unroll
      for (int r = 0; r < 4; ++r) {
        int m = m0 + w * 16 + quad * 4 + r;
        tgt[((size_t)(b * 8 + hh) * M + m) * 64 + (jj & 63)] = f2bs(acc[ot][r] + bv);
      }
    }
  } else {
#pragma unroll
    for (int ot = 0; ot < 4; ++ot) {
#pragma unroll
      for (int r = 0; r < 4; ++r) {
        int o = oo0 + ot * 16 + quad * 4 + r;
        float val = acc[ot][r] + ldf(bias, o, f32);
        int m = m0 + w * 16 + c;
        size_t oi_ = ((size_t)(b * 512 + o)) * M + m;
        if (f32) ((float*)ob)[oi_] = val;
        else     ((u16*)ob)[oi_] = f2bs(val);
      }
    }
  }
}

// heat[b,mu] = mean over C and 2x2 block of x
__global__ __launch_bounds__(256) void heat_kernel(const void* __restrict__ x,
                                                   float* __restrict__ heat,
                                                   const int* __restrict__ dtf) {
  const int f32 = *dtf;
  int bm = blockIdx.x;
  int b = bm >> 10, mu = bm & 1023;
  int hu = mu >> 5, wu = mu & 31;
  int t = threadIdx.x;
  float s = 0.f;
  for (int c = t; c < 512; c += 256) {
    size_t base = ((size_t)(b * 512 + c) * 64 + hu * 2) * 64 + wu * 2;
    s += ldf(x, base, f32) + ldf(x, base + 1, f32) + ldf(x, base + 64, f32) + ldf(x, base + 65, f32);
  }
  __shared__ float r[256];
  r[t] = s; __syncthreads();
  for (int off = 128; off; off >>= 1) { if (t < off) r[t] += r[t + off]; __syncthreads(); }
  if (t == 0) heat[bm] = r[0] * (1.0f / 2048.0f);
}

// stage 1 of qsum: partial[bh][chunk][d] = sum over 256 n-rows
__global__ __launch_bounds__(256) void qsum_partial(const u16* __restrict__ q,
                                                    float* __restrict__ qsumP) {
  int bh = blockIdx.x, ch = blockIdx.y, t = threadIdx.x;
  int d = t & 63, g = t >> 6;
  int n0 = ch * 256 + g * 64;
  float s = 0.f;
  for (int r = 0; r < 64; ++r)
    s += bs2f(q[((size_t)bh * 4096 + n0 + r) * 64 + d]);
  __shared__ float r[256];
  r[t] = s; __syncthreads();
  if (t < 64) qsumP[(size_t)(bh * 16 + ch) * 64 + t] = r[t] + r[t + 64] + r[t + 128] + r[t + 192];
}

// scores -> top-16 coarse cells -> 64 full-res positions into posb
__global__ __launch_bounds__(256) void topk_kernel(
    const float* __restrict__ qsumP, const u16* __restrict__ k,
    const float* __restrict__ heat, const void* __restrict__ gumbel,
    int* __restrict__ posb, const int* __restrict__ dtf) {
  const int f32 = *dtf;
  int bh = blockIdx.x, b = bh >> 3, t = threadIdx.x;
  __shared__ float qs[64];
  __shared__ float s[1024];
  __shared__ float rv[256];
  __shared__ int   ri[256];
  if (t < 64) {
    float acc = 0.f;
    for (int ch = 0; ch < 16; ++ch) acc += qsumP[(size_t)(bh * 16 + ch) * 64 + t];
    qs[t] = acc;
  }
  __syncthreads();
  for (int j = 0; j < 4; ++j) {
    int m = t + j * 256;
    const u16* kr = k + ((size_t)bh * 1024 + m) * 64;
    float dot = 0.f;
    for (int d = 0; d < 64; ++d) dot += qs[d] * bs2f(kr[d]);
    s[m] = dot * (0.125f / 4096.0f) * heat[b * 1024 + m] + ldf(gumbel, (size_t)bh * 1024 + m, f32);
  }
  __syncthreads();
  for (int it = 0; it < 16; ++it) {
    float bv = -1e30f; int bi = 0x7fffffff;
    for (int j = 0; j < 4; ++j) {
      int m = t + j * 256; float vv = s[m];
      if (vv > bv || (vv == bv && m < bi)) { bv = vv; bi = m; }
    }
    rv[t] = bv; ri[t] = bi; __syncthreads();
    for (int off = 128; off; off >>= 1) {
      if (t < off) {
        if (rv[t + off] > rv[t] || (rv[t + off] == rv[t] && ri[t + off] < ri[t])) {
          rv[t] = rv[t + off]; ri[t] = ri[t + off];
        }
      }
      __syncthreads();
    }
    if (t == 0) {
      int mi = ri[0]; s[mi] = -1e30f;
      int hy = (mi >> 5) * 2, wx = (mi & 31) * 2;
      posb[bh * 64 + it]      = hy * 64 + wx;
      posb[bh * 64 + 16 + it] = hy * 64 + wx + 1;
      posb[bh * 64 + 32 + it] = (hy + 1) * 64 + wx;
      posb[bh * 64 + 48 + it] = (hy + 1) * 64 + wx + 1;
    }
    __syncthreads();
  }
}

// tk/tv[bh][m][d] = sum_c xT[b,pos[m],c] * kv_w[obase+d, c] + kv_b
__global__ __launch_bounds__(256) void gather_kv(
    const u16* __restrict__ xT, const void* __restrict__ kv_w,
    const void* __restrict__ kv_b, const int* __restrict__ posb,
    float* __restrict__ tk, float* __restrict__ tv,
    const int* __restrict__ dtf) {
  const int f32 = *dtf;
  const int bh = blockIdx.x, b = bh >> 3, h = bh & 7;
  const int half = blockIdx.y;
  const int t = threadIdx.x;
  const int m = t & 63, dg = t >> 6;
  __shared__ int pos[64];
  __shared__ float xcol[64][33];   // [m][cc]
  __shared__ float wch[64][32];    // [d][cc]
  if (t < 64) pos[t] = posb[bh * 64 + t];
  __syncthreads();
  float acc[16];
#pragma unroll
  for (int i = 0; i < 16; ++i) acc[i] = 0.f;
  const int obase = h * 128 + half * 64;
  for (int c0 = 0; c0 < 512; c0 += 32) {
    __syncthreads();
    for (int i = t; i < 2048; i += 256) {
      int mm = i >> 5, cc = i & 31;
      xcol[mm][cc] = bs2f(xT[((size_t)b * 4096 + pos[mm]) * 512 + c0 + cc]);
    }
    for (int i = t; i < 2048; i += 256) {
      int d = i >> 5, cc = i & 31;
      wch[d][cc] = ldf(kv_w, (size_t)(obase + d) * 512 + c0 + cc, f32);
    }
    __syncthreads();
    for (int cc = 0; cc < 32; ++cc) {
      float xv = xcol[m][cc];
#pragma unroll
      for (int dd = 0; dd < 16; ++dd)
        acc[dd] += xv * wch[dg * 16 + dd][cc];
    }
  }
  float* tgt = half ? tv : tk;
  for (int dd = 0; dd < 16; ++dd) {
    int d = dg * 16 + dd;
    tgt[((size_t)bh * 64 + m) * 64 + d] = acc[dd] + ldf(kv_b, obase + d, f32);
  }
}

// ---------------------------------------------------------------------------
// coarse attention, bf16 MFMA, bf16 in/out.
// ---------------------------------------------------------------------------
__global__ __launch_bounds__(256) void coarse_attn_mfma(
    const u16* __restrict__ q, const u16* __restrict__ k,
    const u16* __restrict__ v, u16* __restrict__ coarse) {
  const int bh = blockIdx.y;
  const int n0 = blockIdx.x * 64;
  const int t = threadIdx.x;
  const int w = t >> 6, lane = t & 63;
  const int quad = lane >> 4, c = lane & 15;

  __shared__ __align__(16) u16 Ks[64][72];     // K[m][d]
  __shared__ __align__(16) u16 Vt[64][72];     // V^T[d][m]
  __shared__ __align__(16) u16 Ps[4][16][72];  // per-wave P^T as [n][m]

  const int n = n0 + w * 16 + c;
  bf16x8 bq[2];
  {
    const u16* qr = q + ((size_t)bh * 4096 + n) * 64;
    bq[0] = *reinterpret_cast<const bf16x8*>(qr + quad * 8);
    bq[1] = *reinterpret_cast<const bf16x8*>(qr + 32 + quad * 8);
  }

  f32x4 po[4];
#pragma unroll
  for (int dt = 0; dt < 4; ++dt) po[dt] = (f32x4){0.f, 0.f, 0.f, 0.f};
  float sume = 0.f;

  for (int m0 = 0; m0 < 1024; m0 += 64) {
    __syncthreads();
    {
      // K rows: vectorized copy
      int row = t >> 2, col = (t & 3) * 16;
      const u16* gk = k + ((size_t)bh * 1024 + m0 + row) * 64 + col;
      *reinterpret_cast<uint4*>(&Ks[row][col])     = *reinterpret_cast<const uint4*>(gk);
      *reinterpret_cast<uint4*>(&Ks[row][col + 8]) = *reinterpret_cast<const uint4*>(gk + 8);
      // V transposed: scalar
      for (int i = t; i < 4096; i += 256) {
        int mm = i >> 6, dd = i & 63;
        Vt[dd][mm] = v[((size_t)bh * 1024 + m0 + mm) * 64 + dd];
      }
    }
    __syncthreads();

    f32x4 st[4];
#pragma unroll
    for (int mt = 0; mt < 4; ++mt) {
      f32x4 acc = (f32x4){0.f, 0.f, 0.f, 0.f};
#pragma unroll
      for (int s = 0; s < 2; ++s) {
        bf16x8 ak = *reinterpret_cast<const bf16x8*>(&Ks[mt * 16 + c][s * 32 + quad * 8]);
        acc = __builtin_amdgcn_mfma_f32_16x16x32_bf16(ak, bq[s], acc, 0, 0, 0);
      }
      st[mt] = acc;
    }

    float chunksum = 0.f;
#pragma unroll
    for (int mt = 0; mt < 4; ++mt) {
      float e0 = __expf(st[mt][0] * 0.125f);
      float e1 = __expf(st[mt][1] * 0.125f);
      float e2 = __expf(st[mt][2] * 0.125f);
      float e3 = __expf(st[mt][3] * 0.125f);
      chunksum += (e0 + e1) + (e2 + e3);
      ushort4 pw;
      pw.x = f2bs(e0); pw.y = f2bs(e1); pw.z = f2bs(e2); pw.w = f2bs(e3);
      *reinterpret_cast<ushort4*>(&Ps[w][c][mt * 16 + quad * 4]) = pw;
    }
    chunksum += __shfl_xor(chunksum, 16, 64);
    chunksum += __shfl_xor(chunksum, 32, 64);
    sume += chunksum;

#pragma unroll
    for (int s = 0; s < 2; ++s) {
      bf16x8 bp = *reinterpret_cast<const bf16x8*>(&Ps[w][c][s * 32 + quad * 8]);
#pragma unroll
      for (int dt = 0; dt < 4; ++dt) {
        bf16x8 av = *reinterpret_cast<const bf16x8*>(&Vt[dt * 16 + c][s * 32 + quad * 8]);
        po[dt] = __builtin_amdgcn_mfma_f32_16x16x32_bf16(av, bp, po[dt], 0, 0, 0);
      }
    }
  }

  float inv = 1.0f / sume;
  u16* orow = coarse + ((size_t)bh * 4096 + n) * 64;
#pragma unroll
  for (int dt = 0; dt < 4; ++dt) {
    ushort4 r;
    r.x = f2bs(po[dt][0] * inv); r.y = f2bs(po[dt][1] * inv);
    r.z = f2bs(po[dt][2] * inv); r.w = f2bs(po[dt][3] * inv);
    *reinterpret_cast<ushort4*>(&orow[dt * 16 + quad * 4]) = r;
  }
}

// fine attention + gate + combine -> xs fp32 [b][c][n]
__global__ __launch_bounds__(256) void fine_kernel(
    const u16* __restrict__ q, const float* __restrict__ tk,
    const float* __restrict__ tv, const u16* __restrict__ coarse,
    const void* __restrict__ gate_w, const void* __restrict__ gate_b,
    float* __restrict__ xsum, const int* __restrict__ dtf) {
  const int f32 = *dtf;
  const int bh = blockIdx.y, b = bh >> 3, h = bh & 7;
  const int n0 = blockIdx.x * 64;
  const int t = threadIdx.x, lane = t & 63, w = t >> 6;
  __shared__ float tks_t[64][64];
  __shared__ float tvs[64][64];
  __shared__ bf16  gwsh[128][64];
  __shared__ float qrow[4][64], wrow[4][64], crow[4][64], rrow[4][64];
  for (int i = t; i < 4096; i += 256) {
    int m = i >> 6, d = i & 63;
    tks_t[d][m] = tk[(size_t)bh * 4096 + i];
    tvs[m][d] = tv[(size_t)bh * 4096 + i];
  }
  for (int i = t; i < 8192; i += 256)
    gwsh[i & 127][i >> 7] = f32 ? __float2bfloat16(((const float*)gate_w)[i])
                                : ((const bf16*)gate_w)[i];
  float gb = ldf(gate_b, lane, f32);
  __syncthreads();

  for (int it = 0; it < 16; ++it) {
    int n = n0 + w + it * 4;
    float qv = bs2f(q[((size_t)bh * 4096 + n) * 64 + lane]);
    float cv = bs2f(coarse[((size_t)bh * 4096 + n) * 64 + lane]);
    qrow[w][lane] = qv;
    crow[w][lane] = cv;
    __syncthreads();
    float sm = 0.f;
#pragma unroll
    for (int d = 0; d < 64; ++d) sm += qrow[w][d] * tks_t[d][lane];
    sm *= 0.125f;
    float mx = sm;
    for (int off = 32; off; off >>= 1) mx = fmaxf(mx, __shfl_xor(mx, off, 64));
    float e = __expf(sm - mx);
    float se = e;
    for (int off = 32; off; off >>= 1) se += __shfl_xor(se, off, 64);
    wrow[w][lane] = e / se;
    __syncthreads();
    float r = 0.f;
#pragma unroll
    for (int m = 0; m < 64; ++m) r += wrow[w][m] * tvs[m][lane];
    rrow[w][lane] = r;
    __syncthreads();
    float g = gb;
#pragma unroll
    for (int c = 0; c < 64; ++c)
      g += crow[w][c] * b2f(gwsh[c][lane]) + rrow[w][c] * b2f(gwsh[64 + c][lane]);
    g = 1.0f / (1.0f + __expf(-g));
    float outv = g * r + (1.0f - g) * cv;
    xsum[((size_t)(b * 512 + h * 64 + lane)) * 4096 + n] = outv;
    __syncthreads();
  }
}

// depthwise 7x7 conv on v (bf16) -> vpe fp32
__global__ __launch_bounds__(256) void dwconv_kernel(
    const u16* __restrict__ v, const void* __restrict__ pe_w,
    const void* __restrict__ pe_b, float* __restrict__ vpe,
    const int* __restrict__ dtf) {
  const int f32 = *dtf;
  int bc = blockIdx.x;
  int b = bc >> 9, c = bc & 511;
  int h = c >> 6, d = c & 63;
  int t = threadIdx.x;
  __shared__ float img[1024];
  __shared__ float wts[49];
  for (int i = t; i < 1024; i += 256)
    img[i] = bs2f(v[((size_t)(b * 8 + h) * 1024 + i) * 64 + d]);
  if (t < 49) wts[t] = ldf(pe_w, c * 49 + t, f32);
  float bias = ldf(pe_b, c, f32);
  __syncthreads();
  for (int i = t; i < 1024; i += 256) {
    int y = i >> 5, xx = i & 31;
    float a = 0.f;
#pragma unroll
    for (int ky = 0; ky < 7; ++ky) {
      int yy = y + ky - 3;
      if ((unsigned)yy >= 32u) continue;
#pragma unroll
      for (int kx = 0; kx < 7; ++kx) {
        int xc = xx + kx - 3;
        if ((unsigned)xc >= 32u) continue;
        a += img[yy * 32 + xc] * wts[ky * 7 + kx];
      }
    }
    vpe[(size_t)bc * 1024 + i] = a + bias;
  }
}

// bilinear 2x upsample of vpe added into xs fp32
__global__ __launch_bounds__(256) void resize_add_kernel(
    const float* __restrict__ vpe, float* __restrict__ xsum) {
  size_t idx = (size_t)blockIdx.x * 256 + threadIdx.x;
  int nx = idx & 63;
  int rest = (int)(idx >> 6);
  int ny = rest & 63;
  int bc = rest >> 6;
  int jy = ny >> 1, jx = nx >> 1;
  int y0, y1, x0, x1; float wy0, wy1, wx0, wx1;
  if ((ny & 1) == 0) { y0 = (jy > 0) ? jy - 1 : 0; y1 = jy; wy0 = 0.25f; wy1 = 0.75f; }
  else               { y0 = jy; y1 = (jy < 31) ? jy + 1 : 31; wy0 = 0.75f; wy1 = 0.25f; }
  if ((nx & 1) == 0) { x0 = (jx > 0) ? jx - 1 : 0; x1 = jx; wx0 = 0.25f; wx1 = 0.75f; }
  else               { x0 = jx; x1 = (jx < 31) ? jx + 1 : 31; wx0 = 0.75f; wx1 = 0.25f; }
  const float* p = vpe + (size_t)bc * 1024;
  float val = wy0 * (wx0 * p[y0 * 32 + x0] + wx1 * p[y0 * 32 + x1]) +
              wy1 * (wx0 * p[y1 * 32 + x0] + wx1 * p[y1 * 32 + x1]);
  xsum[idx] += val;
}

extern "C" void kernel_launch(void* const* d_in, const int* in_sizes, int n_in,
                              void* d_out, int out_size, void* d_ws, size_t ws_size,
                              hipStream_t stream) {
  const void* x    = d_in[0];
  const void* up   = d_in[1];
  const void* gum  = d_in[2];
  const void* q_w  = d_in[3];
  const void* q_b  = d_in[4];
  const void* kv_w = d_in[5];
  const void* kv_b = d_in[6];
  const void* p_w  = d_in[7];
  const void* p_b  = d_in[8];
  const void* pe_w = d_in[9];
  const void* pe_b = d_in[10];
  const void* g_w  = d_in[11];
  const void* g_b  = d_in[12];

  float* ws    = (float*)d_ws;
  int*   dtf   = (int*)ws;                  // 16
  float* qsumP = ws + 16;                   // 16384
  float* heat  = qsumP + 16384;             // 2048
  int*   posb  = (int*)(heat + 2048);       // 1024
  float* tk    = heat + 2048 + 1024;        // 65536
  float* tv    = tk + 65536;                // 65536
  u16*   qb    = (u16*)(tv + 65536);        // 4M u16
  u16*   kb    = qb + 4194304;              // 1M
  u16*   vb    = kb + 1048576;              // 1M
  u16*   xT    = vb + 1048576;              // 4M
  u16*   upT   = xT + 4194304;              // 1M
  u16*   co    = upT + 1048576;             // 4M
  u16*   xsT   = co + 4194304;              // 4M
  float* xs    = (float*)(xsT + 4194304);   // 4M floats
  float* vpe   = xs + 4194304;              // 1M floats  (~58.6 MB total)

  dim3 blk(256);
  hipMemsetAsync(dtf, 0, 4, stream);
  detect_dtype<<<dim3(16384), blk, 0, stream>>>((const u16*)x, dtf);
  transpose_bf16<0><<<dim3(64, 8, 2), blk, 0, stream>>>(x, xT, 4096, dtf);
  transpose_bf16<0><<<dim3(16, 8, 2), blk, 0, stream>>>(up, upT, 1024, dtf);
  heat_kernel<<<dim3(2048), blk, 0, stream>>>(x, heat, dtf);
  gemm_mfma<0><<<dim3(64, 8, 2), blk, 0, stream>>>(xT, q_w, q_b, qb, nullptr, nullptr, 4096, dtf);
  gemm_mfma<1><<<dim3(16, 16, 2), blk, 0, stream>>>(upT, kv_w, kv_b, kb, vb, nullptr, 1024, dtf);
  qsum_partial<<<dim3(16, 16), blk, 0, stream>>>(qb, qsumP);
  topk_kernel<<<dim3(16), blk, 0, stream>>>(qsumP, kb, heat, gum, posb, dtf);
  gather_kv<<<dim3(16, 2), blk, 0, stream>>>(xT, kv_w, kv_b, posb, tk, tv, dtf);
  coarse_attn_mfma<<<dim3(64, 16), blk, 0, stream>>>(qb, kb, vb, co);
  dwconv_kernel<<<dim3(1024), blk, 0, stream>>>(vb, pe_w, pe_b, vpe, dtf);
  fine_kernel<<<dim3(64, 16), blk, 0, stream>>>(qb, tk, tv, co, g_w, g_b, xs, dtf);
  resize_add_kernel<<<dim3(16384), blk, 0, stream>>>(vpe, xs);
  transpose_bf16<1><<<dim3(64, 8, 2), blk, 0, stream>>>(xs, xsT, 4096, dtf);
  gemm_mfma<3><<<dim3(64, 8, 2), blk, 0, stream>>>(xsT, p_w, p_b, nullptr, nullptr, d_out, 4096, dtf);
}

// Round 5
// 436.638 us; speedup vs baseline: 3.8608x; 1.4235x over previous
//
#include <hip/hip_runtime.h>
#include <hip/hip_bf16.h>
#include <cstdint>

typedef __hip_bfloat16 bf16;
typedef unsigned short u16;
typedef __attribute__((ext_vector_type(8))) short bf16x8;
typedef __attribute__((ext_vector_type(4))) float f32x4;

static __device__ __forceinline__ float b2f(bf16 v) { return __bfloat162float(v); }
static __device__ __forceinline__ float bs2f(u16 s) {
  unsigned int u = ((unsigned int)s) << 16;
  float f;
  __builtin_memcpy(&f, &u, 4);
  return f;
}
static __device__ __forceinline__ u16 f2bs(float f) {
  bf16 h = __float2bfloat16(f);
  u16 s;
  __builtin_memcpy(&s, &h, 2);
  return s;
}
// dual-dtype load: f32!=0 -> buffer is float32, else packed bf16
static __device__ __forceinline__ float ldf(const void* p, size_t i, int f32) {
  return f32 ? ((const float*)p)[i] : bs2f(((const u16*)p)[i]);
}

// ---------------------------------------------------------------------------
// dtype detection on x (first 8 MB viewed as u16): bf16-exp==0xFF impossible
// for N(0,1) bf16 data. uint4 loads; one atomic per wave max.
// ---------------------------------------------------------------------------
__global__ __launch_bounds__(256) void detect_dtype(const uint4* __restrict__ xs,
                                                    int* __restrict__ flag) {
  int i = blockIdx.x * 256 + threadIdx.x;
  uint4 v = xs[i];
  bool hit = false;
#pragma unroll
  for (int j = 0; j < 4; ++j) {
    unsigned w = (j == 0) ? v.x : (j == 1) ? v.y : (j == 2) ? v.z : v.w;
    if ((w & 0x7F80u) == 0x7F80u) hit = true;
    if ((w & 0x7F800000u) == 0x7F800000u) hit = true;
  }
  unsigned long long mask = __ballot(hit);
  if (mask != 0ull && (threadIdx.x & 63) == 0) atomicOr(flag, 1);
}

// ---------------------------------------------------------------------------
// transpose [b][c=512][N] (dual dtype) -> [b][N][512] bf16; grid (N/64,8,B)
// ---------------------------------------------------------------------------
__global__ __launch_bounds__(256) void transpose_bf16(
    const void* __restrict__ src, u16* __restrict__ dst, int N,
    const int* __restrict__ dtf) {
  const int f32 = *dtf;
  const int b = blockIdx.z, n0 = blockIdx.x * 64, c0 = blockIdx.y * 64;
  const int t = threadIdx.x;
  __shared__ __align__(16) u16 tile[64][72];
#pragma unroll
  for (int j = 0; j < 2; ++j) {
    int cc = (t >> 3) + j * 32;
    int nn = (t & 7) * 8;
    u16 tmp[8];
    if (f32) {
      const float* s4 = (const float*)src + ((size_t)(b * 512 + c0 + cc)) * N + n0 + nn;
#pragma unroll
      for (int u = 0; u < 8; ++u) tmp[u] = f2bs(s4[u]);
    } else {
      *reinterpret_cast<uint4*>(tmp) = *reinterpret_cast<const uint4*>(
          (const u16*)src + ((size_t)(b * 512 + c0 + cc)) * N + n0 + nn);
    }
    *reinterpret_cast<uint4*>(&tile[cc][nn]) = *reinterpret_cast<const uint4*>(tmp);
  }
  __syncthreads();
#pragma unroll
  for (int j = 0; j < 2; ++j) {
    int nn = (t >> 3) + j * 32;
    int cc0 = (t & 7) * 8;
    u16 tmp[8];
#pragma unroll
    for (int u = 0; u < 8; ++u) tmp[u] = tile[cc0 + u][nn];
    *reinterpret_cast<uint4*>(&dst[((size_t)b * N + n0 + nn) * 512 + c0 + cc0]) =
        *reinterpret_cast<const uint4*>(tmp);
  }
}

// ---------------------------------------------------------------------------
// MFMA conv1x1 GEMM (see round-4 header). K=512, tile 64x64, 4 waves.
// ---------------------------------------------------------------------------
template<int MODE>
__global__ __launch_bounds__(256) void gemm_mfma(
    const u16* __restrict__ A, const void* __restrict__ W,
    const void* __restrict__ bias, u16* __restrict__ o0, u16* __restrict__ o1,
    void* __restrict__ ob, int M, const int* __restrict__ dtf) {
  const int f32 = *dtf;
  const int b = blockIdx.z, m0 = blockIdx.x * 64, oo0 = blockIdx.y * 64;
  const int t = threadIdx.x, w = t >> 6, lane = t & 63;
  const int quad = lane >> 4, c = lane & 15;
  __shared__ __align__(16) u16 As[64][72];
  __shared__ __align__(16) u16 Ws[64][72];
  f32x4 acc[4];
#pragma unroll
  for (int ot = 0; ot < 4; ++ot) acc[ot] = (f32x4){0.f, 0.f, 0.f, 0.f};
  const u16* Ab = A + (size_t)b * M * 512;
  const int srow = t >> 2, scol = (t & 3) * 16;

  for (int k0 = 0; k0 < 512; k0 += 64) {
    __syncthreads();
    {
      const u16* ga = Ab + (size_t)(m0 + srow) * 512 + k0 + scol;
      *reinterpret_cast<uint4*>(&As[srow][scol])     = *reinterpret_cast<const uint4*>(ga);
      *reinterpret_cast<uint4*>(&As[srow][scol + 8]) = *reinterpret_cast<const uint4*>(ga + 8);
      if (f32) {
        const float* gw = (const float*)W + (size_t)(oo0 + srow) * 512 + k0 + scol;
#pragma unroll
        for (int e = 0; e < 16; ++e) Ws[srow][scol + e] = f2bs(gw[e]);
      } else {
        const u16* gw = (const u16*)W + (size_t)(oo0 + srow) * 512 + k0 + scol;
        *reinterpret_cast<uint4*>(&Ws[srow][scol])     = *reinterpret_cast<const uint4*>(gw);
        *reinterpret_cast<uint4*>(&Ws[srow][scol + 8]) = *reinterpret_cast<const uint4*>(gw + 8);
      }
    }
    __syncthreads();
#pragma unroll
    for (int ks = 0; ks < 2; ++ks) {
      bf16x8 av = *reinterpret_cast<const bf16x8*>(&As[w * 16 + c][ks * 32 + quad * 8]);
#pragma unroll
      for (int ot = 0; ot < 4; ++ot) {
        bf16x8 wv = *reinterpret_cast<const bf16x8*>(&Ws[ot * 16 + c][ks * 32 + quad * 8]);
        if (MODE == 3)
          acc[ot] = __builtin_amdgcn_mfma_f32_16x16x32_bf16(wv, av, acc[ot], 0, 0, 0);
        else
          acc[ot] = __builtin_amdgcn_mfma_f32_16x16x32_bf16(av, wv, acc[ot], 0, 0, 0);
      }
    }
  }

  if (MODE == 0) {
#pragma unroll
    for (int ot = 0; ot < 4; ++ot) {
      int o = oo0 + ot * 16 + c;
      float bv = ldf(bias, o, f32);
      int h = o >> 6, d = o & 63;
#pragma unroll
      for (int r = 0; r < 4; ++r) {
        int m = m0 + w * 16 + quad * 4 + r;
        o0[((size_t)(b * 8 + h) * M + m) * 64 + d] = f2bs(acc[ot][r] + bv);
      }
    }
  } else if (MODE == 1) {
#pragma unroll
    for (int ot = 0; ot < 4; ++ot) {
      int o = oo0 + ot * 16 + c;
      float bv = ldf(bias, o, f32);
      int hh = o >> 7, jj = o & 127;
      u16* tgt = (jj < 64) ? o0 : o1;
#pragma unroll
      for (int r = 0; r < 4; ++r) {
        int m = m0 + w * 16 + quad * 4 + r;
        tgt[((size_t)(b * 8 + hh) * M + m) * 64 + (jj & 63)] = f2bs(acc[ot][r] + bv);
      }
    }
  } else {
#pragma unroll
    for (int ot = 0; ot < 4; ++ot) {
#pragma unroll
      for (int r = 0; r < 4; ++r) {
        int o = oo0 + ot * 16 + quad * 4 + r;
        float val = acc[ot][r] + ldf(bias, o, f32);
        int m = m0 + w * 16 + c;
        size_t oi_ = ((size_t)(b * 512 + o)) * M + m;
        if (f32) ((float*)ob)[oi_] = val;
        else     ((u16*)ob)[oi_] = f2bs(val);
      }
    }
  }
}

// heat[b,mu] = mean over C and 2x2 spatial of x, computed from coalesced xT
__global__ __launch_bounds__(256) void heat_kernel(const u16* __restrict__ xT,
                                                   float* __restrict__ heat) {
  int bm = blockIdx.x;
  int b = bm >> 10, mu = bm & 1023;
  int hu = mu >> 5, wu = mu & 31;
  int t = threadIdx.x;
  int row = t >> 6, seg = t & 63;  // 4 spatial rows x 64 uint4 segments
  int y = hu * 2 + (row >> 1), xx = wu * 2 + (row & 1);
  const uint4* p = reinterpret_cast<const uint4*>(
      xT + ((size_t)b * 4096 + y * 64 + xx) * 512);
  uint4 v = p[seg];
  float s = 0.f;
#pragma unroll
  for (int j = 0; j < 4; ++j) {
    unsigned w = (j == 0) ? v.x : (j == 1) ? v.y : (j == 2) ? v.z : v.w;
    s += bs2f((u16)(w & 0xFFFF)) + bs2f((u16)(w >> 16));
  }
  __shared__ float r[256];
  r[t] = s; __syncthreads();
  for (int off = 128; off; off >>= 1) { if (t < off) r[t] += r[t + off]; __syncthreads(); }
  if (t == 0) heat[bm] = r[0] * (1.0f / 2048.0f);
}

// stage 1 of qsum: partial[bh][chunk][d] = sum over 256 n-rows
__global__ __launch_bounds__(256) void qsum_partial(const u16* __restrict__ q,
                                                    float* __restrict__ qsumP) {
  int bh = blockIdx.x, ch = blockIdx.y, t = threadIdx.x;
  int d = t & 63, g = t >> 6;
  int n0 = ch * 256 + g * 64;
  float s = 0.f;
  for (int r = 0; r < 64; ++r)
    s += bs2f(q[((size_t)bh * 4096 + n0 + r) * 64 + d]);
  __shared__ float r[256];
  r[t] = s; __syncthreads();
  if (t < 64) qsumP[(size_t)(bh * 16 + ch) * 64 + t] = r[t] + r[t + 64] + r[t + 128] + r[t + 192];
}

// scores -> top-16 coarse cells -> 64 full-res positions into posb
__global__ __launch_bounds__(256) void topk_kernel(
    const float* __restrict__ qsumP, const u16* __restrict__ k,
    const float* __restrict__ heat, const void* __restrict__ gumbel,
    int* __restrict__ posb, const int* __restrict__ dtf) {
  const int f32 = *dtf;
  int bh = blockIdx.x, b = bh >> 3, t = threadIdx.x;
  __shared__ float qs[64];
  __shared__ float s[1024];
  __shared__ float rv[256];
  __shared__ int   ri[256];
  if (t < 64) {
    float acc = 0.f;
    for (int ch = 0; ch < 16; ++ch) acc += qsumP[(size_t)(bh * 16 + ch) * 64 + t];
    qs[t] = acc;
  }
  __syncthreads();
  for (int j = 0; j < 4; ++j) {
    int m = t + j * 256;
    const u16* kr = k + ((size_t)bh * 1024 + m) * 64;
    float dot = 0.f;
    for (int d = 0; d < 64; ++d) dot += qs[d] * bs2f(kr[d]);
    s[m] = dot * (0.125f / 4096.0f) * heat[b * 1024 + m] + ldf(gumbel, (size_t)bh * 1024 + m, f32);
  }
  __syncthreads();
  for (int it = 0; it < 16; ++it) {
    float bv = -1e30f; int bi = 0x7fffffff;
    for (int j = 0; j < 4; ++j) {
      int m = t + j * 256; float vv = s[m];
      if (vv > bv || (vv == bv && m < bi)) { bv = vv; bi = m; }
    }
    rv[t] = bv; ri[t] = bi; __syncthreads();
    for (int off = 128; off; off >>= 1) {
      if (t < off) {
        if (rv[t + off] > rv[t] || (rv[t + off] == rv[t] && ri[t + off] < ri[t])) {
          rv[t] = rv[t + off]; ri[t] = ri[t + off];
        }
      }
      __syncthreads();
    }
    if (t == 0) {
      int mi = ri[0]; s[mi] = -1e30f;
      int hy = (mi >> 5) * 2, wx = (mi & 31) * 2;
      posb[bh * 64 + it]      = hy * 64 + wx;
      posb[bh * 64 + 16 + it] = hy * 64 + wx + 1;
      posb[bh * 64 + 32 + it] = (hy + 1) * 64 + wx;
      posb[bh * 64 + 48 + it] = (hy + 1) * 64 + wx + 1;
    }
    __syncthreads();
  }
}

// tkb[bh][m][d] (bf16), tvTb[bh][d][m] (bf16) from gathered conv1x1
__global__ __launch_bounds__(256) void gather_kv(
    const u16* __restrict__ xT, const void* __restrict__ kv_w,
    const void* __restrict__ kv_b, const int* __restrict__ posb,
    u16* __restrict__ tkb, u16* __restrict__ tvTb,
    const int* __restrict__ dtf) {
  const int f32 = *dtf;
  const int bh = blockIdx.x, b = bh >> 3, h = bh & 7;
  const int half = blockIdx.y;
  const int t = threadIdx.x;
  const int m = t & 63, dg = t >> 6;
  __shared__ int pos[64];
  __shared__ float xcol[64][33];   // [m][cc]
  __shared__ float wch[64][32];    // [d][cc]
  if (t < 64) pos[t] = posb[bh * 64 + t];
  __syncthreads();
  float acc[16];
#pragma unroll
  for (int i = 0; i < 16; ++i) acc[i] = 0.f;
  const int obase = h * 128 + half * 64;
  for (int c0 = 0; c0 < 512; c0 += 32) {
    __syncthreads();
    for (int i = t; i < 2048; i += 256) {
      int mm = i >> 5, cc = i & 31;
      xcol[mm][cc] = bs2f(xT[((size_t)b * 4096 + pos[mm]) * 512 + c0 + cc]);
    }
    for (int i = t; i < 2048; i += 256) {
      int d = i >> 5, cc = i & 31;
      wch[d][cc] = ldf(kv_w, (size_t)(obase + d) * 512 + c0 + cc, f32);
    }
    __syncthreads();
    for (int cc = 0; cc < 32; ++cc) {
      float xv = xcol[m][cc];
#pragma unroll
      for (int dd = 0; dd < 16; ++dd)
        acc[dd] += xv * wch[dg * 16 + dd][cc];
    }
  }
  for (int dd = 0; dd < 16; ++dd) {
    int d = dg * 16 + dd;
    u16 val = f2bs(acc[dd] + ldf(kv_b, obase + d, f32));
    if (half) tvTb[((size_t)bh * 64 + d) * 64 + m] = val;
    else      tkb[((size_t)bh * 64 + m) * 64 + d] = val;
  }
}

// ---------------------------------------------------------------------------
// coarse attention, bf16 MFMA (validated round 3/4 structure).
// ---------------------------------------------------------------------------
__global__ __launch_bounds__(256) void coarse_attn_mfma(
    const u16* __restrict__ q, const u16* __restrict__ k,
    const u16* __restrict__ v, u16* __restrict__ coarse) {
  const int bh = blockIdx.y;
  const int n0 = blockIdx.x * 64;
  const int t = threadIdx.x;
  const int w = t >> 6, lane = t & 63;
  const int quad = lane >> 4, c = lane & 15;

  __shared__ __align__(16) u16 Ks[64][72];
  __shared__ __align__(16) u16 Vt[64][72];
  __shared__ __align__(16) u16 Ps[4][16][72];

  const int n = n0 + w * 16 + c;
  bf16x8 bq[2];
  {
    const u16* qr = q + ((size_t)bh * 4096 + n) * 64;
    bq[0] = *reinterpret_cast<const bf16x8*>(qr + quad * 8);
    bq[1] = *reinterpret_cast<const bf16x8*>(qr + 32 + quad * 8);
  }

  f32x4 po[4];
#pragma unroll
  for (int dt = 0; dt < 4; ++dt) po[dt] = (f32x4){0.f, 0.f, 0.f, 0.f};
  float sume = 0.f;

  for (int m0 = 0; m0 < 1024; m0 += 64) {
    __syncthreads();
    {
      int row = t >> 2, col = (t & 3) * 16;
      const u16* gk = k + ((size_t)bh * 1024 + m0 + row) * 64 + col;
      *reinterpret_cast<uint4*>(&Ks[row][col])     = *reinterpret_cast<const uint4*>(gk);
      *reinterpret_cast<uint4*>(&Ks[row][col + 8]) = *reinterpret_cast<const uint4*>(gk + 8);
      for (int i = t; i < 4096; i += 256) {
        int mm = i >> 6, dd = i & 63;
        Vt[dd][mm] = v[((size_t)bh * 1024 + m0 + mm) * 64 + dd];
      }
    }
    __syncthreads();

    f32x4 st[4];
#pragma unroll
    for (int mt = 0; mt < 4; ++mt) {
      f32x4 acc = (f32x4){0.f, 0.f, 0.f, 0.f};
#pragma unroll
      for (int s = 0; s < 2; ++s) {
        bf16x8 ak = *reinterpret_cast<const bf16x8*>(&Ks[mt * 16 + c][s * 32 + quad * 8]);
        acc = __builtin_amdgcn_mfma_f32_16x16x32_bf16(ak, bq[s], acc, 0, 0, 0);
      }
      st[mt] = acc;
    }

    float chunksum = 0.f;
#pragma unroll
    for (int mt = 0; mt < 4; ++mt) {
      float e0 = __expf(st[mt][0] * 0.125f);
      float e1 = __expf(st[mt][1] * 0.125f);
      float e2 = __expf(st[mt][2] * 0.125f);
      float e3 = __expf(st[mt][3] * 0.125f);
      chunksum += (e0 + e1) + (e2 + e3);
      ushort4 pw;
      pw.x = f2bs(e0); pw.y = f2bs(e1); pw.z = f2bs(e2); pw.w = f2bs(e3);
      *reinterpret_cast<ushort4*>(&Ps[w][c][mt * 16 + quad * 4]) = pw;
    }
    chunksum += __shfl_xor(chunksum, 16, 64);
    chunksum += __shfl_xor(chunksum, 32, 64);
    sume += chunksum;

#pragma unroll
    for (int s = 0; s < 2; ++s) {
      bf16x8 bp = *reinterpret_cast<const bf16x8*>(&Ps[w][c][s * 32 + quad * 8]);
#pragma unroll
      for (int dt = 0; dt < 4; ++dt) {
        bf16x8 av = *reinterpret_cast<const bf16x8*>(&Vt[dt * 16 + c][s * 32 + quad * 8]);
        po[dt] = __builtin_amdgcn_mfma_f32_16x16x32_bf16(av, bp, po[dt], 0, 0, 0);
      }
    }
  }

  float inv = 1.0f / sume;
  u16* orow = coarse + ((size_t)bh * 4096 + n) * 64;
#pragma unroll
  for (int dt = 0; dt < 4; ++dt) {
    ushort4 r;
    r.x = f2bs(po[dt][0] * inv); r.y = f2bs(po[dt][1] * inv);
    r.z = f2bs(po[dt][2] * inv); r.w = f2bs(po[dt][3] * inv);
    *reinterpret_cast<ushort4*>(&orow[dt * 16 + quad * 4]) = r;
  }
}

// depthwise 7x7 conv on v (bf16) -> vpe bf16
__global__ __launch_bounds__(256) void dwconv_kernel(
    const u16* __restrict__ v, const void* __restrict__ pe_w,
    const void* __restrict__ pe_b, u16* __restrict__ vpe,
    const int* __restrict__ dtf) {
  const int f32 = *dtf;
  int bc = blockIdx.x;
  int b = bc >> 9, c = bc & 511;
  int h = c >> 6, d = c & 63;
  int t = threadIdx.x;
  __shared__ float img[1024];
  __shared__ float wts[49];
  for (int i = t; i < 1024; i += 256)
    img[i] = bs2f(v[((size_t)(b * 8 + h) * 1024 + i) * 64 + d]);
  if (t < 49) wts[t] = ldf(pe_w, c * 49 + t, f32);
  float bias = ldf(pe_b, c, f32);
  __syncthreads();
  for (int i = t; i < 1024; i += 256) {
    int y = i >> 5, xx = i & 31;
    float a = 0.f;
#pragma unroll
    for (int ky = 0; ky < 7; ++ky) {
      int yy = y + ky - 3;
      if ((unsigned)yy >= 32u) continue;
#pragma unroll
      for (int kx = 0; kx < 7; ++kx) {
        int xc = xx + kx - 3;
        if ((unsigned)xc >= 32u) continue;
        a += img[yy * 32 + xc] * wts[ky * 7 + kx];
      }
    }
    vpe[(size_t)bc * 1024 + i] = f2bs(a + bias);
  }
}

// ---------------------------------------------------------------------------
// fused fine attention + gate MFMA + combine + bilinear vpe add -> xsT bf16.
// grid (64 n-tiles == spatial row y, 16 bh); 4 waves; wave owns 16 n.
// ---------------------------------------------------------------------------
__global__ __launch_bounds__(256) void fine_mfma(
    const u16* __restrict__ q, const u16* __restrict__ tkb,
    const u16* __restrict__ tvTb, const u16* __restrict__ co,
    const void* __restrict__ gate_w, const void* __restrict__ gate_b,
    const u16* __restrict__ vpe, u16* __restrict__ xsT,
    const int* __restrict__ dtf) {
  const int f32 = *dtf;
  const int bh = blockIdx.y, b = bh >> 3, h = bh & 7;
  const int y = blockIdx.x;
  const int n0 = y * 64;
  const int t = threadIdx.x, w = t >> 6, lane = t & 63;
  const int quad = lane >> 4, c = lane & 15;

  __shared__ __align__(16) u16 gw[64][136];      // gate_w [o][128]
  __shared__ __align__(16) u16 fus[4][16][136];  // per-wave [n][k]
  __shared__ __align__(16) u16 vl[64][66];       // vpe [ch][2 rows x 33]
  __shared__ __align__(16) u16 outb[4][16][72];  // [n][ch]
  __shared__ float gbl[64];

  // scalar bilinear y-weights for this block's spatial row
  int jy = y >> 1, y0, y1; float wy0, wy1;
  if ((y & 1) == 0) { y0 = (jy > 0) ? jy - 1 : 0; y1 = jy; wy0 = 0.25f; wy1 = 0.75f; }
  else              { y0 = jy; y1 = (jy < 31) ? jy + 1 : 31; wy0 = 0.75f; wy1 = 0.25f; }

  // staging
  for (int i = t; i < 8192; i += 256) {
    gw[i >> 7][i & 127] = f32 ? f2bs(((const float*)gate_w)[i]) : ((const u16*)gate_w)[i];
  }
  for (int i = t; i < 4096; i += 256) {
    int ch = i >> 6, r = (i >> 5) & 1, xx = i & 31;
    int yy = r ? y1 : y0;
    vl[ch][r * 33 + xx] = vpe[((size_t)(b * 512 + h * 64 + ch)) * 1024 + yy * 32 + xx];
  }
  if (t < 64) gbl[t] = ldf(gate_b, t, f32);

  const int n = n0 + w * 16 + c;
  bf16x8 bq[2];
  {
    const u16* qr = q + ((size_t)bh * 4096 + n) * 64;
    bq[0] = *reinterpret_cast<const bf16x8*>(qr + quad * 8);
    bq[1] = *reinterpret_cast<const bf16x8*>(qr + 32 + quad * 8);
  }
  __syncthreads();

  // phase 1: S^T = TK . Q^T  (A-frags from global tkb, L2-hot)
  f32x4 st[4];
#pragma unroll
  for (int mt = 0; mt < 4; ++mt) {
    f32x4 acc = (f32x4){0.f, 0.f, 0.f, 0.f};
#pragma unroll
    for (int s = 0; s < 2; ++s) {
      bf16x8 ak = *reinterpret_cast<const bf16x8*>(
          &tkb[((size_t)bh * 64 + mt * 16 + c) * 64 + s * 32 + quad * 8]);
      acc = __builtin_amdgcn_mfma_f32_16x16x32_bf16(ak, bq[s], acc, 0, 0, 0);
    }
    st[mt] = acc;
  }
  // exp + write P^T into fus[n][m] + col-sum
  float sume = 0.f;
#pragma unroll
  for (int mt = 0; mt < 4; ++mt) {
    float e0 = __expf(st[mt][0] * 0.125f);
    float e1 = __expf(st[mt][1] * 0.125f);
    float e2 = __expf(st[mt][2] * 0.125f);
    float e3 = __expf(st[mt][3] * 0.125f);
    sume += (e0 + e1) + (e2 + e3);
    ushort4 pw;
    pw.x = f2bs(e0); pw.y = f2bs(e1); pw.z = f2bs(e2); pw.w = f2bs(e3);
    *reinterpret_cast<ushort4*>(&fus[w][c][mt * 16 + quad * 4]) = pw;
  }
  sume += __shfl_xor(sume, 16, 64);
  sume += __shfl_xor(sume, 32, 64);
  float inv = 1.0f / sume;
  __syncthreads();

  // phase 2: O^T = TV^T . P^T
  f32x4 po[4];
#pragma unroll
  for (int dt = 0; dt < 4; ++dt) po[dt] = (f32x4){0.f, 0.f, 0.f, 0.f};
#pragma unroll
  for (int s = 0; s < 2; ++s) {
    bf16x8 bp = *reinterpret_cast<const bf16x8*>(&fus[w][c][s * 32 + quad * 8]);
#pragma unroll
    for (int dt = 0; dt < 4; ++dt) {
      bf16x8 av = *reinterpret_cast<const bf16x8*>(
          &tvTb[((size_t)bh * 64 + dt * 16 + c) * 64 + s * 32 + quad * 8]);
      po[dt] = __builtin_amdgcn_mfma_f32_16x16x32_bf16(av, bp, po[dt], 0, 0, 0);
    }
  }
  __syncthreads();

  // phase 3: build fusion [coarse | refined] in fus[n][k]
  {
    const u16* crow = co + ((size_t)bh * 4096 + n) * 64 + quad * 16;
    *reinterpret_cast<uint4*>(&fus[w][c][quad * 16])     = *reinterpret_cast<const uint4*>(crow);
    *reinterpret_cast<uint4*>(&fus[w][c][quad * 16 + 8]) = *reinterpret_cast<const uint4*>(crow + 8);
  }
#pragma unroll
  for (int dt = 0; dt < 4; ++dt) {
    ushort4 rw;
    rw.x = f2bs(po[dt][0] * inv); rw.y = f2bs(po[dt][1] * inv);
    rw.z = f2bs(po[dt][2] * inv); rw.w = f2bs(po[dt][3] * inv);
    *reinterpret_cast<ushort4*>(&fus[w][c][64 + dt * 16 + quad * 4]) = rw;
  }
  __syncthreads();

  // phase 4: gate MFMA, K=128
  f32x4 ga[4];
#pragma unroll
  for (int ot = 0; ot < 4; ++ot) ga[ot] = (f32x4){0.f, 0.f, 0.f, 0.f};
#pragma unroll
  for (int s = 0; s < 4; ++s) {
    bf16x8 bf = *reinterpret_cast<const bf16x8*>(&fus[w][c][s * 32 + quad * 8]);
#pragma unroll
    for (int ot = 0; ot < 4; ++ot) {
      bf16x8 ag = *reinterpret_cast<const bf16x8*>(&gw[ot * 16 + c][s * 32 + quad * 8]);
      ga[ot] = __builtin_amdgcn_mfma_f32_16x16x32_bf16(ag, bf, ga[ot], 0, 0, 0);
    }
  }

  // phase 5: combine + bilinear vpe add -> outb[n][ch]
  const int x = w * 16 + c;
  int jx = x >> 1, x0, x1; float wx0, wx1;
  if ((x & 1) == 0) { x0 = (jx > 0) ? jx - 1 : 0; x1 = jx; wx0 = 0.25f; wx1 = 0.75f; }
  else              { x0 = jx; x1 = (jx < 31) ? jx + 1 : 31; wx0 = 0.75f; wx1 = 0.25f; }
#pragma unroll
  for (int dt = 0; dt < 4; ++dt) {
    ushort4 ow;
    u16 tmp[4];
#pragma unroll
    for (int r = 0; r < 4; ++r) {
      int row = dt * 16 + quad * 4 + r;
      float ref = po[dt][r] * inv;
      float coar = bs2f(fus[w][c][row]);
      float g = 1.0f / (1.0f + __expf(-(ga[dt][r] + gbl[row])));
      float vv = wy0 * (wx0 * bs2f(vl[row][x0]) + wx1 * bs2f(vl[row][x1])) +
                 wy1 * (wx0 * bs2f(vl[row][33 + x0]) + wx1 * bs2f(vl[row][33 + x1]));
      tmp[r] = f2bs(g * ref + (1.0f - g) * coar + vv);
    }
    ow.x = tmp[0]; ow.y = tmp[1]; ow.z = tmp[2]; ow.w = tmp[3];
    *reinterpret_cast<ushort4*>(&outb[w][c][dt * 16 + quad * 4]) = ow;
  }
  __syncthreads();

  // store: n-major rows to xsT[b][n][512] at channel block h*64
  {
    int nl = lane >> 2, cs = (lane & 3) * 16;
    u16* dst = xsT + ((size_t)b * 4096 + n0 + w * 16 + nl) * 512 + h * 64 + cs;
    *reinterpret_cast<uint4*>(dst)     = *reinterpret_cast<const uint4*>(&outb[w][nl][cs]);
    *reinterpret_cast<uint4*>(dst + 8) = *reinterpret_cast<const uint4*>(&outb[w][nl][cs + 8]);
  }
}

extern "C" void kernel_launch(void* const* d_in, const int* in_sizes, int n_in,
                              void* d_out, int out_size, void* d_ws, size_t ws_size,
                              hipStream_t stream) {
  const void* x    = d_in[0];
  const void* up   = d_in[1];
  const void* gum  = d_in[2];
  const void* q_w  = d_in[3];
  const void* q_b  = d_in[4];
  const void* kv_w = d_in[5];
  const void* kv_b = d_in[6];
  const void* p_w  = d_in[7];
  const void* p_b  = d_in[8];
  const void* pe_w = d_in[9];
  const void* pe_b = d_in[10];
  const void* g_w  = d_in[11];
  const void* g_b  = d_in[12];

  float* ws    = (float*)d_ws;
  int*   dtf   = (int*)ws;                   // 16
  float* qsumP = ws + 16;                    // 16384
  float* heat  = qsumP + 16384;              // 2048
  int*   posb  = (int*)(heat + 2048);        // 1024
  u16*   tkb   = (u16*)(posb + 1024);        // 65536
  u16*   tvTb  = tkb + 65536;                // 65536
  u16*   qb    = tvTb + 65536;               // 4M
  u16*   kb    = qb + 4194304;               // 1M
  u16*   vb    = kb + 1048576;               // 1M
  u16*   xT    = vb + 1048576;               // 4M
  u16*   upT   = xT + 4194304;               // 1M
  u16*   co    = upT + 1048576;              // 4M
  u16*   xsT   = co + 4194304;               // 4M
  u16*   vpe   = xsT + 4194304;              // 1M   (~34 MB total)

  dim3 blk(256);
  hipMemsetAsync(dtf, 0, 4, stream);
  detect_dtype<<<dim3(2048), blk, 0, stream>>>((const uint4*)x, dtf);
  transpose_bf16<<<dim3(64, 8, 2), blk, 0, stream>>>(x, xT, 4096, dtf);
  transpose_bf16<<<dim3(16, 8, 2), blk, 0, stream>>>(up, upT, 1024, dtf);
  heat_kernel<<<dim3(2048), blk, 0, stream>>>(xT, heat);
  gemm_mfma<0><<<dim3(64, 8, 2), blk, 0, stream>>>(xT, q_w, q_b, qb, nullptr, nullptr, 4096, dtf);
  gemm_mfma<1><<<dim3(16, 16, 2), blk, 0, stream>>>(upT, kv_w, kv_b, kb, vb, nullptr, 1024, dtf);
  qsum_partial<<<dim3(16, 16), blk, 0, stream>>>(qb, qsumP);
  topk_kernel<<<dim3(16), blk, 0, stream>>>(qsumP, kb, heat, gum, posb, dtf);
  gather_kv<<<dim3(16, 2), blk, 0, stream>>>(xT, kv_w, kv_b, posb, tkb, tvTb, dtf);
  coarse_attn_mfma<<<dim3(64, 16), blk, 0, stream>>>(qb, kb, vb, co);
  dwconv_kernel<<<dim3(1024), blk, 0, stream>>>(vb, pe_w, pe_b, vpe, dtf);
  fine_mfma<<<dim3(64, 16), blk, 0, stream>>>(qb, tkb, tvTb, co, g_w, g_b, vpe, xsT, dtf);
  gemm_mfma<3><<<dim3(64, 8, 2), blk, 0, stream>>>(xsT, p_w, p_b, nullptr, nullptr, d_out, 4096, dtf);
}

// Round 6
// 358.923 us; speedup vs baseline: 4.6968x; 1.2165x over previous
//
#include <hip/hip_runtime.h>
#include <hip/hip_bf16.h>
#include <cstdint>

typedef __hip_bfloat16 bf16;
typedef unsigned short u16;
typedef __attribute__((ext_vector_type(8))) short bf16x8;
typedef __attribute__((ext_vector_type(4))) float f32x4;

static __device__ __forceinline__ float b2f(bf16 v) { return __bfloat162float(v); }
static __device__ __forceinline__ float bs2f(u16 s) {
  unsigned int u = ((unsigned int)s) << 16;
  float f;
  __builtin_memcpy(&f, &u, 4);
  return f;
}
static __device__ __forceinline__ u16 f2bs(float f) {
  bf16 h = __float2bfloat16(f);
  u16 s;
  __builtin_memcpy(&s, &h, 2);
  return s;
}
// dual-dtype load: f32!=0 -> buffer is float32, else packed bf16
static __device__ __forceinline__ float ldf(const void* p, size_t i, int f32) {
  return f32 ? ((const float*)p)[i] : bs2f(((const u16*)p)[i]);
}

// ---------------------------------------------------------------------------
// dtype detection on x (first 8 MB viewed as u16): bf16-exp==0xFF impossible
// for N(0,1) bf16 data. uint4 loads; one atomic per wave max.
// ---------------------------------------------------------------------------
__global__ __launch_bounds__(256) void detect_dtype(const uint4* __restrict__ xs,
                                                    int* __restrict__ flag) {
  int i = blockIdx.x * 256 + threadIdx.x;
  uint4 v = xs[i];
  bool hit = false;
#pragma unroll
  for (int j = 0; j < 4; ++j) {
    unsigned w = (j == 0) ? v.x : (j == 1) ? v.y : (j == 2) ? v.z : v.w;
    if ((w & 0x7F80u) == 0x7F80u) hit = true;
    if ((w & 0x7F800000u) == 0x7F800000u) hit = true;
  }
  unsigned long long mask = __ballot(hit);
  if (mask != 0ull && (threadIdx.x & 63) == 0) atomicOr(flag, 1);
}

// ---------------------------------------------------------------------------
// transpose [b][c=512][N] (dual dtype) -> [b][N][512] bf16; grid (N/64,8,B)
// ---------------------------------------------------------------------------
__global__ __launch_bounds__(256) void transpose_bf16(
    const void* __restrict__ src, u16* __restrict__ dst, int N,
    const int* __restrict__ dtf) {
  const int f32 = *dtf;
  const int b = blockIdx.z, n0 = blockIdx.x * 64, c0 = blockIdx.y * 64;
  const int t = threadIdx.x;
  __shared__ __align__(16) u16 tile[64][72];
#pragma unroll
  for (int j = 0; j < 2; ++j) {
    int cc = (t >> 3) + j * 32;
    int nn = (t & 7) * 8;
    u16 tmp[8];
    if (f32) {
      const float* s4 = (const float*)src + ((size_t)(b * 512 + c0 + cc)) * N + n0 + nn;
#pragma unroll
      for (int u = 0; u < 8; ++u) tmp[u] = f2bs(s4[u]);
    } else {
      *reinterpret_cast<uint4*>(tmp) = *reinterpret_cast<const uint4*>(
          (const u16*)src + ((size_t)(b * 512 + c0 + cc)) * N + n0 + nn);
    }
    *reinterpret_cast<uint4*>(&tile[cc][nn]) = *reinterpret_cast<const uint4*>(tmp);
  }
  __syncthreads();
#pragma unroll
  for (int j = 0; j < 2; ++j) {
    int nn = (t >> 3) + j * 32;
    int cc0 = (t & 7) * 8;
    u16 tmp[8];
#pragma unroll
    for (int u = 0; u < 8; ++u) tmp[u] = tile[cc0 + u][nn];
    *reinterpret_cast<uint4*>(&dst[((size_t)b * N + n0 + nn) * 512 + c0 + cc0]) =
        *reinterpret_cast<const uint4*>(tmp);
  }
}

// ---------------------------------------------------------------------------
// MFMA conv1x1 GEMM. K=512, tile 64x64, 4 waves.
// ---------------------------------------------------------------------------
template<int MODE>
__global__ __launch_bounds__(256) void gemm_mfma(
    const u16* __restrict__ A, const void* __restrict__ W,
    const void* __restrict__ bias, u16* __restrict__ o0, u16* __restrict__ o1,
    void* __restrict__ ob, int M, const int* __restrict__ dtf) {
  const int f32 = *dtf;
  const int b = blockIdx.z, m0 = blockIdx.x * 64, oo0 = blockIdx.y * 64;
  const int t = threadIdx.x, w = t >> 6, lane = t & 63;
  const int quad = lane >> 4, c = lane & 15;
  __shared__ __align__(16) u16 As[64][72];
  __shared__ __align__(16) u16 Ws[64][72];
  f32x4 acc[4];
#pragma unroll
  for (int ot = 0; ot < 4; ++ot) acc[ot] = (f32x4){0.f, 0.f, 0.f, 0.f};
  const u16* Ab = A + (size_t)b * M * 512;
  const int srow = t >> 2, scol = (t & 3) * 16;

  for (int k0 = 0; k0 < 512; k0 += 64) {
    __syncthreads();
    {
      const u16* ga = Ab + (size_t)(m0 + srow) * 512 + k0 + scol;
      *reinterpret_cast<uint4*>(&As[srow][scol])     = *reinterpret_cast<const uint4*>(ga);
      *reinterpret_cast<uint4*>(&As[srow][scol + 8]) = *reinterpret_cast<const uint4*>(ga + 8);
      if (f32) {
        const float* gw = (const float*)W + (size_t)(oo0 + srow) * 512 + k0 + scol;
#pragma unroll
        for (int e = 0; e < 16; ++e) Ws[srow][scol + e] = f2bs(gw[e]);
      } else {
        const u16* gw = (const u16*)W + (size_t)(oo0 + srow) * 512 + k0 + scol;
        *reinterpret_cast<uint4*>(&Ws[srow][scol])     = *reinterpret_cast<const uint4*>(gw);
        *reinterpret_cast<uint4*>(&Ws[srow][scol + 8]) = *reinterpret_cast<const uint4*>(gw + 8);
      }
    }
    __syncthreads();
#pragma unroll
    for (int ks = 0; ks < 2; ++ks) {
      bf16x8 av = *reinterpret_cast<const bf16x8*>(&As[w * 16 + c][ks * 32 + quad * 8]);
#pragma unroll
      for (int ot = 0; ot < 4; ++ot) {
        bf16x8 wv = *reinterpret_cast<const bf16x8*>(&Ws[ot * 16 + c][ks * 32 + quad * 8]);
        if (MODE == 3)
          acc[ot] = __builtin_amdgcn_mfma_f32_16x16x32_bf16(wv, av, acc[ot], 0, 0, 0);
        else
          acc[ot] = __builtin_amdgcn_mfma_f32_16x16x32_bf16(av, wv, acc[ot], 0, 0, 0);
      }
    }
  }

  if (MODE == 0) {
#pragma unroll
    for (int ot = 0; ot < 4; ++ot) {
      int o = oo0 + ot * 16 + c;
      float bv = ldf(bias, o, f32);
      int h = o >> 6, d = o & 63;
#pragma unroll
      for (int r = 0; r < 4; ++r) {
        int m = m0 + w * 16 + quad * 4 + r;
        o0[((size_t)(b * 8 + h) * M + m) * 64 + d] = f2bs(acc[ot][r] + bv);
      }
    }
  } else if (MODE == 1) {
#pragma unroll
    for (int ot = 0; ot < 4; ++ot) {
      int o = oo0 + ot * 16 + c;
      float bv = ldf(bias, o, f32);
      int hh = o >> 7, jj = o & 127;
      u16* tgt = (jj < 64) ? o0 : o1;
#pragma unroll
      for (int r = 0; r < 4; ++r) {
        int m = m0 + w * 16 + quad * 4 + r;
        tgt[((size_t)(b * 8 + hh) * M + m) * 64 + (jj & 63)] = f2bs(acc[ot][r] + bv);
      }
    }
  } else {
#pragma unroll
    for (int ot = 0; ot < 4; ++ot) {
#pragma unroll
      for (int r = 0; r < 4; ++r) {
        int o = oo0 + ot * 16 + quad * 4 + r;
        float val = acc[ot][r] + ldf(bias, o, f32);
        int m = m0 + w * 16 + c;
        size_t oi_ = ((size_t)(b * 512 + o)) * M + m;
        if (f32) ((float*)ob)[oi_] = val;
        else     ((u16*)ob)[oi_] = f2bs(val);
      }
    }
  }
}

// heat[b,mu] = mean over C and 2x2 spatial of x, computed from coalesced xT
__global__ __launch_bounds__(256) void heat_kernel(const u16* __restrict__ xT,
                                                   float* __restrict__ heat) {
  int bm = blockIdx.x;
  int b = bm >> 10, mu = bm & 1023;
  int hu = mu >> 5, wu = mu & 31;
  int t = threadIdx.x;
  int row = t >> 6, seg = t & 63;
  int y = hu * 2 + (row >> 1), xx = wu * 2 + (row & 1);
  const uint4* p = reinterpret_cast<const uint4*>(
      xT + ((size_t)b * 4096 + y * 64 + xx) * 512);
  uint4 v = p[seg];
  float s = 0.f;
#pragma unroll
  for (int j = 0; j < 4; ++j) {
    unsigned w = (j == 0) ? v.x : (j == 1) ? v.y : (j == 2) ? v.z : v.w;
    s += bs2f((u16)(w & 0xFFFF)) + bs2f((u16)(w >> 16));
  }
  __shared__ float r[256];
  r[t] = s; __syncthreads();
  for (int off = 128; off; off >>= 1) { if (t < off) r[t] += r[t + off]; __syncthreads(); }
  if (t == 0) heat[bm] = r[0] * (1.0f / 2048.0f);
}

// stage 1 of qsum: partial[bh][chunk][d] = sum over 256 n-rows
__global__ __launch_bounds__(256) void qsum_partial(const u16* __restrict__ q,
                                                    float* __restrict__ qsumP) {
  int bh = blockIdx.x, ch = blockIdx.y, t = threadIdx.x;
  int d = t & 63, g = t >> 6;
  int n0 = ch * 256 + g * 64;
  float s = 0.f;
  for (int r = 0; r < 64; ++r)
    s += bs2f(q[((size_t)bh * 4096 + n0 + r) * 64 + d]);
  __shared__ float r[256];
  r[t] = s; __syncthreads();
  if (t < 64) qsumP[(size_t)(bh * 16 + ch) * 64 + t] = r[t] + r[t + 64] + r[t + 128] + r[t + 192];
}

// scores -> top-16 coarse cells -> 64 full-res positions into posb
__global__ __launch_bounds__(256) void topk_kernel(
    const float* __restrict__ qsumP, const u16* __restrict__ k,
    const float* __restrict__ heat, const void* __restrict__ gumbel,
    int* __restrict__ posb, const int* __restrict__ dtf) {
  const int f32 = *dtf;
  int bh = blockIdx.x, b = bh >> 3, t = threadIdx.x;
  __shared__ float qs[64];
  __shared__ float s[1024];
  __shared__ float rv[256];
  __shared__ int   ri[256];
  if (t < 64) {
    float acc = 0.f;
    for (int ch = 0; ch < 16; ++ch) acc += qsumP[(size_t)(bh * 16 + ch) * 64 + t];
    qs[t] = acc;
  }
  __syncthreads();
  for (int j = 0; j < 4; ++j) {
    int m = t + j * 256;
    const u16* kr = k + ((size_t)bh * 1024 + m) * 64;
    float dot = 0.f;
    for (int d = 0; d < 64; ++d) dot += qs[d] * bs2f(kr[d]);
    s[m] = dot * (0.125f / 4096.0f) * heat[b * 1024 + m] + ldf(gumbel, (size_t)bh * 1024 + m, f32);
  }
  __syncthreads();
  for (int it = 0; it < 16; ++it) {
    float bv = -1e30f; int bi = 0x7fffffff;
    for (int j = 0; j < 4; ++j) {
      int m = t + j * 256; float vv = s[m];
      if (vv > bv || (vv == bv && m < bi)) { bv = vv; bi = m; }
    }
    rv[t] = bv; ri[t] = bi; __syncthreads();
    for (int off = 128; off; off >>= 1) {
      if (t < off) {
        if (rv[t + off] > rv[t] || (rv[t + off] == rv[t] && ri[t + off] < ri[t])) {
          rv[t] = rv[t + off]; ri[t] = ri[t + off];
        }
      }
      __syncthreads();
    }
    if (t == 0) {
      int mi = ri[0]; s[mi] = -1e30f;
      int hy = (mi >> 5) * 2, wx = (mi & 31) * 2;
      posb[bh * 64 + it]      = hy * 64 + wx;
      posb[bh * 64 + 16 + it] = hy * 64 + wx + 1;
      posb[bh * 64 + 32 + it] = (hy + 1) * 64 + wx;
      posb[bh * 64 + 48 + it] = (hy + 1) * 64 + wx + 1;
    }
    __syncthreads();
  }
}

// ---------------------------------------------------------------------------
// gather_kv as MFMA GEMM: per (bh, half): OUT[64 m][64 o] = Xg[64][512].W^T.
// A rows gathered via pos[]; 8 k-chunks, uint4 staging, 16 MFMAs/chunk/wave.
// half 0 -> tkb[bh][m][d], half 1 -> tvTb[bh][d][m].
// ---------------------------------------------------------------------------
__global__ __launch_bounds__(256) void gather_kv_mfma(
    const u16* __restrict__ xT, const void* __restrict__ kv_w,
    const void* __restrict__ kv_b, const int* __restrict__ posb,
    u16* __restrict__ tkb, u16* __restrict__ tvTb,
    const int* __restrict__ dtf) {
  const int f32 = *dtf;
  const int bh = blockIdx.x, b = bh >> 3, h = bh & 7;
  const int half = blockIdx.y;
  const int t = threadIdx.x, w = t >> 6, lane = t & 63;
  const int quad = lane >> 4, c = lane & 15;
  __shared__ int pos[64];
  __shared__ __align__(16) u16 As[64][72];
  __shared__ __align__(16) u16 Ws[64][72];
  if (t < 64) pos[t] = posb[bh * 64 + t];
  __syncthreads();
  const int obase = h * 128 + half * 64;
  const int srow = t >> 2, scol = (t & 3) * 16;
  const int arow = pos[srow];
  f32x4 acc[4];
#pragma unroll
  for (int ot = 0; ot < 4; ++ot) acc[ot] = (f32x4){0.f, 0.f, 0.f, 0.f};

  for (int k0 = 0; k0 < 512; k0 += 64) {
    __syncthreads();
    {
      const u16* ga = xT + ((size_t)b * 4096 + arow) * 512 + k0 + scol;
      *reinterpret_cast<uint4*>(&As[srow][scol])     = *reinterpret_cast<const uint4*>(ga);
      *reinterpret_cast<uint4*>(&As[srow][scol + 8]) = *reinterpret_cast<const uint4*>(ga + 8);
      if (f32) {
        const float* gw = (const float*)kv_w + (size_t)(obase + srow) * 512 + k0 + scol;
#pragma unroll
        for (int e = 0; e < 16; ++e) Ws[srow][scol + e] = f2bs(gw[e]);
      } else {
        const u16* gw = (const u16*)kv_w + (size_t)(obase + srow) * 512 + k0 + scol;
        *reinterpret_cast<uint4*>(&Ws[srow][scol])     = *reinterpret_cast<const uint4*>(gw);
        *reinterpret_cast<uint4*>(&Ws[srow][scol + 8]) = *reinterpret_cast<const uint4*>(gw + 8);
      }
    }
    __syncthreads();
#pragma unroll
    for (int ks = 0; ks < 2; ++ks) {
      bf16x8 av = *reinterpret_cast<const bf16x8*>(&As[w * 16 + c][ks * 32 + quad * 8]);
#pragma unroll
      for (int ot = 0; ot < 4; ++ot) {
        bf16x8 wv = *reinterpret_cast<const bf16x8*>(&Ws[ot * 16 + c][ks * 32 + quad * 8]);
        acc[ot] = __builtin_amdgcn_mfma_f32_16x16x32_bf16(av, wv, acc[ot], 0, 0, 0);
      }
    }
  }

#pragma unroll
  for (int ot = 0; ot < 4; ++ot) {
    int d = ot * 16 + c;
    float bv = ldf(kv_b, obase + d, f32);
#pragma unroll
    for (int r = 0; r < 4; ++r) {
      int m = w * 16 + quad * 4 + r;
      u16 val = f2bs(acc[ot][r] + bv);
      if (half) tvTb[((size_t)bh * 64 + d) * 64 + m] = val;
      else      tkb[((size_t)bh * 64 + m) * 64 + d] = val;
    }
  }
}

// ---------------------------------------------------------------------------
// coarse attention, bf16 MFMA (validated round 3/4 structure).
// ---------------------------------------------------------------------------
__global__ __launch_bounds__(256) void coarse_attn_mfma(
    const u16* __restrict__ q, const u16* __restrict__ k,
    const u16* __restrict__ v, u16* __restrict__ coarse) {
  const int bh = blockIdx.y;
  const int n0 = blockIdx.x * 64;
  const int t = threadIdx.x;
  const int w = t >> 6, lane = t & 63;
  const int quad = lane >> 4, c = lane & 15;

  __shared__ __align__(16) u16 Ks[64][72];
  __shared__ __align__(16) u16 Vt[64][72];
  __shared__ __align__(16) u16 Ps[4][16][72];

  const int n = n0 + w * 16 + c;
  bf16x8 bq[2];
  {
    const u16* qr = q + ((size_t)bh * 4096 + n) * 64;
    bq[0] = *reinterpret_cast<const bf16x8*>(qr + quad * 8);
    bq[1] = *reinterpret_cast<const bf16x8*>(qr + 32 + quad * 8);
  }

  f32x4 po[4];
#pragma unroll
  for (int dt = 0; dt < 4; ++dt) po[dt] = (f32x4){0.f, 0.f, 0.f, 0.f};
  float sume = 0.f;

  for (int m0 = 0; m0 < 1024; m0 += 64) {
    __syncthreads();
    {
      int row = t >> 2, col = (t & 3) * 16;
      const u16* gk = k + ((size_t)bh * 1024 + m0 + row) * 64 + col;
      *reinterpret_cast<uint4*>(&Ks[row][col])     = *reinterpret_cast<const uint4*>(gk);
      *reinterpret_cast<uint4*>(&Ks[row][col + 8]) = *reinterpret_cast<const uint4*>(gk + 8);
      for (int i = t; i < 4096; i += 256) {
        int mm = i >> 6, dd = i & 63;
        Vt[dd][mm] = v[((size_t)bh * 1024 + m0 + mm) * 64 + dd];
      }
    }
    __syncthreads();

    f32x4 st[4];
#pragma unroll
    for (int mt = 0; mt < 4; ++mt) {
      f32x4 acc = (f32x4){0.f, 0.f, 0.f, 0.f};
#pragma unroll
      for (int s = 0; s < 2; ++s) {
        bf16x8 ak = *reinterpret_cast<const bf16x8*>(&Ks[mt * 16 + c][s * 32 + quad * 8]);
        acc = __builtin_amdgcn_mfma_f32_16x16x32_bf16(ak, bq[s], acc, 0, 0, 0);
      }
      st[mt] = acc;
    }

    float chunksum = 0.f;
#pragma unroll
    for (int mt = 0; mt < 4; ++mt) {
      float e0 = __expf(st[mt][0] * 0.125f);
      float e1 = __expf(st[mt][1] * 0.125f);
      float e2 = __expf(st[mt][2] * 0.125f);
      float e3 = __expf(st[mt][3] * 0.125f);
      chunksum += (e0 + e1) + (e2 + e3);
      ushort4 pw;
      pw.x = f2bs(e0); pw.y = f2bs(e1); pw.z = f2bs(e2); pw.w = f2bs(e3);
      *reinterpret_cast<ushort4*>(&Ps[w][c][mt * 16 + quad * 4]) = pw;
    }
    chunksum += __shfl_xor(chunksum, 16, 64);
    chunksum += __shfl_xor(chunksum, 32, 64);
    sume += chunksum;

#pragma unroll
    for (int s = 0; s < 2; ++s) {
      bf16x8 bp = *reinterpret_cast<const bf16x8*>(&Ps[w][c][s * 32 + quad * 8]);
#pragma unroll
      for (int dt = 0; dt < 4; ++dt) {
        bf16x8 av = *reinterpret_cast<const bf16x8*>(&Vt[dt * 16 + c][s * 32 + quad * 8]);
        po[dt] = __builtin_amdgcn_mfma_f32_16x16x32_bf16(av, bp, po[dt], 0, 0, 0);
      }
    }
  }

  float inv = 1.0f / sume;
  u16* orow = coarse + ((size_t)bh * 4096 + n) * 64;
#pragma unroll
  for (int dt = 0; dt < 4; ++dt) {
    ushort4 r;
    r.x = f2bs(po[dt][0] * inv); r.y = f2bs(po[dt][1] * inv);
    r.z = f2bs(po[dt][2] * inv); r.w = f2bs(po[dt][3] * inv);
    *reinterpret_cast<ushort4*>(&orow[dt * 16 + quad * 4]) = r;
  }
}

// depthwise 7x7 conv on v (bf16) -> vpe bf16
__global__ __launch_bounds__(256) void dwconv_kernel(
    const u16* __restrict__ v, const void* __restrict__ pe_w,
    const void* __restrict__ pe_b, u16* __restrict__ vpe,
    const int* __restrict__ dtf) {
  const int f32 = *dtf;
  int bc = blockIdx.x;
  int b = bc >> 9, c = bc & 511;
  int h = c >> 6, d = c & 63;
  int t = threadIdx.x;
  __shared__ float img[1024];
  __shared__ float wts[49];
  for (int i = t; i < 1024; i += 256)
    img[i] = bs2f(v[((size_t)(b * 8 + h) * 1024 + i) * 64 + d]);
  if (t < 49) wts[t] = ldf(pe_w, c * 49 + t, f32);
  float bias = ldf(pe_b, c, f32);
  __syncthreads();
  for (int i = t; i < 1024; i += 256) {
    int y = i >> 5, xx = i & 31;
    float a = 0.f;
#pragma unroll
    for (int ky = 0; ky < 7; ++ky) {
      int yy = y + ky - 3;
      if ((unsigned)yy >= 32u) continue;
#pragma unroll
      for (int kx = 0; kx < 7; ++kx) {
        int xc = xx + kx - 3;
        if ((unsigned)xc >= 32u) continue;
        a += img[yy * 32 + xc] * wts[ky * 7 + kx];
      }
    }
    vpe[(size_t)bc * 1024 + i] = f2bs(a + bias);
  }
}

// ---------------------------------------------------------------------------
// fused fine attention + gate MFMA + combine + bilinear vpe add -> xsT bf16.
// ---------------------------------------------------------------------------
__global__ __launch_bounds__(256) void fine_mfma(
    const u16* __restrict__ q, const u16* __restrict__ tkb,
    const u16* __restrict__ tvTb, const u16* __restrict__ co,
    const void* __restrict__ gate_w, const void* __restrict__ gate_b,
    const u16* __restrict__ vpe, u16* __restrict__ xsT,
    const int* __restrict__ dtf) {
  const int f32 = *dtf;
  const int bh = blockIdx.y, b = bh >> 3, h = bh & 7;
  const int y = blockIdx.x;
  const int n0 = y * 64;
  const int t = threadIdx.x, w = t >> 6, lane = t & 63;
  const int quad = lane >> 4, c = lane & 15;

  __shared__ __align__(16) u16 gw[64][136];
  __shared__ __align__(16) u16 fus[4][16][136];
  __shared__ __align__(16) u16 vl[64][66];
  __shared__ __align__(16) u16 outb[4][16][72];
  __shared__ float gbl[64];

  int jy = y >> 1, y0, y1; float wy0, wy1;
  if ((y & 1) == 0) { y0 = (jy > 0) ? jy - 1 : 0; y1 = jy; wy0 = 0.25f; wy1 = 0.75f; }
  else              { y0 = jy; y1 = (jy < 31) ? jy + 1 : 31; wy0 = 0.75f; wy1 = 0.25f; }

  for (int i = t; i < 8192; i += 256) {
    gw[i >> 7][i & 127] = f32 ? f2bs(((const float*)gate_w)[i]) : ((const u16*)gate_w)[i];
  }
  for (int i = t; i < 4096; i += 256) {
    int ch = i >> 6, r = (i >> 5) & 1, xx = i & 31;
    int yy = r ? y1 : y0;
    vl[ch][r * 33 + xx] = vpe[((size_t)(b * 512 + h * 64 + ch)) * 1024 + yy * 32 + xx];
  }
  if (t < 64) gbl[t] = ldf(gate_b, t, f32);

  const int n = n0 + w * 16 + c;
  bf16x8 bq[2];
  {
    const u16* qr = q + ((size_t)bh * 4096 + n) * 64;
    bq[0] = *reinterpret_cast<const bf16x8*>(qr + quad * 8);
    bq[1] = *reinterpret_cast<const bf16x8*>(qr + 32 + quad * 8);
  }
  __syncthreads();

  f32x4 st[4];
#pragma unroll
  for (int mt = 0; mt < 4; ++mt) {
    f32x4 acc = (f32x4){0.f, 0.f, 0.f, 0.f};
#pragma unroll
    for (int s = 0; s < 2; ++s) {
      bf16x8 ak = *reinterpret_cast<const bf16x8*>(
          &tkb[((size_t)bh * 64 + mt * 16 + c) * 64 + s * 32 + quad * 8]);
      acc = __builtin_amdgcn_mfma_f32_16x16x32_bf16(ak, bq[s], acc, 0, 0, 0);
    }
    st[mt] = acc;
  }
  float sume = 0.f;
#pragma unroll
  for (int mt = 0; mt < 4; ++mt) {
    float e0 = __expf(st[mt][0] * 0.125f);
    float e1 = __expf(st[mt][1] * 0.125f);
    float e2 = __expf(st[mt][2] * 0.125f);
    float e3 = __expf(st[mt][3] * 0.125f);
    sume += (e0 + e1) + (e2 + e3);
    ushort4 pw;
    pw.x = f2bs(e0); pw.y = f2bs(e1); pw.z = f2bs(e2); pw.w = f2bs(e3);
    *reinterpret_cast<ushort4*>(&fus[w][c][mt * 16 + quad * 4]) = pw;
  }
  sume += __shfl_xor(sume, 16, 64);
  sume += __shfl_xor(sume, 32, 64);
  float inv = 1.0f / sume;
  __syncthreads();

  f32x4 po[4];
#pragma unroll
  for (int dt = 0; dt < 4; ++dt) po[dt] = (f32x4){0.f, 0.f, 0.f, 0.f};
#pragma unroll
  for (int s = 0; s < 2; ++s) {
    bf16x8 bp = *reinterpret_cast<const bf16x8*>(&fus[w][c][s * 32 + quad * 8]);
#pragma unroll
    for (int dt = 0; dt < 4; ++dt) {
      bf16x8 av = *reinterpret_cast<const bf16x8*>(
          &tvTb[((size_t)bh * 64 + dt * 16 + c) * 64 + s * 32 + quad * 8]);
      po[dt] = __builtin_amdgcn_mfma_f32_16x16x32_bf16(av, bp, po[dt], 0, 0, 0);
    }
  }
  __syncthreads();

  {
    const u16* crow = co + ((size_t)bh * 4096 + n) * 64 + quad * 16;
    *reinterpret_cast<uint4*>(&fus[w][c][quad * 16])     = *reinterpret_cast<const uint4*>(crow);
    *reinterpret_cast<uint4*>(&fus[w][c][quad * 16 + 8]) = *reinterpret_cast<const uint4*>(crow + 8);
  }
#pragma unroll
  for (int dt = 0; dt < 4; ++dt) {
    ushort4 rw;
    rw.x = f2bs(po[dt][0] * inv); rw.y = f2bs(po[dt][1] * inv);
    rw.z = f2bs(po[dt][2] * inv); rw.w = f2bs(po[dt][3] * inv);
    *reinterpret_cast<ushort4*>(&fus[w][c][64 + dt * 16 + quad * 4]) = rw;
  }
  __syncthreads();

  f32x4 ga[4];
#pragma unroll
  for (int ot = 0; ot < 4; ++ot) ga[ot] = (f32x4){0.f, 0.f, 0.f, 0.f};
#pragma unroll
  for (int s = 0; s < 4; ++s) {
    bf16x8 bf = *reinterpret_cast<const bf16x8*>(&fus[w][c][s * 32 + quad * 8]);
#pragma unroll
    for (int ot = 0; ot < 4; ++ot) {
      bf16x8 ag = *reinterpret_cast<const bf16x8*>(&gw[ot * 16 + c][s * 32 + quad * 8]);
      ga[ot] = __builtin_amdgcn_mfma_f32_16x16x32_bf16(ag, bf, ga[ot], 0, 0, 0);
    }
  }

  const int x = w * 16 + c;
  int jx = x >> 1, x0, x1; float wx0, wx1;
  if ((x & 1) == 0) { x0 = (jx > 0) ? jx - 1 : 0; x1 = jx; wx0 = 0.25f; wx1 = 0.75f; }
  else              { x0 = jx; x1 = (jx < 31) ? jx + 1 : 31; wx0 = 0.75f; wx1 = 0.25f; }
#pragma unroll
  for (int dt = 0; dt < 4; ++dt) {
    ushort4 ow;
    u16 tmp[4];
#pragma unroll
    for (int r = 0; r < 4; ++r) {
      int row = dt * 16 + quad * 4 + r;
      float ref = po[dt][r] * inv;
      float coar = bs2f(fus[w][c][row]);
      float g = 1.0f / (1.0f + __expf(-(ga[dt][r] + gbl[row])));
      float vv = wy0 * (wx0 * bs2f(vl[row][x0]) + wx1 * bs2f(vl[row][x1])) +
                 wy1 * (wx0 * bs2f(vl[row][33 + x0]) + wx1 * bs2f(vl[row][33 + x1]));
      tmp[r] = f2bs(g * ref + (1.0f - g) * coar + vv);
    }
    ow.x = tmp[0]; ow.y = tmp[1]; ow.z = tmp[2]; ow.w = tmp[3];
    *reinterpret_cast<ushort4*>(&outb[w][c][dt * 16 + quad * 4]) = ow;
  }
  __syncthreads();

  {
    int nl = lane >> 2, cs = (lane & 3) * 16;
    u16* dst = xsT + ((size_t)b * 4096 + n0 + w * 16 + nl) * 512 + h * 64 + cs;
    *reinterpret_cast<uint4*>(dst)     = *reinterpret_cast<const uint4*>(&outb[w][nl][cs]);
    *reinterpret_cast<uint4*>(dst + 8) = *reinterpret_cast<const uint4*>(&outb[w][nl][cs + 8]);
  }
}

extern "C" void kernel_launch(void* const* d_in, const int* in_sizes, int n_in,
                              void* d_out, int out_size, void* d_ws, size_t ws_size,
                              hipStream_t stream) {
  const void* x    = d_in[0];
  const void* up   = d_in[1];
  const void* gum  = d_in[2];
  const void* q_w  = d_in[3];
  const void* q_b  = d_in[4];
  const void* kv_w = d_in[5];
  const void* kv_b = d_in[6];
  const void* p_w  = d_in[7];
  const void* p_b  = d_in[8];
  const void* pe_w = d_in[9];
  const void* pe_b = d_in[10];
  const void* g_w  = d_in[11];
  const void* g_b  = d_in[12];

  float* ws    = (float*)d_ws;
  int*   dtf   = (int*)ws;                   // 16
  float* qsumP = ws + 16;                    // 16384
  float* heat  = qsumP + 16384;              // 2048
  int*   posb  = (int*)(heat + 2048);        // 1024
  u16*   tkb   = (u16*)(posb + 1024);        // 65536
  u16*   tvTb  = tkb + 65536;                // 65536
  u16*   qb    = tvTb + 65536;               // 4M
  u16*   kb    = qb + 4194304;               // 1M
  u16*   vb    = kb + 1048576;               // 1M
  u16*   xT    = vb + 1048576;               // 4M
  u16*   upT   = xT + 4194304;               // 1M
  u16*   co    = upT + 1048576;              // 4M
  u16*   xsT   = co + 4194304;               // 4M
  u16*   vpe   = xsT + 4194304;              // 1M   (~34 MB total)

  dim3 blk(256);
  hipMemsetAsync(dtf, 0, 4, stream);
  detect_dtype<<<dim3(2048), blk, 0, stream>>>((const uint4*)x, dtf);
  transpose_bf16<<<dim3(64, 8, 2), blk, 0, stream>>>(x, xT, 4096, dtf);
  transpose_bf16<<<dim3(16, 8, 2), blk, 0, stream>>>(up, upT, 1024, dtf);
  heat_kernel<<<dim3(2048), blk, 0, stream>>>(xT, heat);
  gemm_mfma<0><<<dim3(64, 8, 2), blk, 0, stream>>>(xT, q_w, q_b, qb, nullptr, nullptr, 4096, dtf);
  gemm_mfma<1><<<dim3(16, 16, 2), blk, 0, stream>>>(upT, kv_w, kv_b, kb, vb, nullptr, 1024, dtf);
  qsum_partial<<<dim3(16, 16), blk, 0, stream>>>(qb, qsumP);
  topk_kernel<<<dim3(16), blk, 0, stream>>>(qsumP, kb, heat, gum, posb, dtf);
  gather_kv_mfma<<<dim3(16, 2), blk, 0, stream>>>(xT, kv_w, kv_b, posb, tkb, tvTb, dtf);
  coarse_attn_mfma<<<dim3(64, 16), blk, 0, stream>>>(qb, kb, vb, co);
  dwconv_kernel<<<dim3(1024), blk, 0, stream>>>(vb, pe_w, pe_b, vpe, dtf);
  fine_mfma<<<dim3(64, 16), blk, 0, stream>>>(qb, tkb, tvTb, co, g_w, g_b, vpe, xsT, dtf);
  gemm_mfma<3><<<dim3(64, 8, 2), blk, 0, stream>>>(xsT, p_w, p_b, nullptr, nullptr, d_out, 4096, dtf);
}

// Round 7
// 329.938 us; speedup vs baseline: 5.1094x; 1.0879x over previous
//
#include <hip/hip_runtime.h>
#include <hip/hip_bf16.h>
#include <cstdint>

typedef __hip_bfloat16 bf16;
typedef unsigned short u16;
typedef __attribute__((ext_vector_type(8))) short bf16x8;
typedef __attribute__((ext_vector_type(4))) float f32x4;

static __device__ __forceinline__ float b2f(bf16 v) { return __bfloat162float(v); }
static __device__ __forceinline__ float bs2f(u16 s) {
  unsigned int u = ((unsigned int)s) << 16;
  float f;
  __builtin_memcpy(&f, &u, 4);
  return f;
}
static __device__ __forceinline__ u16 f2bs(float f) {
  bf16 h = __float2bfloat16(f);
  u16 s;
  __builtin_memcpy(&s, &h, 2);
  return s;
}
// dual-dtype load: f32!=0 -> buffer is float32, else packed bf16
static __device__ __forceinline__ float ldf(const void* p, size_t i, int f32) {
  return f32 ? ((const float*)p)[i] : bs2f(((const u16*)p)[i]);
}

// ---------------------------------------------------------------------------
// dtype detection on a 256 KB sample of x: bf16-exp==0xFF impossible for
// N(0,1) bf16; ~256 expected hits if fp32. One atomic per wave max.
// ---------------------------------------------------------------------------
__global__ __launch_bounds__(256) void detect_dtype(const uint4* __restrict__ xs,
                                                    int* __restrict__ flag) {
  int i = blockIdx.x * 256 + threadIdx.x;
  uint4 v = xs[i];
  bool hit = false;
#pragma unroll
  for (int j = 0; j < 4; ++j) {
    unsigned w = (j == 0) ? v.x : (j == 1) ? v.y : (j == 2) ? v.z : v.w;
    if ((w & 0x7F80u) == 0x7F80u) hit = true;
    if ((w & 0x7F800000u) == 0x7F800000u) hit = true;
  }
  unsigned long long mask = __ballot(hit);
  if (mask != 0ull && (threadIdx.x & 63) == 0) atomicOr(flag, 1);
}

// ---------------------------------------------------------------------------
// transpose [b][c=512][N] (dual dtype) -> [b][N][512] bf16; grid (N/64,8,B)
// ---------------------------------------------------------------------------
__global__ __launch_bounds__(256) void transpose_bf16(
    const void* __restrict__ src, u16* __restrict__ dst, int N,
    const int* __restrict__ dtf) {
  const int f32 = *dtf;
  const int b = blockIdx.z, n0 = blockIdx.x * 64, c0 = blockIdx.y * 64;
  const int t = threadIdx.x;
  __shared__ __align__(16) u16 tile[64][72];
#pragma unroll
  for (int j = 0; j < 2; ++j) {
    int cc = (t >> 3) + j * 32;
    int nn = (t & 7) * 8;
    u16 tmp[8];
    if (f32) {
      const float* s4 = (const float*)src + ((size_t)(b * 512 + c0 + cc)) * N + n0 + nn;
#pragma unroll
      for (int u = 0; u < 8; ++u) tmp[u] = f2bs(s4[u]);
    } else {
      *reinterpret_cast<uint4*>(tmp) = *reinterpret_cast<const uint4*>(
          (const u16*)src + ((size_t)(b * 512 + c0 + cc)) * N + n0 + nn);
    }
    *reinterpret_cast<uint4*>(&tile[cc][nn]) = *reinterpret_cast<const uint4*>(tmp);
  }
  __syncthreads();
#pragma unroll
  for (int j = 0; j < 2; ++j) {
    int nn = (t >> 3) + j * 32;
    int cc0 = (t & 7) * 8;
    u16 tmp[8];
#pragma unroll
    for (int u = 0; u < 8; ++u) tmp[u] = tile[cc0 + u][nn];
    *reinterpret_cast<uint4*>(&dst[((size_t)b * N + n0 + nn) * 512 + c0 + cc0]) =
        *reinterpret_cast<const uint4*>(tmp);
  }
}

// ---------------------------------------------------------------------------
// MFMA conv1x1 GEMM. K=512, tile 64x64, 4 waves.
// MODE 1 additionally writes oT = v transposed [bh][d][m].
// ---------------------------------------------------------------------------
template<int MODE>
__global__ __launch_bounds__(256) void gemm_mfma(
    const u16* __restrict__ A, const void* __restrict__ W,
    const void* __restrict__ bias, u16* __restrict__ o0, u16* __restrict__ o1,
    u16* __restrict__ oT, void* __restrict__ ob, int M,
    const int* __restrict__ dtf) {
  const int f32 = *dtf;
  const int b = blockIdx.z, m0 = blockIdx.x * 64, oo0 = blockIdx.y * 64;
  const int t = threadIdx.x, w = t >> 6, lane = t & 63;
  const int quad = lane >> 4, c = lane & 15;
  __shared__ __align__(16) u16 As[64][72];
  __shared__ __align__(16) u16 Ws[64][72];
  f32x4 acc[4];
#pragma unroll
  for (int ot = 0; ot < 4; ++ot) acc[ot] = (f32x4){0.f, 0.f, 0.f, 0.f};
  const u16* Ab = A + (size_t)b * M * 512;
  const int srow = t >> 2, scol = (t & 3) * 16;

  for (int k0 = 0; k0 < 512; k0 += 64) {
    __syncthreads();
    {
      const u16* ga = Ab + (size_t)(m0 + srow) * 512 + k0 + scol;
      *reinterpret_cast<uint4*>(&As[srow][scol])     = *reinterpret_cast<const uint4*>(ga);
      *reinterpret_cast<uint4*>(&As[srow][scol + 8]) = *reinterpret_cast<const uint4*>(ga + 8);
      if (f32) {
        const float* gw = (const float*)W + (size_t)(oo0 + srow) * 512 + k0 + scol;
#pragma unroll
        for (int e = 0; e < 16; ++e) Ws[srow][scol + e] = f2bs(gw[e]);
      } else {
        const u16* gw = (const u16*)W + (size_t)(oo0 + srow) * 512 + k0 + scol;
        *reinterpret_cast<uint4*>(&Ws[srow][scol])     = *reinterpret_cast<const uint4*>(gw);
        *reinterpret_cast<uint4*>(&Ws[srow][scol + 8]) = *reinterpret_cast<const uint4*>(gw + 8);
      }
    }
    __syncthreads();
#pragma unroll
    for (int ks = 0; ks < 2; ++ks) {
      bf16x8 av = *reinterpret_cast<const bf16x8*>(&As[w * 16 + c][ks * 32 + quad * 8]);
#pragma unroll
      for (int ot = 0; ot < 4; ++ot) {
        bf16x8 wv = *reinterpret_cast<const bf16x8*>(&Ws[ot * 16 + c][ks * 32 + quad * 8]);
        if (MODE == 3)
          acc[ot] = __builtin_amdgcn_mfma_f32_16x16x32_bf16(wv, av, acc[ot], 0, 0, 0);
        else
          acc[ot] = __builtin_amdgcn_mfma_f32_16x16x32_bf16(av, wv, acc[ot], 0, 0, 0);
      }
    }
  }

  if (MODE == 0) {
#pragma unroll
    for (int ot = 0; ot < 4; ++ot) {
      int o = oo0 + ot * 16 + c;
      float bv = ldf(bias, o, f32);
      int h = o >> 6, d = o & 63;
#pragma unroll
      for (int r = 0; r < 4; ++r) {
        int m = m0 + w * 16 + quad * 4 + r;
        o0[((size_t)(b * 8 + h) * M + m) * 64 + d] = f2bs(acc[ot][r] + bv);
      }
    }
  } else if (MODE == 1) {
#pragma unroll
    for (int ot = 0; ot < 4; ++ot) {
      int o = oo0 + ot * 16 + c;
      float bv = ldf(bias, o, f32);
      int hh = o >> 7, jj = o & 127;
#pragma unroll
      for (int r = 0; r < 4; ++r) {
        int m = m0 + w * 16 + quad * 4 + r;
        u16 val = f2bs(acc[ot][r] + bv);
        if (jj < 64) {
          o0[((size_t)(b * 8 + hh) * M + m) * 64 + jj] = val;
        } else {
          o1[((size_t)(b * 8 + hh) * M + m) * 64 + (jj & 63)] = val;
          oT[((size_t)(b * 8 + hh) * 64 + (jj & 63)) * M + m] = val;
        }
      }
    }
  } else {
#pragma unroll
    for (int ot = 0; ot < 4; ++ot) {
#pragma unroll
      for (int r = 0; r < 4; ++r) {
        int o = oo0 + ot * 16 + quad * 4 + r;
        float val = acc[ot][r] + ldf(bias, o, f32);
        int m = m0 + w * 16 + c;
        size_t oi_ = ((size_t)(b * 512 + o)) * M + m;
        if (f32) ((float*)ob)[oi_] = val;
        else     ((u16*)ob)[oi_] = f2bs(val);
      }
    }
  }
}

// heat[b,mu] = mean over C and 2x2 spatial of x, computed from coalesced xT
__global__ __launch_bounds__(256) void heat_kernel(const u16* __restrict__ xT,
                                                   float* __restrict__ heat) {
  int bm = blockIdx.x;
  int b = bm >> 10, mu = bm & 1023;
  int hu = mu >> 5, wu = mu & 31;
  int t = threadIdx.x;
  int row = t >> 6, seg = t & 63;
  int y = hu * 2 + (row >> 1), xx = wu * 2 + (row & 1);
  const uint4* p = reinterpret_cast<const uint4*>(
      xT + ((size_t)b * 4096 + y * 64 + xx) * 512);
  uint4 v = p[seg];
  float s = 0.f;
#pragma unroll
  for (int j = 0; j < 4; ++j) {
    unsigned w = (j == 0) ? v.x : (j == 1) ? v.y : (j == 2) ? v.z : v.w;
    s += bs2f((u16)(w & 0xFFFF)) + bs2f((u16)(w >> 16));
  }
  __shared__ float r[256];
  r[t] = s; __syncthreads();
  for (int off = 128; off; off >>= 1) { if (t < off) r[t] += r[t + off]; __syncthreads(); }
  if (t == 0) heat[bm] = r[0] * (1.0f / 2048.0f);
}

// stage 1 of qsum: partial[bh][chunk][d] = sum over 256 n-rows
__global__ __launch_bounds__(256) void qsum_partial(const u16* __restrict__ q,
                                                    float* __restrict__ qsumP) {
  int bh = blockIdx.x, ch = blockIdx.y, t = threadIdx.x;
  int d = t & 63, g = t >> 6;
  int n0 = ch * 256 + g * 64;
  float s = 0.f;
  for (int r = 0; r < 64; ++r)
    s += bs2f(q[((size_t)bh * 4096 + n0 + r) * 64 + d]);
  __shared__ float r[256];
  r[t] = s; __syncthreads();
  if (t < 64) qsumP[(size_t)(bh * 16 + ch) * 64 + t] = r[t] + r[t + 64] + r[t + 128] + r[t + 192];
}

// scores -> top-16 coarse cells -> 64 full-res positions into posb
__global__ __launch_bounds__(256) void topk_kernel(
    const float* __restrict__ qsumP, const u16* __restrict__ k,
    const float* __restrict__ heat, const void* __restrict__ gumbel,
    int* __restrict__ posb, const int* __restrict__ dtf) {
  const int f32 = *dtf;
  int bh = blockIdx.x, b = bh >> 3, t = threadIdx.x;
  __shared__ float qs[64];
  __shared__ float s[1024];
  __shared__ float rv[256];
  __shared__ int   ri[256];
  if (t < 64) {
    float acc = 0.f;
    for (int ch = 0; ch < 16; ++ch) acc += qsumP[(size_t)(bh * 16 + ch) * 64 + t];
    qs[t] = acc;
  }
  __syncthreads();
  for (int j = 0; j < 4; ++j) {
    int m = t + j * 256;
    const u16* kr = k + ((size_t)bh * 1024 + m) * 64;
    float dot = 0.f;
    for (int d = 0; d < 64; ++d) dot += qs[d] * bs2f(kr[d]);
    s[m] = dot * (0.125f / 4096.0f) * heat[b * 1024 + m] + ldf(gumbel, (size_t)bh * 1024 + m, f32);
  }
  __syncthreads();
  for (int it = 0; it < 16; ++it) {
    float bv = -1e30f; int bi = 0x7fffffff;
    for (int j = 0; j < 4; ++j) {
      int m = t + j * 256; float vv = s[m];
      if (vv > bv || (vv == bv && m < bi)) { bv = vv; bi = m; }
    }
    rv[t] = bv; ri[t] = bi; __syncthreads();
    for (int off = 128; off; off >>= 1) {
      if (t < off) {
        if (rv[t + off] > rv[t] || (rv[t + off] == rv[t] && ri[t + off] < ri[t])) {
          rv[t] = rv[t + off]; ri[t] = ri[t + off];
        }
      }
      __syncthreads();
    }
    if (t == 0) {
      int mi = ri[0]; s[mi] = -1e30f;
      int hy = (mi >> 5) * 2, wx = (mi & 31) * 2;
      posb[bh * 64 + it]      = hy * 64 + wx;
      posb[bh * 64 + 16 + it] = hy * 64 + wx + 1;
      posb[bh * 64 + 32 + it] = (hy + 1) * 64 + wx;
      posb[bh * 64 + 48 + it] = (hy + 1) * 64 + wx + 1;
    }
    __syncthreads();
  }
}

// ---------------------------------------------------------------------------
// gather_kv as MFMA GEMM (round-5 structure).
// ---------------------------------------------------------------------------
__global__ __launch_bounds__(256) void gather_kv_mfma(
    const u16* __restrict__ xT, const void* __restrict__ kv_w,
    const void* __restrict__ kv_b, const int* __restrict__ posb,
    u16* __restrict__ tkb, u16* __restrict__ tvTb,
    const int* __restrict__ dtf) {
  const int f32 = *dtf;
  const int bh = blockIdx.x, b = bh >> 3, h = bh & 7;
  const int half = blockIdx.y;
  const int t = threadIdx.x, w = t >> 6, lane = t & 63;
  const int quad = lane >> 4, c = lane & 15;
  __shared__ int pos[64];
  __shared__ __align__(16) u16 As[64][72];
  __shared__ __align__(16) u16 Ws[64][72];
  if (t < 64) pos[t] = posb[bh * 64 + t];
  __syncthreads();
  const int obase = h * 128 + half * 64;
  const int srow = t >> 2, scol = (t & 3) * 16;
  const int arow = pos[srow];
  f32x4 acc[4];
#pragma unroll
  for (int ot = 0; ot < 4; ++ot) acc[ot] = (f32x4){0.f, 0.f, 0.f, 0.f};

  for (int k0 = 0; k0 < 512; k0 += 64) {
    __syncthreads();
    {
      const u16* ga = xT + ((size_t)b * 4096 + arow) * 512 + k0 + scol;
      *reinterpret_cast<uint4*>(&As[srow][scol])     = *reinterpret_cast<const uint4*>(ga);
      *reinterpret_cast<uint4*>(&As[srow][scol + 8]) = *reinterpret_cast<const uint4*>(ga + 8);
      if (f32) {
        const float* gw = (const float*)kv_w + (size_t)(obase + srow) * 512 + k0 + scol;
#pragma unroll
        for (int e = 0; e < 16; ++e) Ws[srow][scol + e] = f2bs(gw[e]);
      } else {
        const u16* gw = (const u16*)kv_w + (size_t)(obase + srow) * 512 + k0 + scol;
        *reinterpret_cast<uint4*>(&Ws[srow][scol])     = *reinterpret_cast<const uint4*>(gw);
        *reinterpret_cast<uint4*>(&Ws[srow][scol + 8]) = *reinterpret_cast<const uint4*>(gw + 8);
      }
    }
    __syncthreads();
#pragma unroll
    for (int ks = 0; ks < 2; ++ks) {
      bf16x8 av = *reinterpret_cast<const bf16x8*>(&As[w * 16 + c][ks * 32 + quad * 8]);
#pragma unroll
      for (int ot = 0; ot < 4; ++ot) {
        bf16x8 wv = *reinterpret_cast<const bf16x8*>(&Ws[ot * 16 + c][ks * 32 + quad * 8]);
        acc[ot] = __builtin_amdgcn_mfma_f32_16x16x32_bf16(av, wv, acc[ot], 0, 0, 0);
      }
    }
  }

#pragma unroll
  for (int ot = 0; ot < 4; ++ot) {
    int d = ot * 16 + c;
    float bv = ldf(kv_b, obase + d, f32);
#pragma unroll
    for (int r = 0; r < 4; ++r) {
      int m = w * 16 + quad * 4 + r;
      u16 val = f2bs(acc[ot][r] + bv);
      if (half) tvTb[((size_t)bh * 64 + d) * 64 + m] = val;
      else      tkb[((size_t)bh * 64 + m) * 64 + d] = val;
    }
  }
}

// ---------------------------------------------------------------------------
// coarse attention, barrier-free: K and V^T A-frags straight from global
// (L2-resident), per-wave P^T LDS round trip only. Block = 128 n, wave = 32 n.
// ---------------------------------------------------------------------------
__global__ __launch_bounds__(256) void coarse_attn_mfma(
    const u16* __restrict__ q, const u16* __restrict__ k,
    const u16* __restrict__ vT, u16* __restrict__ coarse) {
  const int bh = blockIdx.y;
  const int n0 = blockIdx.x * 128;
  const int t = threadIdx.x, w = t >> 6, lane = t & 63;
  const int quad = lane >> 4, c = lane & 15;
  __shared__ __align__(16) u16 Ps[4][2][16][72];

  bf16x8 bq[2][2];
#pragma unroll
  for (int nt = 0; nt < 2; ++nt) {
    const u16* qr = q + ((size_t)bh * 4096 + n0 + w * 32 + nt * 16 + c) * 64;
    bq[nt][0] = *reinterpret_cast<const bf16x8*>(qr + quad * 8);
    bq[nt][1] = *reinterpret_cast<const bf16x8*>(qr + 32 + quad * 8);
  }
  f32x4 po[2][4];
#pragma unroll
  for (int nt = 0; nt < 2; ++nt)
#pragma unroll
    for (int dt = 0; dt < 4; ++dt) po[nt][dt] = (f32x4){0.f, 0.f, 0.f, 0.f};
  float sume[2] = {0.f, 0.f};

  const u16* kbase = k + (size_t)bh * 1024 * 64;
  const u16* vbase = vT + (size_t)bh * 64 * 1024;

  for (int m0 = 0; m0 < 1024; m0 += 64) {
    // QK^T: S^T tiles (col=n, row=m)
    f32x4 st[2][4];
#pragma unroll
    for (int mt = 0; mt < 4; ++mt) {
      const u16* kr = kbase + (size_t)(m0 + mt * 16 + c) * 64;
      bf16x8 ak0 = *reinterpret_cast<const bf16x8*>(kr + quad * 8);
      bf16x8 ak1 = *reinterpret_cast<const bf16x8*>(kr + 32 + quad * 8);
#pragma unroll
      for (int nt = 0; nt < 2; ++nt) {
        f32x4 acc = (f32x4){0.f, 0.f, 0.f, 0.f};
        acc = __builtin_amdgcn_mfma_f32_16x16x32_bf16(ak0, bq[nt][0], acc, 0, 0, 0);
        acc = __builtin_amdgcn_mfma_f32_16x16x32_bf16(ak1, bq[nt][1], acc, 0, 0, 0);
        st[nt][mt] = acc;
      }
    }
    // exp + pack P^T (per-wave LDS, no barrier) + column sums
#pragma unroll
    for (int nt = 0; nt < 2; ++nt) {
      float cs = 0.f;
#pragma unroll
      for (int mt = 0; mt < 4; ++mt) {
        float e0 = __expf(st[nt][mt][0] * 0.125f);
        float e1 = __expf(st[nt][mt][1] * 0.125f);
        float e2 = __expf(st[nt][mt][2] * 0.125f);
        float e3 = __expf(st[nt][mt][3] * 0.125f);
        cs += (e0 + e1) + (e2 + e3);
        ushort4 pw;
        pw.x = f2bs(e0); pw.y = f2bs(e1); pw.z = f2bs(e2); pw.w = f2bs(e3);
        *reinterpret_cast<ushort4*>(&Ps[w][nt][c][mt * 16 + quad * 4]) = pw;
      }
      cs += __shfl_xor(cs, 16, 64);
      cs += __shfl_xor(cs, 32, 64);
      sume[nt] += cs;
    }
    // PV: O^T += V^T . P^T (V^T frags from global, reused across both n-tiles)
#pragma unroll
    for (int s = 0; s < 2; ++s) {
      bf16x8 bp0 = *reinterpret_cast<const bf16x8*>(&Ps[w][0][c][s * 32 + quad * 8]);
      bf16x8 bp1 = *reinterpret_cast<const bf16x8*>(&Ps[w][1][c][s * 32 + quad * 8]);
#pragma unroll
      for (int dt = 0; dt < 4; ++dt) {
        bf16x8 av = *reinterpret_cast<const bf16x8*>(
            vbase + (size_t)(dt * 16 + c) * 1024 + m0 + s * 32 + quad * 8);
        po[0][dt] = __builtin_amdgcn_mfma_f32_16x16x32_bf16(av, bp0, po[0][dt], 0, 0, 0);
        po[1][dt] = __builtin_amdgcn_mfma_f32_16x16x32_bf16(av, bp1, po[1][dt], 0, 0, 0);
      }
    }
  }

#pragma unroll
  for (int nt = 0; nt < 2; ++nt) {
    float inv = 1.0f / sume[nt];
    u16* orow = coarse + ((size_t)bh * 4096 + n0 + w * 32 + nt * 16 + c) * 64;
#pragma unroll
    for (int dt = 0; dt < 4; ++dt) {
      ushort4 r;
      r.x = f2bs(po[nt][dt][0] * inv); r.y = f2bs(po[nt][dt][1] * inv);
      r.z = f2bs(po[nt][dt][2] * inv); r.w = f2bs(po[nt][dt][3] * inv);
      *reinterpret_cast<ushort4*>(&orow[dt * 16 + quad * 4]) = r;
    }
  }
}

// depthwise 7x7 conv on v (bf16) -> vpe bf16
__global__ __launch_bounds__(256) void dwconv_kernel(
    const u16* __restrict__ v, const void* __restrict__ pe_w,
    const void* __restrict__ pe_b, u16* __restrict__ vpe,
    const int* __restrict__ dtf) {
  const int f32 = *dtf;
  int bc = blockIdx.x;
  int b = bc >> 9, c = bc & 511;
  int h = c >> 6, d = c & 63;
  int t = threadIdx.x;
  __shared__ float img[1024];
  __shared__ float wts[49];
  for (int i = t; i < 1024; i += 256)
    img[i] = bs2f(v[((size_t)(b * 8 + h) * 1024 + i) * 64 + d]);
  if (t < 49) wts[t] = ldf(pe_w, c * 49 + t, f32);
  float bias = ldf(pe_b, c, f32);
  __syncthreads();
  for (int i = t; i < 1024; i += 256) {
    int y = i >> 5, xx = i & 31;
    float a = 0.f;
#pragma unroll
    for (int ky = 0; ky < 7; ++ky) {
      int yy = y + ky - 3;
      if ((unsigned)yy >= 32u) continue;
#pragma unroll
      for (int kx = 0; kx < 7; ++kx) {
        int xc = xx + kx - 3;
        if ((unsigned)xc >= 32u) continue;
        a += img[yy * 32 + xc] * wts[ky * 7 + kx];
      }
    }
    vpe[(size_t)bc * 1024 + i] = f2bs(a + bias);
  }
}

// ---------------------------------------------------------------------------
// fused fine attention + gate MFMA + combine + bilinear vpe add -> xsT bf16.
// ---------------------------------------------------------------------------
__global__ __launch_bounds__(256) void fine_mfma(
    const u16* __restrict__ q, const u16* __restrict__ tkb,
    const u16* __restrict__ tvTb, const u16* __restrict__ co,
    const void* __restrict__ gate_w, const void* __restrict__ gate_b,
    const u16* __restrict__ vpe, u16* __restrict__ xsT,
    const int* __restrict__ dtf) {
  const int f32 = *dtf;
  const int bh = blockIdx.y, b = bh >> 3, h = bh & 7;
  const int y = blockIdx.x;
  const int n0 = y * 64;
  const int t = threadIdx.x, w = t >> 6, lane = t & 63;
  const int quad = lane >> 4, c = lane & 15;

  __shared__ __align__(16) u16 gw[64][136];
  __shared__ __align__(16) u16 fus[4][16][136];
  __shared__ __align__(16) u16 vl[64][66];
  __shared__ __align__(16) u16 outb[4][16][72];
  __shared__ float gbl[64];

  int jy = y >> 1, y0, y1; float wy0, wy1;
  if ((y & 1) == 0) { y0 = (jy > 0) ? jy - 1 : 0; y1 = jy; wy0 = 0.25f; wy1 = 0.75f; }
  else              { y0 = jy; y1 = (jy < 31) ? jy + 1 : 31; wy0 = 0.75f; wy1 = 0.25f; }

  for (int i = t; i < 8192; i += 256) {
    gw[i >> 7][i & 127] = f32 ? f2bs(((const float*)gate_w)[i]) : ((const u16*)gate_w)[i];
  }
  for (int i = t; i < 4096; i += 256) {
    int ch = i >> 6, r = (i >> 5) & 1, xx = i & 31;
    int yy = r ? y1 : y0;
    vl[ch][r * 33 + xx] = vpe[((size_t)(b * 512 + h * 64 + ch)) * 1024 + yy * 32 + xx];
  }
  if (t < 64) gbl[t] = ldf(gate_b, t, f32);

  const int n = n0 + w * 16 + c;
  bf16x8 bq[2];
  {
    const u16* qr = q + ((size_t)bh * 4096 + n) * 64;
    bq[0] = *reinterpret_cast<const bf16x8*>(qr + quad * 8);
    bq[1] = *reinterpret_cast<const bf16x8*>(qr + 32 + quad * 8);
  }
  __syncthreads();

  f32x4 st[4];
#pragma unroll
  for (int mt = 0; mt < 4; ++mt) {
    f32x4 acc = (f32x4){0.f, 0.f, 0.f, 0.f};
#pragma unroll
    for (int s = 0; s < 2; ++s) {
      bf16x8 ak = *reinterpret_cast<const bf16x8*>(
          &tkb[((size_t)bh * 64 + mt * 16 + c) * 64 + s * 32 + quad * 8]);
      acc = __builtin_amdgcn_mfma_f32_16x16x32_bf16(ak, bq[s], acc, 0, 0, 0);
    }
    st[mt] = acc;
  }
  float sume = 0.f;
#pragma unroll
  for (int mt = 0; mt < 4; ++mt) {
    float e0 = __expf(st[mt][0] * 0.125f);
    float e1 = __expf(st[mt][1] * 0.125f);
    float e2 = __expf(st[mt][2] * 0.125f);
    float e3 = __expf(st[mt][3] * 0.125f);
    sume += (e0 + e1) + (e2 + e3);
    ushort4 pw;
    pw.x = f2bs(e0); pw.y = f2bs(e1); pw.z = f2bs(e2); pw.w = f2bs(e3);
    *reinterpret_cast<ushort4*>(&fus[w][c][mt * 16 + quad * 4]) = pw;
  }
  sume += __shfl_xor(sume, 16, 64);
  sume += __shfl_xor(sume, 32, 64);
  float inv = 1.0f / sume;
  __syncthreads();

  f32x4 po[4];
#pragma unroll
  for (int dt = 0; dt < 4; ++dt) po[dt] = (f32x4){0.f, 0.f, 0.f, 0.f};
#pragma unroll
  for (int s = 0; s < 2; ++s) {
    bf16x8 bp = *reinterpret_cast<const bf16x8*>(&fus[w][c][s * 32 + quad * 8]);
#pragma unroll
    for (int dt = 0; dt < 4; ++dt) {
      bf16x8 av = *reinterpret_cast<const bf16x8*>(
          &tvTb[((size_t)bh * 64 + dt * 16 + c) * 64 + s * 32 + quad * 8]);
      po[dt] = __builtin_amdgcn_mfma_f32_16x16x32_bf16(av, bp, po[dt], 0, 0, 0);
    }
  }
  __syncthreads();

  {
    const u16* crow = co + ((size_t)bh * 4096 + n) * 64 + quad * 16;
    *reinterpret_cast<uint4*>(&fus[w][c][quad * 16])     = *reinterpret_cast<const uint4*>(crow);
    *reinterpret_cast<uint4*>(&fus[w][c][quad * 16 + 8]) = *reinterpret_cast<const uint4*>(crow + 8);
  }
#pragma unroll
  for (int dt = 0; dt < 4; ++dt) {
    ushort4 rw;
    rw.x = f2bs(po[dt][0] * inv); rw.y = f2bs(po[dt][1] * inv);
    rw.z = f2bs(po[dt][2] * inv); rw.w = f2bs(po[dt][3] * inv);
    *reinterpret_cast<ushort4*>(&fus[w][c][64 + dt * 16 + quad * 4]) = rw;
  }
  __syncthreads();

  f32x4 ga[4];
#pragma unroll
  for (int ot = 0; ot < 4; ++ot) ga[ot] = (f32x4){0.f, 0.f, 0.f, 0.f};
#pragma unroll
  for (int s = 0; s < 4; ++s) {
    bf16x8 bf = *reinterpret_cast<const bf16x8*>(&fus[w][c][s * 32 + quad * 8]);
#pragma unroll
    for (int ot = 0; ot < 4; ++ot) {
      bf16x8 ag = *reinterpret_cast<const bf16x8*>(&gw[ot * 16 + c][s * 32 + quad * 8]);
      ga[ot] = __builtin_amdgcn_mfma_f32_16x16x32_bf16(ag, bf, ga[ot], 0, 0, 0);
    }
  }

  const int x = w * 16 + c;
  int jx = x >> 1, x0, x1; float wx0, wx1;
  if ((x & 1) == 0) { x0 = (jx > 0) ? jx - 1 : 0; x1 = jx; wx0 = 0.25f; wx1 = 0.75f; }
  else              { x0 = jx; x1 = (jx < 31) ? jx + 1 : 31; wx0 = 0.75f; wx1 = 0.25f; }
#pragma unroll
  for (int dt = 0; dt < 4; ++dt) {
    ushort4 ow;
    u16 tmp[4];
#pragma unroll
    for (int r = 0; r < 4; ++r) {
      int row = dt * 16 + quad * 4 + r;
      float ref = po[dt][r] * inv;
      float coar = bs2f(fus[w][c][row]);
      float g = 1.0f / (1.0f + __expf(-(ga[dt][r] + gbl[row])));
      float vv = wy0 * (wx0 * bs2f(vl[row][x0]) + wx1 * bs2f(vl[row][x1])) +
                 wy1 * (wx0 * bs2f(vl[row][33 + x0]) + wx1 * bs2f(vl[row][33 + x1]));
      tmp[r] = f2bs(g * ref + (1.0f - g) * coar + vv);
    }
    ow.x = tmp[0]; ow.y = tmp[1]; ow.z = tmp[2]; ow.w = tmp[3];
    *reinterpret_cast<ushort4*>(&outb[w][c][dt * 16 + quad * 4]) = ow;
  }
  __syncthreads();

  {
    int nl = lane >> 2, cs = (lane & 3) * 16;
    u16* dst = xsT + ((size_t)b * 4096 + n0 + w * 16 + nl) * 512 + h * 64 + cs;
    *reinterpret_cast<uint4*>(dst)     = *reinterpret_cast<const uint4*>(&outb[w][nl][cs]);
    *reinterpret_cast<uint4*>(dst + 8) = *reinterpret_cast<const uint4*>(&outb[w][nl][cs + 8]);
  }
}

extern "C" void kernel_launch(void* const* d_in, const int* in_sizes, int n_in,
                              void* d_out, int out_size, void* d_ws, size_t ws_size,
                              hipStream_t stream) {
  const void* x    = d_in[0];
  const void* up   = d_in[1];
  const void* gum  = d_in[2];
  const void* q_w  = d_in[3];
  const void* q_b  = d_in[4];
  const void* kv_w = d_in[5];
  const void* kv_b = d_in[6];
  const void* p_w  = d_in[7];
  const void* p_b  = d_in[8];
  const void* pe_w = d_in[9];
  const void* pe_b = d_in[10];
  const void* g_w  = d_in[11];
  const void* g_b  = d_in[12];

  float* ws    = (float*)d_ws;
  int*   dtf   = (int*)ws;                   // 16
  float* qsumP = ws + 16;                    // 16384
  float* heat  = qsumP + 16384;              // 2048
  int*   posb  = (int*)(heat + 2048);        // 1024
  u16*   tkb   = (u16*)(posb + 1024);        // 65536
  u16*   tvTb  = tkb + 65536;                // 65536
  u16*   qb    = tvTb + 65536;               // 4M
  u16*   kb    = qb + 4194304;               // 1M
  u16*   vb    = kb + 1048576;               // 1M
  u16*   vTb   = vb + 1048576;               // 1M
  u16*   xT    = vTb + 1048576;              // 4M
  u16*   upT   = xT + 4194304;               // 1M
  u16*   co    = upT + 1048576;              // 4M
  u16*   xsT   = co + 4194304;               // 4M
  u16*   vpe   = xsT + 4194304;              // 1M   (~36 MB total)

  dim3 blk(256);
  hipMemsetAsync(dtf, 0, 4, stream);
  detect_dtype<<<dim3(64), blk, 0, stream>>>((const uint4*)x, dtf);
  transpose_bf16<<<dim3(64, 8, 2), blk, 0, stream>>>(x, xT, 4096, dtf);
  transpose_bf16<<<dim3(16, 8, 2), blk, 0, stream>>>(up, upT, 1024, dtf);
  heat_kernel<<<dim3(2048), blk, 0, stream>>>(xT, heat);
  gemm_mfma<0><<<dim3(64, 8, 2), blk, 0, stream>>>(xT, q_w, q_b, qb, nullptr, nullptr, nullptr, 4096, dtf);
  gemm_mfma<1><<<dim3(16, 16, 2), blk, 0, stream>>>(upT, kv_w, kv_b, kb, vb, vTb, nullptr, 1024, dtf);
  qsum_partial<<<dim3(16, 16), blk, 0, stream>>>(qb, qsumP);
  topk_kernel<<<dim3(16), blk, 0, stream>>>(qsumP, kb, heat, gum, posb, dtf);
  gather_kv_mfma<<<dim3(16, 2), blk, 0, stream>>>(xT, kv_w, kv_b, posb, tkb, tvTb, dtf);
  coarse_attn_mfma<<<dim3(32, 16), blk, 0, stream>>>(qb, kb, vTb, co);
  dwconv_kernel<<<dim3(1024), blk, 0, stream>>>(vb, pe_w, pe_b, vpe, dtf);
  fine_mfma<<<dim3(64, 16), blk, 0, stream>>>(qb, tkb, tvTb, co, g_w, g_b, vpe, xsT, dtf);
  gemm_mfma<3><<<dim3(64, 8, 2), blk, 0, stream>>>(xsT, p_w, p_b, nullptr, nullptr, nullptr, d_out, 4096, dtf);
}

// Round 8
// 289.967 us; speedup vs baseline: 5.8137x; 1.1378x over previous
//
#include <hip/hip_runtime.h>
#include <hip/hip_bf16.h>
#include <cstdint>

typedef __hip_bfloat16 bf16;
typedef unsigned short u16;
typedef __attribute__((ext_vector_type(8))) short bf16x8;
typedef __attribute__((ext_vector_type(4))) float f32x4;

static __device__ __forceinline__ float b2f(bf16 v) { return __bfloat162float(v); }
static __device__ __forceinline__ float bs2f(u16 s) {
  unsigned int u = ((unsigned int)s) << 16;
  float f;
  __builtin_memcpy(&f, &u, 4);
  return f;
}
static __device__ __forceinline__ u16 f2bs(float f) {
  bf16 h = __float2bfloat16(f);
  u16 s;
  __builtin_memcpy(&s, &h, 2);
  return s;
}
// dual-dtype load: f32!=0 -> buffer is float32, else packed bf16
static __device__ __forceinline__ float ldf(const void* p, size_t i, int f32) {
  return f32 ? ((const float*)p)[i] : bs2f(((const u16*)p)[i]);
}

// ---------------------------------------------------------------------------
// dtype detection on a 256 KB sample of x.
// ---------------------------------------------------------------------------
__global__ __launch_bounds__(256) void detect_dtype(const uint4* __restrict__ xs,
                                                    int* __restrict__ flag) {
  int i = blockIdx.x * 256 + threadIdx.x;
  uint4 v = xs[i];
  bool hit = false;
#pragma unroll
  for (int j = 0; j < 4; ++j) {
    unsigned w = (j == 0) ? v.x : (j == 1) ? v.y : (j == 2) ? v.z : v.w;
    if ((w & 0x7F80u) == 0x7F80u) hit = true;
    if ((w & 0x7F800000u) == 0x7F800000u) hit = true;
  }
  unsigned long long mask = __ballot(hit);
  if (mask != 0ull && (threadIdx.x & 63) == 0) atomicOr(flag, 1);
}

// ---------------------------------------------------------------------------
// transpose [b][c=512][N] (dual dtype) -> [b][N][512] bf16; grid (N/64,8,B)
// ---------------------------------------------------------------------------
__global__ __launch_bounds__(256) void transpose_bf16(
    const void* __restrict__ src, u16* __restrict__ dst, int N,
    const int* __restrict__ dtf) {
  const int f32 = *dtf;
  const int b = blockIdx.z, n0 = blockIdx.x * 64, c0 = blockIdx.y * 64;
  const int t = threadIdx.x;
  __shared__ __align__(16) u16 tile[64][72];
#pragma unroll
  for (int j = 0; j < 2; ++j) {
    int cc = (t >> 3) + j * 32;
    int nn = (t & 7) * 8;
    u16 tmp[8];
    if (f32) {
      const float* s4 = (const float*)src + ((size_t)(b * 512 + c0 + cc)) * N + n0 + nn;
#pragma unroll
      for (int u = 0; u < 8; ++u) tmp[u] = f2bs(s4[u]);
    } else {
      *reinterpret_cast<uint4*>(tmp) = *reinterpret_cast<const uint4*>(
          (const u16*)src + ((size_t)(b * 512 + c0 + cc)) * N + n0 + nn);
    }
    *reinterpret_cast<uint4*>(&tile[cc][nn]) = *reinterpret_cast<const uint4*>(tmp);
  }
  __syncthreads();
#pragma unroll
  for (int j = 0; j < 2; ++j) {
    int nn = (t >> 3) + j * 32;
    int cc0 = (t & 7) * 8;
    u16 tmp[8];
#pragma unroll
    for (int u = 0; u < 8; ++u) tmp[u] = tile[cc0 + u][nn];
    *reinterpret_cast<uint4*>(&dst[((size_t)b * N + n0 + nn) * 512 + c0 + cc0]) =
        *reinterpret_cast<const uint4*>(tmp);
  }
}

// ---------------------------------------------------------------------------
// MFMA conv1x1 GEMM. K=512, tile 64x64, 4 waves.
// MODE 1 additionally writes oT = v transposed [bh][d][m].
// ---------------------------------------------------------------------------
template<int MODE>
__global__ __launch_bounds__(256) void gemm_mfma(
    const u16* __restrict__ A, const void* __restrict__ W,
    const void* __restrict__ bias, u16* __restrict__ o0, u16* __restrict__ o1,
    u16* __restrict__ oT, void* __restrict__ ob, int M,
    const int* __restrict__ dtf) {
  const int f32 = *dtf;
  const int b = blockIdx.z, m0 = blockIdx.x * 64, oo0 = blockIdx.y * 64;
  const int t = threadIdx.x, w = t >> 6, lane = t & 63;
  const int quad = lane >> 4, c = lane & 15;
  __shared__ __align__(16) u16 As[64][72];
  __shared__ __align__(16) u16 Ws[64][72];
  f32x4 acc[4];
#pragma unroll
  for (int ot = 0; ot < 4; ++ot) acc[ot] = (f32x4){0.f, 0.f, 0.f, 0.f};
  const u16* Ab = A + (size_t)b * M * 512;
  const int srow = t >> 2, scol = (t & 3) * 16;

  for (int k0 = 0; k0 < 512; k0 += 64) {
    __syncthreads();
    {
      const u16* ga = Ab + (size_t)(m0 + srow) * 512 + k0 + scol;
      *reinterpret_cast<uint4*>(&As[srow][scol])     = *reinterpret_cast<const uint4*>(ga);
      *reinterpret_cast<uint4*>(&As[srow][scol + 8]) = *reinterpret_cast<const uint4*>(ga + 8);
      if (f32) {
        const float* gw = (const float*)W + (size_t)(oo0 + srow) * 512 + k0 + scol;
#pragma unroll
        for (int e = 0; e < 16; ++e) Ws[srow][scol + e] = f2bs(gw[e]);
      } else {
        const u16* gw = (const u16*)W + (size_t)(oo0 + srow) * 512 + k0 + scol;
        *reinterpret_cast<uint4*>(&Ws[srow][scol])     = *reinterpret_cast<const uint4*>(gw);
        *reinterpret_cast<uint4*>(&Ws[srow][scol + 8]) = *reinterpret_cast<const uint4*>(gw + 8);
      }
    }
    __syncthreads();
#pragma unroll
    for (int ks = 0; ks < 2; ++ks) {
      bf16x8 av = *reinterpret_cast<const bf16x8*>(&As[w * 16 + c][ks * 32 + quad * 8]);
#pragma unroll
      for (int ot = 0; ot < 4; ++ot) {
        bf16x8 wv = *reinterpret_cast<const bf16x8*>(&Ws[ot * 16 + c][ks * 32 + quad * 8]);
        if (MODE == 3)
          acc[ot] = __builtin_amdgcn_mfma_f32_16x16x32_bf16(wv, av, acc[ot], 0, 0, 0);
        else
          acc[ot] = __builtin_amdgcn_mfma_f32_16x16x32_bf16(av, wv, acc[ot], 0, 0, 0);
      }
    }
  }

  if (MODE == 0) {
#pragma unroll
    for (int ot = 0; ot < 4; ++ot) {
      int o = oo0 + ot * 16 + c;
      float bv = ldf(bias, o, f32);
      int h = o >> 6, d = o & 63;
#pragma unroll
      for (int r = 0; r < 4; ++r) {
        int m = m0 + w * 16 + quad * 4 + r;
        o0[((size_t)(b * 8 + h) * M + m) * 64 + d] = f2bs(acc[ot][r] + bv);
      }
    }
  } else if (MODE == 1) {
#pragma unroll
    for (int ot = 0; ot < 4; ++ot) {
      int o = oo0 + ot * 16 + c;
      float bv = ldf(bias, o, f32);
      int hh = o >> 7, jj = o & 127;
#pragma unroll
      for (int r = 0; r < 4; ++r) {
        int m = m0 + w * 16 + quad * 4 + r;
        u16 val = f2bs(acc[ot][r] + bv);
        if (jj < 64) {
          o0[((size_t)(b * 8 + hh) * M + m) * 64 + jj] = val;
        } else {
          o1[((size_t)(b * 8 + hh) * M + m) * 64 + (jj & 63)] = val;
          oT[((size_t)(b * 8 + hh) * 64 + (jj & 63)) * M + m] = val;
        }
      }
    }
  } else {
#pragma unroll
    for (int ot = 0; ot < 4; ++ot) {
#pragma unroll
      for (int r = 0; r < 4; ++r) {
        int o = oo0 + ot * 16 + quad * 4 + r;
        float val = acc[ot][r] + ldf(bias, o, f32);
        int m = m0 + w * 16 + c;
        size_t oi_ = ((size_t)(b * 512 + o)) * M + m;
        if (f32) ((float*)ob)[oi_] = val;
        else     ((u16*)ob)[oi_] = f2bs(val);
      }
    }
  }
}

// heat[b,mu] = mean over C and 2x2 spatial of x, computed from coalesced xT
__global__ __launch_bounds__(256) void heat_kernel(const u16* __restrict__ xT,
                                                   float* __restrict__ heat) {
  int bm = blockIdx.x;
  int b = bm >> 10, mu = bm & 1023;
  int hu = mu >> 5, wu = mu & 31;
  int t = threadIdx.x;
  int row = t >> 6, seg = t & 63;
  int y = hu * 2 + (row >> 1), xx = wu * 2 + (row & 1);
  const uint4* p = reinterpret_cast<const uint4*>(
      xT + ((size_t)b * 4096 + y * 64 + xx) * 512);
  uint4 v = p[seg];
  float s = 0.f;
#pragma unroll
  for (int j = 0; j < 4; ++j) {
    unsigned w = (j == 0) ? v.x : (j == 1) ? v.y : (j == 2) ? v.z : v.w;
    s += bs2f((u16)(w & 0xFFFF)) + bs2f((u16)(w >> 16));
  }
  __shared__ float r[256];
  r[t] = s; __syncthreads();
  for (int off = 128; off; off >>= 1) { if (t < off) r[t] += r[t + off]; __syncthreads(); }
  if (t == 0) heat[bm] = r[0] * (1.0f / 2048.0f);
}

// stage 1 of qsum: partial[bh][chunk][d] = sum over 256 n-rows
__global__ __launch_bounds__(256) void qsum_partial(const u16* __restrict__ q,
                                                    float* __restrict__ qsumP) {
  int bh = blockIdx.x, ch = blockIdx.y, t = threadIdx.x;
  int d = t & 63, g = t >> 6;
  int n0 = ch * 256 + g * 64;
  float s = 0.f;
  for (int r = 0; r < 64; ++r)
    s += bs2f(q[((size_t)bh * 4096 + n0 + r) * 64 + d]);
  __shared__ float r[256];
  r[t] = s; __syncthreads();
  if (t < 64) qsumP[(size_t)(bh * 16 + ch) * 64 + t] = r[t] + r[t + 64] + r[t + 128] + r[t + 192];
}

// scores -> top-16 coarse cells -> 64 full-res positions into posb
__global__ __launch_bounds__(256) void topk_kernel(
    const float* __restrict__ qsumP, const u16* __restrict__ k,
    const float* __restrict__ heat, const void* __restrict__ gumbel,
    int* __restrict__ posb, const int* __restrict__ dtf) {
  const int f32 = *dtf;
  int bh = blockIdx.x, b = bh >> 3, t = threadIdx.x;
  __shared__ float qs[64];
  __shared__ float s[1024];
  __shared__ float rv[256];
  __shared__ int   ri[256];
  if (t < 64) {
    float acc = 0.f;
    for (int ch = 0; ch < 16; ++ch) acc += qsumP[(size_t)(bh * 16 + ch) * 64 + t];
    qs[t] = acc;
  }
  __syncthreads();
  for (int j = 0; j < 4; ++j) {
    int m = t + j * 256;
    const u16* kr = k + ((size_t)bh * 1024 + m) * 64;
    float dot = 0.f;
    for (int d = 0; d < 64; ++d) dot += qs[d] * bs2f(kr[d]);
    s[m] = dot * (0.125f / 4096.0f) * heat[b * 1024 + m] + ldf(gumbel, (size_t)bh * 1024 + m, f32);
  }
  __syncthreads();
  for (int it = 0; it < 16; ++it) {
    float bv = -1e30f; int bi = 0x7fffffff;
    for (int j = 0; j < 4; ++j) {
      int m = t + j * 256; float vv = s[m];
      if (vv > bv || (vv == bv && m < bi)) { bv = vv; bi = m; }
    }
    rv[t] = bv; ri[t] = bi; __syncthreads();
    for (int off = 128; off; off >>= 1) {
      if (t < off) {
        if (rv[t + off] > rv[t] || (rv[t + off] == rv[t] && ri[t + off] < ri[t])) {
          rv[t] = rv[t + off]; ri[t] = ri[t + off];
        }
      }
      __syncthreads();
    }
    if (t == 0) {
      int mi = ri[0]; s[mi] = -1e30f;
      int hy = (mi >> 5) * 2, wx = (mi & 31) * 2;
      posb[bh * 64 + it]      = hy * 64 + wx;
      posb[bh * 64 + 16 + it] = hy * 64 + wx + 1;
      posb[bh * 64 + 32 + it] = (hy + 1) * 64 + wx;
      posb[bh * 64 + 48 + it] = (hy + 1) * 64 + wx + 1;
    }
    __syncthreads();
  }
}

// ---------------------------------------------------------------------------
// gather_kv as MFMA GEMM (round-5 structure).
// ---------------------------------------------------------------------------
__global__ __launch_bounds__(256) void gather_kv_mfma(
    const u16* __restrict__ xT, const void* __restrict__ kv_w,
    const void* __restrict__ kv_b, const int* __restrict__ posb,
    u16* __restrict__ tkb, u16* __restrict__ tvTb,
    const int* __restrict__ dtf) {
  const int f32 = *dtf;
  const int bh = blockIdx.x, b = bh >> 3, h = bh & 7;
  const int half = blockIdx.y;
  const int t = threadIdx.x, w = t >> 6, lane = t & 63;
  const int quad = lane >> 4, c = lane & 15;
  __shared__ int pos[64];
  __shared__ __align__(16) u16 As[64][72];
  __shared__ __align__(16) u16 Ws[64][72];
  if (t < 64) pos[t] = posb[bh * 64 + t];
  __syncthreads();
  const int obase = h * 128 + half * 64;
  const int srow = t >> 2, scol = (t & 3) * 16;
  const int arow = pos[srow];
  f32x4 acc[4];
#pragma unroll
  for (int ot = 0; ot < 4; ++ot) acc[ot] = (f32x4){0.f, 0.f, 0.f, 0.f};

  for (int k0 = 0; k0 < 512; k0 += 64) {
    __syncthreads();
    {
      const u16* ga = xT + ((size_t)b * 4096 + arow) * 512 + k0 + scol;
      *reinterpret_cast<uint4*>(&As[srow][scol])     = *reinterpret_cast<const uint4*>(ga);
      *reinterpret_cast<uint4*>(&As[srow][scol + 8]) = *reinterpret_cast<const uint4*>(ga + 8);
      if (f32) {
        const float* gw = (const float*)kv_w + (size_t)(obase + srow) * 512 + k0 + scol;
#pragma unroll
        for (int e = 0; e < 16; ++e) Ws[srow][scol + e] = f2bs(gw[e]);
      } else {
        const u16* gw = (const u16*)kv_w + (size_t)(obase + srow) * 512 + k0 + scol;
        *reinterpret_cast<uint4*>(&Ws[srow][scol])     = *reinterpret_cast<const uint4*>(gw);
        *reinterpret_cast<uint4*>(&Ws[srow][scol + 8]) = *reinterpret_cast<const uint4*>(gw + 8);
      }
    }
    __syncthreads();
#pragma unroll
    for (int ks = 0; ks < 2; ++ks) {
      bf16x8 av = *reinterpret_cast<const bf16x8*>(&As[w * 16 + c][ks * 32 + quad * 8]);
#pragma unroll
      for (int ot = 0; ot < 4; ++ot) {
        bf16x8 wv = *reinterpret_cast<const bf16x8*>(&Ws[ot * 16 + c][ks * 32 + quad * 8]);
        acc[ot] = __builtin_amdgcn_mfma_f32_16x16x32_bf16(av, wv, acc[ot], 0, 0, 0);
      }
    }
  }

#pragma unroll
  for (int ot = 0; ot < 4; ++ot) {
    int d = ot * 16 + c;
    float bv = ldf(kv_b, obase + d, f32);
#pragma unroll
    for (int r = 0; r < 4; ++r) {
      int m = w * 16 + quad * 4 + r;
      u16 val = f2bs(acc[ot][r] + bv);
      if (half) tvTb[((size_t)bh * 64 + d) * 64 + m] = val;
      else      tkb[((size_t)bh * 64 + m) * 64 + d] = val;
    }
  }
}

// ---------------------------------------------------------------------------
// coarse attention: 128 n per block, double-buffered LDS staging of K (rows)
// and V^T (rows, from precomputed vTb — pure uint4 copies). One barrier per
// 64-m chunk; staging loads overlap MFMA compute. Per-wave P^T LDS roundtrip.
// ---------------------------------------------------------------------------
__global__ __launch_bounds__(256) void coarse_attn_mfma(
    const u16* __restrict__ q, const u16* __restrict__ k,
    const u16* __restrict__ vT, u16* __restrict__ coarse) {
  const int bh = blockIdx.y;
  const int n0 = blockIdx.x * 128;
  const int t = threadIdx.x, w = t >> 6, lane = t & 63;
  const int quad = lane >> 4, c = lane & 15;
  __shared__ __align__(16) u16 Ks[2][64][72];
  __shared__ __align__(16) u16 Vt[2][64][72];
  __shared__ __align__(16) u16 Ps[4][2][16][72];

  bf16x8 bq[2][2];
#pragma unroll
  for (int nt = 0; nt < 2; ++nt) {
    const u16* qr = q + ((size_t)bh * 4096 + n0 + w * 32 + nt * 16 + c) * 64;
    bq[nt][0] = *reinterpret_cast<const bf16x8*>(qr + quad * 8);
    bq[nt][1] = *reinterpret_cast<const bf16x8*>(qr + 32 + quad * 8);
  }
  f32x4 po[2][4];
#pragma unroll
  for (int nt = 0; nt < 2; ++nt)
#pragma unroll
    for (int dt = 0; dt < 4; ++dt) po[nt][dt] = (f32x4){0.f, 0.f, 0.f, 0.f};
  float sume[2] = {0.f, 0.f};

  const u16* kbase = k + (size_t)bh * 65536;
  const u16* vbase = vT + (size_t)bh * 65536;
  const int srow = t >> 2, scol = (t & 3) * 16;

  uint4 kr0, kr1, vr0, vr1;
  {
    const u16* gk = kbase + (size_t)srow * 64 + scol;
    kr0 = *reinterpret_cast<const uint4*>(gk);
    kr1 = *reinterpret_cast<const uint4*>(gk + 8);
    const u16* gv = vbase + (size_t)srow * 1024 + scol;
    vr0 = *reinterpret_cast<const uint4*>(gv);
    vr1 = *reinterpret_cast<const uint4*>(gv + 8);
    *reinterpret_cast<uint4*>(&Ks[0][srow][scol])     = kr0;
    *reinterpret_cast<uint4*>(&Ks[0][srow][scol + 8]) = kr1;
    *reinterpret_cast<uint4*>(&Vt[0][srow][scol])     = vr0;
    *reinterpret_cast<uint4*>(&Vt[0][srow][scol + 8]) = vr1;
  }

  for (int ch = 0; ch < 16; ++ch) {
    __syncthreads();
    const int buf = ch & 1;
    if (ch + 1 < 16) {
      int m1 = (ch + 1) * 64;
      const u16* gk = kbase + (size_t)(m1 + srow) * 64 + scol;
      kr0 = *reinterpret_cast<const uint4*>(gk);
      kr1 = *reinterpret_cast<const uint4*>(gk + 8);
      const u16* gv = vbase + (size_t)srow * 1024 + m1 + scol;
      vr0 = *reinterpret_cast<const uint4*>(gv);
      vr1 = *reinterpret_cast<const uint4*>(gv + 8);
    }

    // QK^T: S^T tiles (col=n, row=m)
    f32x4 st[2][4];
#pragma unroll
    for (int mt = 0; mt < 4; ++mt) {
      bf16x8 ak0 = *reinterpret_cast<const bf16x8*>(&Ks[buf][mt * 16 + c][quad * 8]);
      bf16x8 ak1 = *reinterpret_cast<const bf16x8*>(&Ks[buf][mt * 16 + c][32 + quad * 8]);
#pragma unroll
      for (int nt = 0; nt < 2; ++nt) {
        f32x4 acc = (f32x4){0.f, 0.f, 0.f, 0.f};
        acc = __builtin_amdgcn_mfma_f32_16x16x32_bf16(ak0, bq[nt][0], acc, 0, 0, 0);
        acc = __builtin_amdgcn_mfma_f32_16x16x32_bf16(ak1, bq[nt][1], acc, 0, 0, 0);
        st[nt][mt] = acc;
      }
    }
    // exp + pack P^T (per-wave LDS, no barrier) + column sums
#pragma unroll
    for (int nt = 0; nt < 2; ++nt) {
      float cs = 0.f;
#pragma unroll
      for (int mt = 0; mt < 4; ++mt) {
        float e0 = __expf(st[nt][mt][0] * 0.125f);
        float e1 = __expf(st[nt][mt][1] * 0.125f);
        float e2 = __expf(st[nt][mt][2] * 0.125f);
        float e3 = __expf(st[nt][mt][3] * 0.125f);
        cs += (e0 + e1) + (e2 + e3);
        ushort4 pw;
        pw.x = f2bs(e0); pw.y = f2bs(e1); pw.z = f2bs(e2); pw.w = f2bs(e3);
        *reinterpret_cast<ushort4*>(&Ps[w][nt][c][mt * 16 + quad * 4]) = pw;
      }
      cs += __shfl_xor(cs, 16, 64);
      cs += __shfl_xor(cs, 32, 64);
      sume[nt] += cs;
    }
    // PV: O^T += V^T . P^T
#pragma unroll
    for (int s = 0; s < 2; ++s) {
      bf16x8 bp0 = *reinterpret_cast<const bf16x8*>(&Ps[w][0][c][s * 32 + quad * 8]);
      bf16x8 bp1 = *reinterpret_cast<const bf16x8*>(&Ps[w][1][c][s * 32 + quad * 8]);
#pragma unroll
      for (int dt = 0; dt < 4; ++dt) {
        bf16x8 av = *reinterpret_cast<const bf16x8*>(&Vt[buf][dt * 16 + c][s * 32 + quad * 8]);
        po[0][dt] = __builtin_amdgcn_mfma_f32_16x16x32_bf16(av, bp0, po[0][dt], 0, 0, 0);
        po[1][dt] = __builtin_amdgcn_mfma_f32_16x16x32_bf16(av, bp1, po[1][dt], 0, 0, 0);
      }
    }

    if (ch + 1 < 16) {
      const int nb = buf ^ 1;
      *reinterpret_cast<uint4*>(&Ks[nb][srow][scol])     = kr0;
      *reinterpret_cast<uint4*>(&Ks[nb][srow][scol + 8]) = kr1;
      *reinterpret_cast<uint4*>(&Vt[nb][srow][scol])     = vr0;
      *reinterpret_cast<uint4*>(&Vt[nb][srow][scol + 8]) = vr1;
    }
  }

#pragma unroll
  for (int nt = 0; nt < 2; ++nt) {
    float inv = 1.0f / sume[nt];
    u16* orow = coarse + ((size_t)bh * 4096 + n0 + w * 32 + nt * 16 + c) * 64;
#pragma unroll
    for (int dt = 0; dt < 4; ++dt) {
      ushort4 r;
      r.x = f2bs(po[nt][dt][0] * inv); r.y = f2bs(po[nt][dt][1] * inv);
      r.z = f2bs(po[nt][dt][2] * inv); r.w = f2bs(po[nt][dt][3] * inv);
      *reinterpret_cast<ushort4*>(&orow[dt * 16 + quad * 4]) = r;
    }
  }
}

// depthwise 7x7 conv on v (bf16) -> vpe bf16
__global__ __launch_bounds__(256) void dwconv_kernel(
    const u16* __restrict__ v, const void* __restrict__ pe_w,
    const void* __restrict__ pe_b, u16* __restrict__ vpe,
    const int* __restrict__ dtf) {
  const int f32 = *dtf;
  int bc = blockIdx.x;
  int b = bc >> 9, c = bc & 511;
  int h = c >> 6, d = c & 63;
  int t = threadIdx.x;
  __shared__ float img[1024];
  __shared__ float wts[49];
  for (int i = t; i < 1024; i += 256)
    img[i] = bs2f(v[((size_t)(b * 8 + h) * 1024 + i) * 64 + d]);
  if (t < 49) wts[t] = ldf(pe_w, c * 49 + t, f32);
  float bias = ldf(pe_b, c, f32);
  __syncthreads();
  for (int i = t; i < 1024; i += 256) {
    int y = i >> 5, xx = i & 31;
    float a = 0.f;
#pragma unroll
    for (int ky = 0; ky < 7; ++ky) {
      int yy = y + ky - 3;
      if ((unsigned)yy >= 32u) continue;
#pragma unroll
      for (int kx = 0; kx < 7; ++kx) {
        int xc = xx + kx - 3;
        if ((unsigned)xc >= 32u) continue;
        a += img[yy * 32 + xc] * wts[ky * 7 + kx];
      }
    }
    vpe[(size_t)bc * 1024 + i] = f2bs(a + bias);
  }
}

// ---------------------------------------------------------------------------
// fused fine attention + gate MFMA + combine + bilinear vpe add -> xsT bf16.
// ---------------------------------------------------------------------------
__global__ __launch_bounds__(256) void fine_mfma(
    const u16* __restrict__ q, const u16* __restrict__ tkb,
    const u16* __restrict__ tvTb, const u16* __restrict__ co,
    const void* __restrict__ gate_w, const void* __restrict__ gate_b,
    const u16* __restrict__ vpe, u16* __restrict__ xsT,
    const int* __restrict__ dtf) {
  const int f32 = *dtf;
  const int bh = blockIdx.y, b = bh >> 3, h = bh & 7;
  const int y = blockIdx.x;
  const int n0 = y * 64;
  const int t = threadIdx.x, w = t >> 6, lane = t & 63;
  const int quad = lane >> 4, c = lane & 15;

  __shared__ __align__(16) u16 gw[64][136];
  __shared__ __align__(16) u16 fus[4][16][136];
  __shared__ __align__(16) u16 vl[64][66];
  __shared__ __align__(16) u16 outb[4][16][72];
  __shared__ float gbl[64];

  int jy = y >> 1, y0, y1; float wy0, wy1;
  if ((y & 1) == 0) { y0 = (jy > 0) ? jy - 1 : 0; y1 = jy; wy0 = 0.25f; wy1 = 0.75f; }
  else              { y0 = jy; y1 = (jy < 31) ? jy + 1 : 31; wy0 = 0.75f; wy1 = 0.25f; }

  for (int i = t; i < 8192; i += 256) {
    gw[i >> 7][i & 127] = f32 ? f2bs(((const float*)gate_w)[i]) : ((const u16*)gate_w)[i];
  }
  for (int i = t; i < 4096; i += 256) {
    int ch = i >> 6, r = (i >> 5) & 1, xx = i & 31;
    int yy = r ? y1 : y0;
    vl[ch][r * 33 + xx] = vpe[((size_t)(b * 512 + h * 64 + ch)) * 1024 + yy * 32 + xx];
  }
  if (t < 64) gbl[t] = ldf(gate_b, t, f32);

  const int n = n0 + w * 16 + c;
  bf16x8 bq[2];
  {
    const u16* qr = q + ((size_t)bh * 4096 + n) * 64;
    bq[0] = *reinterpret_cast<const bf16x8*>(qr + quad * 8);
    bq[1] = *reinterpret_cast<const bf16x8*>(qr + 32 + quad * 8);
  }
  __syncthreads();

  f32x4 st[4];
#pragma unroll
  for (int mt = 0; mt < 4; ++mt) {
    f32x4 acc = (f32x4){0.f, 0.f, 0.f, 0.f};
#pragma unroll
    for (int s = 0; s < 2; ++s) {
      bf16x8 ak = *reinterpret_cast<const bf16x8*>(
          &tkb[((size_t)bh * 64 + mt * 16 + c) * 64 + s * 32 + quad * 8]);
      acc = __builtin_amdgcn_mfma_f32_16x16x32_bf16(ak, bq[s], acc, 0, 0, 0);
    }
    st[mt] = acc;
  }
  float sume = 0.f;
#pragma unroll
  for (int mt = 0; mt < 4; ++mt) {
    float e0 = __expf(st[mt][0] * 0.125f);
    float e1 = __expf(st[mt][1] * 0.125f);
    float e2 = __expf(st[mt][2] * 0.125f);
    float e3 = __expf(st[mt][3] * 0.125f);
    sume += (e0 + e1) + (e2 + e3);
    ushort4 pw;
    pw.x = f2bs(e0); pw.y = f2bs(e1); pw.z = f2bs(e2); pw.w = f2bs(e3);
    *reinterpret_cast<ushort4*>(&fus[w][c][mt * 16 + quad * 4]) = pw;
  }
  sume += __shfl_xor(sume, 16, 64);
  sume += __shfl_xor(sume, 32, 64);
  float inv = 1.0f / sume;
  __syncthreads();

  f32x4 po[4];
#pragma unroll
  for (int dt = 0; dt < 4; ++dt) po[dt] = (f32x4){0.f, 0.f, 0.f, 0.f};
#pragma unroll
  for (int s = 0; s < 2; ++s) {
    bf16x8 bp = *reinterpret_cast<const bf16x8*>(&fus[w][c][s * 32 + quad * 8]);
#pragma unroll
    for (int dt = 0; dt < 4; ++dt) {
      bf16x8 av = *reinterpret_cast<const bf16x8*>(
          &tvTb[((size_t)bh * 64 + dt * 16 + c) * 64 + s * 32 + quad * 8]);
      po[dt] = __builtin_amdgcn_mfma_f32_16x16x32_bf16(av, bp, po[dt], 0, 0, 0);
    }
  }
  __syncthreads();

  {
    const u16* crow = co + ((size_t)bh * 4096 + n) * 64 + quad * 16;
    *reinterpret_cast<uint4*>(&fus[w][c][quad * 16])     = *reinterpret_cast<const uint4*>(crow);
    *reinterpret_cast<uint4*>(&fus[w][c][quad * 16 + 8]) = *reinterpret_cast<const uint4*>(crow + 8);
  }
#pragma unroll
  for (int dt = 0; dt < 4; ++dt) {
    ushort4 rw;
    rw.x = f2bs(po[dt][0] * inv); rw.y = f2bs(po[dt][1] * inv);
    rw.z = f2bs(po[dt][2] * inv); rw.w = f2bs(po[dt][3] * inv);
    *reinterpret_cast<ushort4*>(&fus[w][c][64 + dt * 16 + quad * 4]) = rw;
  }
  __syncthreads();

  f32x4 ga[4];
#pragma unroll
  for (int ot = 0; ot < 4; ++ot) ga[ot] = (f32x4){0.f, 0.f, 0.f, 0.f};
#pragma unroll
  for (int s = 0; s < 4; ++s) {
    bf16x8 bf = *reinterpret_cast<const bf16x8*>(&fus[w][c][s * 32 + quad * 8]);
#pragma unroll
    for (int ot = 0; ot < 4; ++ot) {
      bf16x8 ag = *reinterpret_cast<const bf16x8*>(&gw[ot * 16 + c][s * 32 + quad * 8]);
      ga[ot] = __builtin_amdgcn_mfma_f32_16x16x32_bf16(ag, bf, ga[ot], 0, 0, 0);
    }
  }

  const int x = w * 16 + c;
  int jx = x >> 1, x0, x1; float wx0, wx1;
  if ((x & 1) == 0) { x0 = (jx > 0) ? jx - 1 : 0; x1 = jx; wx0 = 0.25f; wx1 = 0.75f; }
  else              { x0 = jx; x1 = (jx < 31) ? jx + 1 : 31; wx0 = 0.75f; wx1 = 0.25f; }
#pragma unroll
  for (int dt = 0; dt < 4; ++dt) {
    ushort4 ow;
    u16 tmp[4];
#pragma unroll
    for (int r = 0; r < 4; ++r) {
      int row = dt * 16 + quad * 4 + r;
      float ref = po[dt][r] * inv;
      float coar = bs2f(fus[w][c][row]);
      float g = 1.0f / (1.0f + __expf(-(ga[dt][r] + gbl[row])));
      float vv = wy0 * (wx0 * bs2f(vl[row][x0]) + wx1 * bs2f(vl[row][x1])) +
                 wy1 * (wx0 * bs2f(vl[row][33 + x0]) + wx1 * bs2f(vl[row][33 + x1]));
      tmp[r] = f2bs(g * ref + (1.0f - g) * coar + vv);
    }
    ow.x = tmp[0]; ow.y = tmp[1]; ow.z = tmp[2]; ow.w = tmp[3];
    *reinterpret_cast<ushort4*>(&outb[w][c][dt * 16 + quad * 4]) = ow;
  }
  __syncthreads();

  {
    int nl = lane >> 2, cs = (lane & 3) * 16;
    u16* dst = xsT + ((size_t)b * 4096 + n0 + w * 16 + nl) * 512 + h * 64 + cs;
    *reinterpret_cast<uint4*>(dst)     = *reinterpret_cast<const uint4*>(&outb[w][nl][cs]);
    *reinterpret_cast<uint4*>(dst + 8) = *reinterpret_cast<const uint4*>(&outb[w][nl][cs + 8]);
  }
}

extern "C" void kernel_launch(void* const* d_in, const int* in_sizes, int n_in,
                              void* d_out, int out_size, void* d_ws, size_t ws_size,
                              hipStream_t stream) {
  const void* x    = d_in[0];
  const void* up   = d_in[1];
  const void* gum  = d_in[2];
  const void* q_w  = d_in[3];
  const void* q_b  = d_in[4];
  const void* kv_w = d_in[5];
  const void* kv_b = d_in[6];
  const void* p_w  = d_in[7];
  const void* p_b  = d_in[8];
  const void* pe_w = d_in[9];
  const void* pe_b = d_in[10];
  const void* g_w  = d_in[11];
  const void* g_b  = d_in[12];

  float* ws    = (float*)d_ws;
  int*   dtf   = (int*)ws;                   // 16
  float* qsumP = ws + 16;                    // 16384
  float* heat  = qsumP + 16384;              // 2048
  int*   posb  = (int*)(heat + 2048);        // 1024
  u16*   tkb   = (u16*)(posb + 1024);        // 65536
  u16*   tvTb  = tkb + 65536;                // 65536
  u16*   qb    = tvTb + 65536;               // 4M
  u16*   kb    = qb + 4194304;               // 1M
  u16*   vb    = kb + 1048576;               // 1M
  u16*   vTb   = vb + 1048576;               // 1M
  u16*   xT    = vTb + 1048576;              // 4M
  u16*   upT   = xT + 4194304;               // 1M
  u16*   co    = upT + 1048576;              // 4M
  u16*   xsT   = co + 4194304;               // 4M
  u16*   vpe   = xsT + 4194304;              // 1M   (~36 MB total)

  dim3 blk(256);
  hipMemsetAsync(dtf, 0, 4, stream);
  detect_dtype<<<dim3(64), blk, 0, stream>>>((const uint4*)x, dtf);
  transpose_bf16<<<dim3(64, 8, 2), blk, 0, stream>>>(x, xT, 4096, dtf);
  transpose_bf16<<<dim3(16, 8, 2), blk, 0, stream>>>(up, upT, 1024, dtf);
  heat_kernel<<<dim3(2048), blk, 0, stream>>>(xT, heat);
  gemm_mfma<0><<<dim3(64, 8, 2), blk, 0, stream>>>(xT, q_w, q_b, qb, nullptr, nullptr, nullptr, 4096, dtf);
  gemm_mfma<1><<<dim3(16, 16, 2), blk, 0, stream>>>(upT, kv_w, kv_b, kb, vb, vTb, nullptr, 1024, dtf);
  qsum_partial<<<dim3(16, 16), blk, 0, stream>>>(qb, qsumP);
  topk_kernel<<<dim3(16), blk, 0, stream>>>(qsumP, kb, heat, gum, posb, dtf);
  gather_kv_mfma<<<dim3(16, 2), blk, 0, stream>>>(xT, kv_w, kv_b, posb, tkb, tvTb, dtf);
  coarse_attn_mfma<<<dim3(32, 16), blk, 0, stream>>>(qb, kb, vTb, co);
  dwconv_kernel<<<dim3(1024), blk, 0, stream>>>(vb, pe_w, pe_b, vpe, dtf);
  fine_mfma<<<dim3(64, 16), blk, 0, stream>>>(qb, tkb, tvTb, co, g_w, g_b, vpe, xsT, dtf);
  gemm_mfma<3><<<dim3(64, 8, 2), blk, 0, stream>>>(xsT, p_w, p_b, nullptr, nullptr, nullptr, d_out, 4096, dtf);
}

// Round 9
// 279.333 us; speedup vs baseline: 6.0350x; 1.0381x over previous
//
#include <hip/hip_runtime.h>
#include <hip/hip_bf16.h>
#include <cstdint>

typedef __hip_bfloat16 bf16;
typedef unsigned short u16;
typedef __attribute__((ext_vector_type(8))) short bf16x8;
typedef __attribute__((ext_vector_type(4))) float f32x4;

static __device__ __forceinline__ float b2f(bf16 v) { return __bfloat162float(v); }
static __device__ __forceinline__ float bs2f(u16 s) {
  unsigned int u = ((unsigned int)s) << 16;
  float f;
  __builtin_memcpy(&f, &u, 4);
  return f;
}
static __device__ __forceinline__ u16 f2bs(float f) {
  bf16 h = __float2bfloat16(f);
  u16 s;
  __builtin_memcpy(&s, &h, 2);
  return s;
}
// dual-dtype load: f32!=0 -> buffer is float32, else packed bf16
static __device__ __forceinline__ float ldf(const void* p, size_t i, int f32) {
  return f32 ? ((const float*)p)[i] : bs2f(((const u16*)p)[i]);
}

// ---------------------------------------------------------------------------
// dtype detection on a 256 KB sample of x.
// ---------------------------------------------------------------------------
__global__ __launch_bounds__(256) void detect_dtype(const uint4* __restrict__ xs,
                                                    int* __restrict__ flag) {
  int i = blockIdx.x * 256 + threadIdx.x;
  uint4 v = xs[i];
  bool hit = false;
#pragma unroll
  for (int j = 0; j < 4; ++j) {
    unsigned w = (j == 0) ? v.x : (j == 1) ? v.y : (j == 2) ? v.z : v.w;
    if ((w & 0x7F80u) == 0x7F80u) hit = true;
    if ((w & 0x7F800000u) == 0x7F800000u) hit = true;
  }
  unsigned long long mask = __ballot(hit);
  if (mask != 0ull && (threadIdx.x & 63) == 0) atomicOr(flag, 1);
}

// one-time gate weights conversion -> bf16 gwb[64][128], f32 gbf[64]
__global__ __launch_bounds__(256) void prep_gate(
    const void* __restrict__ gate_w, const void* __restrict__ gate_b,
    u16* __restrict__ gwb, float* __restrict__ gbf,
    const int* __restrict__ dtf) {
  const int f32 = *dtf;
  int t = threadIdx.x;
  for (int i = t; i < 8192; i += 256)
    gwb[i] = f32 ? f2bs(((const float*)gate_w)[i]) : ((const u16*)gate_w)[i];
  if (t < 64) gbf[t] = ldf(gate_b, t, f32);
}

// ---------------------------------------------------------------------------
// transpose [b][c=512][N] (dual dtype) -> [b][N][512] bf16; grid (N/64,8,B)
// ---------------------------------------------------------------------------
__global__ __launch_bounds__(256) void transpose_bf16(
    const void* __restrict__ src, u16* __restrict__ dst, int N,
    const int* __restrict__ dtf) {
  const int f32 = *dtf;
  const int b = blockIdx.z, n0 = blockIdx.x * 64, c0 = blockIdx.y * 64;
  const int t = threadIdx.x;
  __shared__ __align__(16) u16 tile[64][72];
#pragma unroll
  for (int j = 0; j < 2; ++j) {
    int cc = (t >> 3) + j * 32;
    int nn = (t & 7) * 8;
    u16 tmp[8];
    if (f32) {
      const float* s4 = (const float*)src + ((size_t)(b * 512 + c0 + cc)) * N + n0 + nn;
#pragma unroll
      for (int u = 0; u < 8; ++u) tmp[u] = f2bs(s4[u]);
    } else {
      *reinterpret_cast<uint4*>(tmp) = *reinterpret_cast<const uint4*>(
          (const u16*)src + ((size_t)(b * 512 + c0 + cc)) * N + n0 + nn);
    }
    *reinterpret_cast<uint4*>(&tile[cc][nn]) = *reinterpret_cast<const uint4*>(tmp);
  }
  __syncthreads();
#pragma unroll
  for (int j = 0; j < 2; ++j) {
    int nn = (t >> 3) + j * 32;
    int cc0 = (t & 7) * 8;
    u16 tmp[8];
#pragma unroll
    for (int u = 0; u < 8; ++u) tmp[u] = tile[cc0 + u][nn];
    *reinterpret_cast<uint4*>(&dst[((size_t)b * N + n0 + nn) * 512 + c0 + cc0]) =
        *reinterpret_cast<const uint4*>(tmp);
  }
}

// ---------------------------------------------------------------------------
// MFMA conv1x1 GEMM. K=512, tile 64x64, 4 waves.
// MODE 1 additionally writes oT = v transposed [bh][d][m].
// ---------------------------------------------------------------------------
template<int MODE>
__global__ __launch_bounds__(256) void gemm_mfma(
    const u16* __restrict__ A, const void* __restrict__ W,
    const void* __restrict__ bias, u16* __restrict__ o0, u16* __restrict__ o1,
    u16* __restrict__ oT, void* __restrict__ ob, int M,
    const int* __restrict__ dtf) {
  const int f32 = *dtf;
  const int b = blockIdx.z, m0 = blockIdx.x * 64, oo0 = blockIdx.y * 64;
  const int t = threadIdx.x, w = t >> 6, lane = t & 63;
  const int quad = lane >> 4, c = lane & 15;
  __shared__ __align__(16) u16 As[64][72];
  __shared__ __align__(16) u16 Ws[64][72];
  f32x4 acc[4];
#pragma unroll
  for (int ot = 0; ot < 4; ++ot) acc[ot] = (f32x4){0.f, 0.f, 0.f, 0.f};
  const u16* Ab = A + (size_t)b * M * 512;
  const int srow = t >> 2, scol = (t & 3) * 16;

  for (int k0 = 0; k0 < 512; k0 += 64) {
    __syncthreads();
    {
      const u16* ga = Ab + (size_t)(m0 + srow) * 512 + k0 + scol;
      *reinterpret_cast<uint4*>(&As[srow][scol])     = *reinterpret_cast<const uint4*>(ga);
      *reinterpret_cast<uint4*>(&As[srow][scol + 8]) = *reinterpret_cast<const uint4*>(ga + 8);
      if (f32) {
        const float* gw = (const float*)W + (size_t)(oo0 + srow) * 512 + k0 + scol;
#pragma unroll
        for (int e = 0; e < 16; ++e) Ws[srow][scol + e] = f2bs(gw[e]);
      } else {
        const u16* gw = (const u16*)W + (size_t)(oo0 + srow) * 512 + k0 + scol;
        *reinterpret_cast<uint4*>(&Ws[srow][scol])     = *reinterpret_cast<const uint4*>(gw);
        *reinterpret_cast<uint4*>(&Ws[srow][scol + 8]) = *reinterpret_cast<const uint4*>(gw + 8);
      }
    }
    __syncthreads();
#pragma unroll
    for (int ks = 0; ks < 2; ++ks) {
      bf16x8 av = *reinterpret_cast<const bf16x8*>(&As[w * 16 + c][ks * 32 + quad * 8]);
#pragma unroll
      for (int ot = 0; ot < 4; ++ot) {
        bf16x8 wv = *reinterpret_cast<const bf16x8*>(&Ws[ot * 16 + c][ks * 32 + quad * 8]);
        if (MODE == 3)
          acc[ot] = __builtin_amdgcn_mfma_f32_16x16x32_bf16(wv, av, acc[ot], 0, 0, 0);
        else
          acc[ot] = __builtin_amdgcn_mfma_f32_16x16x32_bf16(av, wv, acc[ot], 0, 0, 0);
      }
    }
  }

  if (MODE == 0) {
#pragma unroll
    for (int ot = 0; ot < 4; ++ot) {
      int o = oo0 + ot * 16 + c;
      float bv = ldf(bias, o, f32);
      int h = o >> 6, d = o & 63;
#pragma unroll
      for (int r = 0; r < 4; ++r) {
        int m = m0 + w * 16 + quad * 4 + r;
        o0[((size_t)(b * 8 + h) * M + m) * 64 + d] = f2bs(acc[ot][r] + bv);
      }
    }
  } else if (MODE == 1) {
#pragma unroll
    for (int ot = 0; ot < 4; ++ot) {
      int o = oo0 + ot * 16 + c;
      float bv = ldf(bias, o, f32);
      int hh = o >> 7, jj = o & 127;
#pragma unroll
      for (int r = 0; r < 4; ++r) {
        int m = m0 + w * 16 + quad * 4 + r;
        u16 val = f2bs(acc[ot][r] + bv);
        if (jj < 64) {
          o0[((size_t)(b * 8 + hh) * M + m) * 64 + jj] = val;
        } else {
          o1[((size_t)(b * 8 + hh) * M + m) * 64 + (jj & 63)] = val;
          oT[((size_t)(b * 8 + hh) * 64 + (jj & 63)) * M + m] = val;
        }
      }
    }
  } else {
#pragma unroll
    for (int ot = 0; ot < 4; ++ot) {
#pragma unroll
      for (int r = 0; r < 4; ++r) {
        int o = oo0 + ot * 16 + quad * 4 + r;
        float val = acc[ot][r] + ldf(bias, o, f32);
        int m = m0 + w * 16 + c;
        size_t oi_ = ((size_t)(b * 512 + o)) * M + m;
        if (f32) ((float*)ob)[oi_] = val;
        else     ((u16*)ob)[oi_] = f2bs(val);
      }
    }
  }
}

// heat[b,mu] = mean over C and 2x2 spatial of x, computed from coalesced xT
__global__ __launch_bounds__(256) void heat_kernel(const u16* __restrict__ xT,
                                                   float* __restrict__ heat) {
  int bm = blockIdx.x;
  int b = bm >> 10, mu = bm & 1023;
  int hu = mu >> 5, wu = mu & 31;
  int t = threadIdx.x;
  int row = t >> 6, seg = t & 63;
  int y = hu * 2 + (row >> 1), xx = wu * 2 + (row & 1);
  const uint4* p = reinterpret_cast<const uint4*>(
      xT + ((size_t)b * 4096 + y * 64 + xx) * 512);
  uint4 v = p[seg];
  float s = 0.f;
#pragma unroll
  for (int j = 0; j < 4; ++j) {
    unsigned w = (j == 0) ? v.x : (j == 1) ? v.y : (j == 2) ? v.z : v.w;
    s += bs2f((u16)(w & 0xFFFF)) + bs2f((u16)(w >> 16));
  }
  __shared__ float r[256];
  r[t] = s; __syncthreads();
  for (int off = 128; off; off >>= 1) { if (t < off) r[t] += r[t + off]; __syncthreads(); }
  if (t == 0) heat[bm] = r[0] * (1.0f / 2048.0f);
}

// stage 1 of qsum: partial[bh][chunk][d] = sum over 256 n-rows
__global__ __launch_bounds__(256) void qsum_partial(const u16* __restrict__ q,
                                                    float* __restrict__ qsumP) {
  int bh = blockIdx.x, ch = blockIdx.y, t = threadIdx.x;
  int d = t & 63, g = t >> 6;
  int n0 = ch * 256 + g * 64;
  float s = 0.f;
  for (int r = 0; r < 64; ++r)
    s += bs2f(q[((size_t)bh * 4096 + n0 + r) * 64 + d]);
  __shared__ float r[256];
  r[t] = s; __syncthreads();
  if (t < 64) qsumP[(size_t)(bh * 16 + ch) * 64 + t] = r[t] + r[t + 64] + r[t + 128] + r[t + 192];
}

// scores -> top-16 coarse cells -> 64 full-res positions into posb
__global__ __launch_bounds__(256) void topk_kernel(
    const float* __restrict__ qsumP, const u16* __restrict__ k,
    const float* __restrict__ heat, const void* __restrict__ gumbel,
    int* __restrict__ posb, const int* __restrict__ dtf) {
  const int f32 = *dtf;
  int bh = blockIdx.x, b = bh >> 3, t = threadIdx.x;
  __shared__ float qs[64];
  __shared__ float s[1024];
  __shared__ float rv[256];
  __shared__ int   ri[256];
  if (t < 64) {
    float acc = 0.f;
    for (int ch = 0; ch < 16; ++ch) acc += qsumP[(size_t)(bh * 16 + ch) * 64 + t];
    qs[t] = acc;
  }
  __syncthreads();
  for (int j = 0; j < 4; ++j) {
    int m = t + j * 256;
    const u16* kr = k + ((size_t)bh * 1024 + m) * 64;
    float dot = 0.f;
    for (int d = 0; d < 64; ++d) dot += qs[d] * bs2f(kr[d]);
    s[m] = dot * (0.125f / 4096.0f) * heat[b * 1024 + m] + ldf(gumbel, (size_t)bh * 1024 + m, f32);
  }
  __syncthreads();
  for (int it = 0; it < 16; ++it) {
    float bv = -1e30f; int bi = 0x7fffffff;
    for (int j = 0; j < 4; ++j) {
      int m = t + j * 256; float vv = s[m];
      if (vv > bv || (vv == bv && m < bi)) { bv = vv; bi = m; }
    }
    rv[t] = bv; ri[t] = bi; __syncthreads();
    for (int off = 128; off; off >>= 1) {
      if (t < off) {
        if (rv[t + off] > rv[t] || (rv[t + off] == rv[t] && ri[t + off] < ri[t])) {
          rv[t] = rv[t + off]; ri[t] = ri[t + off];
        }
      }
      __syncthreads();
    }
    if (t == 0) {
      int mi = ri[0]; s[mi] = -1e30f;
      int hy = (mi >> 5) * 2, wx = (mi & 31) * 2;
      posb[bh * 64 + it]      = hy * 64 + wx;
      posb[bh * 64 + 16 + it] = hy * 64 + wx + 1;
      posb[bh * 64 + 32 + it] = (hy + 1) * 64 + wx;
      posb[bh * 64 + 48 + it] = (hy + 1) * 64 + wx + 1;
    }
    __syncthreads();
  }
}

// ---------------------------------------------------------------------------
// gather_kv as MFMA GEMM (round-5 structure).
// ---------------------------------------------------------------------------
__global__ __launch_bounds__(256) void gather_kv_mfma(
    const u16* __restrict__ xT, const void* __restrict__ kv_w,
    const void* __restrict__ kv_b, const int* __restrict__ posb,
    u16* __restrict__ tkb, u16* __restrict__ tvTb,
    const int* __restrict__ dtf) {
  const int f32 = *dtf;
  const int bh = blockIdx.x, b = bh >> 3, h = bh & 7;
  const int half = blockIdx.y;
  const int t = threadIdx.x, w = t >> 6, lane = t & 63;
  const int quad = lane >> 4, c = lane & 15;
  __shared__ int pos[64];
  __shared__ __align__(16) u16 As[64][72];
  __shared__ __align__(16) u16 Ws[64][72];
  if (t < 64) pos[t] = posb[bh * 64 + t];
  __syncthreads();
  const int obase = h * 128 + half * 64;
  const int srow = t >> 2, scol = (t & 3) * 16;
  const int arow = pos[srow];
  f32x4 acc[4];
#pragma unroll
  for (int ot = 0; ot < 4; ++ot) acc[ot] = (f32x4){0.f, 0.f, 0.f, 0.f};

  for (int k0 = 0; k0 < 512; k0 += 64) {
    __syncthreads();
    {
      const u16* ga = xT + ((size_t)b * 4096 + arow) * 512 + k0 + scol;
      *reinterpret_cast<uint4*>(&As[srow][scol])     = *reinterpret_cast<const uint4*>(ga);
      *reinterpret_cast<uint4*>(&As[srow][scol + 8]) = *reinterpret_cast<const uint4*>(ga + 8);
      if (f32) {
        const float* gw = (const float*)kv_w + (size_t)(obase + srow) * 512 + k0 + scol;
#pragma unroll
        for (int e = 0; e < 16; ++e) Ws[srow][scol + e] = f2bs(gw[e]);
      } else {
        const u16* gw = (const u16*)kv_w + (size_t)(obase + srow) * 512 + k0 + scol;
        *reinterpret_cast<uint4*>(&Ws[srow][scol])     = *reinterpret_cast<const uint4*>(gw);
        *reinterpret_cast<uint4*>(&Ws[srow][scol + 8]) = *reinterpret_cast<const uint4*>(gw + 8);
      }
    }
    __syncthreads();
#pragma unroll
    for (int ks = 0; ks < 2; ++ks) {
      bf16x8 av = *reinterpret_cast<const bf16x8*>(&As[w * 16 + c][ks * 32 + quad * 8]);
#pragma unroll
      for (int ot = 0; ot < 4; ++ot) {
        bf16x8 wv = *reinterpret_cast<const bf16x8*>(&Ws[ot * 16 + c][ks * 32 + quad * 8]);
        acc[ot] = __builtin_amdgcn_mfma_f32_16x16x32_bf16(av, wv, acc[ot], 0, 0, 0);
      }
    }
  }

#pragma unroll
  for (int ot = 0; ot < 4; ++ot) {
    int d = ot * 16 + c;
    float bv = ldf(kv_b, obase + d, f32);
#pragma unroll
    for (int r = 0; r < 4; ++r) {
      int m = w * 16 + quad * 4 + r;
      u16 val = f2bs(acc[ot][r] + bv);
      if (half) tvTb[((size_t)bh * 64 + d) * 64 + m] = val;
      else      tkb[((size_t)bh * 64 + m) * 64 + d] = val;
    }
  }
}

// ---------------------------------------------------------------------------
// coarse attention: 128 n per block, double-buffered LDS staging (round 8).
// ---------------------------------------------------------------------------
__global__ __launch_bounds__(256) void coarse_attn_mfma(
    const u16* __restrict__ q, const u16* __restrict__ k,
    const u16* __restrict__ vT, u16* __restrict__ coarse) {
  const int bh = blockIdx.y;
  const int n0 = blockIdx.x * 128;
  const int t = threadIdx.x, w = t >> 6, lane = t & 63;
  const int quad = lane >> 4, c = lane & 15;
  __shared__ __align__(16) u16 Ks[2][64][72];
  __shared__ __align__(16) u16 Vt[2][64][72];
  __shared__ __align__(16) u16 Ps[4][2][16][72];

  bf16x8 bq[2][2];
#pragma unroll
  for (int nt = 0; nt < 2; ++nt) {
    const u16* qr = q + ((size_t)bh * 4096 + n0 + w * 32 + nt * 16 + c) * 64;
    bq[nt][0] = *reinterpret_cast<const bf16x8*>(qr + quad * 8);
    bq[nt][1] = *reinterpret_cast<const bf16x8*>(qr + 32 + quad * 8);
  }
  f32x4 po[2][4];
#pragma unroll
  for (int nt = 0; nt < 2; ++nt)
#pragma unroll
    for (int dt = 0; dt < 4; ++dt) po[nt][dt] = (f32x4){0.f, 0.f, 0.f, 0.f};
  float sume[2] = {0.f, 0.f};

  const u16* kbase = k + (size_t)bh * 65536;
  const u16* vbase = vT + (size_t)bh * 65536;
  const int srow = t >> 2, scol = (t & 3) * 16;

  uint4 kr0, kr1, vr0, vr1;
  {
    const u16* gk = kbase + (size_t)srow * 64 + scol;
    kr0 = *reinterpret_cast<const uint4*>(gk);
    kr1 = *reinterpret_cast<const uint4*>(gk + 8);
    const u16* gv = vbase + (size_t)srow * 1024 + scol;
    vr0 = *reinterpret_cast<const uint4*>(gv);
    vr1 = *reinterpret_cast<const uint4*>(gv + 8);
    *reinterpret_cast<uint4*>(&Ks[0][srow][scol])     = kr0;
    *reinterpret_cast<uint4*>(&Ks[0][srow][scol + 8]) = kr1;
    *reinterpret_cast<uint4*>(&Vt[0][srow][scol])     = vr0;
    *reinterpret_cast<uint4*>(&Vt[0][srow][scol + 8]) = vr1;
  }

  for (int ch = 0; ch < 16; ++ch) {
    __syncthreads();
    const int buf = ch & 1;
    if (ch + 1 < 16) {
      int m1 = (ch + 1) * 64;
      const u16* gk = kbase + (size_t)(m1 + srow) * 64 + scol;
      kr0 = *reinterpret_cast<const uint4*>(gk);
      kr1 = *reinterpret_cast<const uint4*>(gk + 8);
      const u16* gv = vbase + (size_t)srow * 1024 + m1 + scol;
      vr0 = *reinterpret_cast<const uint4*>(gv);
      vr1 = *reinterpret_cast<const uint4*>(gv + 8);
    }

    f32x4 st[2][4];
#pragma unroll
    for (int mt = 0; mt < 4; ++mt) {
      bf16x8 ak0 = *reinterpret_cast<const bf16x8*>(&Ks[buf][mt * 16 + c][quad * 8]);
      bf16x8 ak1 = *reinterpret_cast<const bf16x8*>(&Ks[buf][mt * 16 + c][32 + quad * 8]);
#pragma unroll
      for (int nt = 0; nt < 2; ++nt) {
        f32x4 acc = (f32x4){0.f, 0.f, 0.f, 0.f};
        acc = __builtin_amdgcn_mfma_f32_16x16x32_bf16(ak0, bq[nt][0], acc, 0, 0, 0);
        acc = __builtin_amdgcn_mfma_f32_16x16x32_bf16(ak1, bq[nt][1], acc, 0, 0, 0);
        st[nt][mt] = acc;
      }
    }
#pragma unroll
    for (int nt = 0; nt < 2; ++nt) {
      float cs = 0.f;
#pragma unroll
      for (int mt = 0; mt < 4; ++mt) {
        float e0 = __expf(st[nt][mt][0] * 0.125f);
        float e1 = __expf(st[nt][mt][1] * 0.125f);
        float e2 = __expf(st[nt][mt][2] * 0.125f);
        float e3 = __expf(st[nt][mt][3] * 0.125f);
        cs += (e0 + e1) + (e2 + e3);
        ushort4 pw;
        pw.x = f2bs(e0); pw.y = f2bs(e1); pw.z = f2bs(e2); pw.w = f2bs(e3);
        *reinterpret_cast<ushort4*>(&Ps[w][nt][c][mt * 16 + quad * 4]) = pw;
      }
      cs += __shfl_xor(cs, 16, 64);
      cs += __shfl_xor(cs, 32, 64);
      sume[nt] += cs;
    }
#pragma unroll
    for (int s = 0; s < 2; ++s) {
      bf16x8 bp0 = *reinterpret_cast<const bf16x8*>(&Ps[w][0][c][s * 32 + quad * 8]);
      bf16x8 bp1 = *reinterpret_cast<const bf16x8*>(&Ps[w][1][c][s * 32 + quad * 8]);
#pragma unroll
      for (int dt = 0; dt < 4; ++dt) {
        bf16x8 av = *reinterpret_cast<const bf16x8*>(&Vt[buf][dt * 16 + c][s * 32 + quad * 8]);
        po[0][dt] = __builtin_amdgcn_mfma_f32_16x16x32_bf16(av, bp0, po[0][dt], 0, 0, 0);
        po[1][dt] = __builtin_amdgcn_mfma_f32_16x16x32_bf16(av, bp1, po[1][dt], 0, 0, 0);
      }
    }

    if (ch + 1 < 16) {
      const int nb = buf ^ 1;
      *reinterpret_cast<uint4*>(&Ks[nb][srow][scol])     = kr0;
      *reinterpret_cast<uint4*>(&Ks[nb][srow][scol + 8]) = kr1;
      *reinterpret_cast<uint4*>(&Vt[nb][srow][scol])     = vr0;
      *reinterpret_cast<uint4*>(&Vt[nb][srow][scol + 8]) = vr1;
    }
  }

#pragma unroll
  for (int nt = 0; nt < 2; ++nt) {
    float inv = 1.0f / sume[nt];
    u16* orow = coarse + ((size_t)bh * 4096 + n0 + w * 32 + nt * 16 + c) * 64;
#pragma unroll
    for (int dt = 0; dt < 4; ++dt) {
      ushort4 r;
      r.x = f2bs(po[nt][dt][0] * inv); r.y = f2bs(po[nt][dt][1] * inv);
      r.z = f2bs(po[nt][dt][2] * inv); r.w = f2bs(po[nt][dt][3] * inv);
      *reinterpret_cast<ushort4*>(&orow[dt * 16 + quad * 4]) = r;
    }
  }
}

// depthwise 7x7 conv on v (bf16) -> vpe bf16
__global__ __launch_bounds__(256) void dwconv_kernel(
    const u16* __restrict__ v, const void* __restrict__ pe_w,
    const void* __restrict__ pe_b, u16* __restrict__ vpe,
    const int* __restrict__ dtf) {
  const int f32 = *dtf;
  int bc = blockIdx.x;
  int b = bc >> 9, c = bc & 511;
  int h = c >> 6, d = c & 63;
  int t = threadIdx.x;
  __shared__ float img[1024];
  __shared__ float wts[49];
  for (int i = t; i < 1024; i += 256)
    img[i] = bs2f(v[((size_t)(b * 8 + h) * 1024 + i) * 64 + d]);
  if (t < 49) wts[t] = ldf(pe_w, c * 49 + t, f32);
  float bias = ldf(pe_b, c, f32);
  __syncthreads();
  for (int i = t; i < 1024; i += 256) {
    int y = i >> 5, xx = i & 31;
    float a = 0.f;
#pragma unroll
    for (int ky = 0; ky < 7; ++ky) {
      int yy = y + ky - 3;
      if ((unsigned)yy >= 32u) continue;
#pragma unroll
      for (int kx = 0; kx < 7; ++kx) {
        int xc = xx + kx - 3;
        if ((unsigned)xc >= 32u) continue;
        a += img[yy * 32 + xc] * wts[ky * 7 + kx];
      }
    }
    vpe[(size_t)bc * 1024 + i] = f2bs(a + bias);
  }
}

// ---------------------------------------------------------------------------
// fused fine attention + gate MFMA + combine + bilinear vpe add -> xsT bf16.
// v2: 28 KB LDS (fus aliased as out buffer, gate_w frags from global gwb,
// uint4 vpe staging), ONE barrier.
// ---------------------------------------------------------------------------
__global__ __launch_bounds__(256) void fine_mfma(
    const u16* __restrict__ q, const u16* __restrict__ tkb,
    const u16* __restrict__ tvTb, const u16* __restrict__ co,
    const u16* __restrict__ gwb, const float* __restrict__ gbf,
    const u16* __restrict__ vpe, u16* __restrict__ xsT) {
  const int bh = blockIdx.y, b = bh >> 3, h = bh & 7;
  const int y = blockIdx.x;
  const int n0 = y * 64;
  const int t = threadIdx.x, w = t >> 6, lane = t & 63;
  const int quad = lane >> 4, c = lane & 15;

  __shared__ __align__(16) u16 fus[4][16][136];  // per-wave: P^T / fusion / out (aliased)
  __shared__ __align__(16) u16 vl[2][64][40];    // vpe rows y0,y1 per channel
  __shared__ float gbl[64];

  int jy = y >> 1, y0, y1; float wy0, wy1;
  if ((y & 1) == 0) { y0 = (jy > 0) ? jy - 1 : 0; y1 = jy; wy0 = 0.25f; wy1 = 0.75f; }
  else              { y0 = jy; y1 = (jy < 31) ? jy + 1 : 31; wy0 = 0.75f; wy1 = 0.25f; }

  // stage vpe rows (uint4, 2 per thread) + gate bias
  for (int idx = t; idx < 512; idx += 256) {
    int seg = idx & 3, ch = (idx >> 2) & 63, r = idx >> 8;
    int yy = r ? y1 : y0;
    const uint4* src = reinterpret_cast<const uint4*>(
        vpe + ((size_t)(b * 512 + h * 64 + ch)) * 1024 + yy * 32);
    *reinterpret_cast<uint4*>(&vl[r][ch][seg * 8]) = src[seg];
  }
  if (t < 64) gbl[t] = gbf[t];

  const int n = n0 + w * 16 + c;
  bf16x8 bq[2];
  {
    const u16* qr = q + ((size_t)bh * 4096 + n) * 64;
    bq[0] = *reinterpret_cast<const bf16x8*>(qr + quad * 8);
    bq[1] = *reinterpret_cast<const bf16x8*>(qr + 32 + quad * 8);
  }
  __syncthreads();  // the only block-wide barrier (vl/gbl)

  // phase 1: S^T = TK . Q^T  (A-frags from global tkb, L2-hot)
  f32x4 st[4];
#pragma unroll
  for (int mt = 0; mt < 4; ++mt) {
    f32x4 acc = (f32x4){0.f, 0.f, 0.f, 0.f};
#pragma unroll
    for (int s = 0; s < 2; ++s) {
      bf16x8 ak = *reinterpret_cast<const bf16x8*>(
          &tkb[((size_t)bh * 64 + mt * 16 + c) * 64 + s * 32 + quad * 8]);
      acc = __builtin_amdgcn_mfma_f32_16x16x32_bf16(ak, bq[s], acc, 0, 0, 0);
    }
    st[mt] = acc;
  }
  float sume = 0.f;
#pragma unroll
  for (int mt = 0; mt < 4; ++mt) {
    float e0 = __expf(st[mt][0] * 0.125f);
    float e1 = __expf(st[mt][1] * 0.125f);
    float e2 = __expf(st[mt][2] * 0.125f);
    float e3 = __expf(st[mt][3] * 0.125f);
    sume += (e0 + e1) + (e2 + e3);
    ushort4 pw;
    pw.x = f2bs(e0); pw.y = f2bs(e1); pw.z = f2bs(e2); pw.w = f2bs(e3);
    *reinterpret_cast<ushort4*>(&fus[w][c][mt * 16 + quad * 4]) = pw;
  }
  sume += __shfl_xor(sume, 16, 64);
  sume += __shfl_xor(sume, 32, 64);
  float inv = 1.0f / sume;

  // phase 2: O^T = TV^T . P^T (per-wave LDS, in-order DS pipe — no barrier)
  f32x4 po[4];
#pragma unroll
  for (int dt = 0; dt < 4; ++dt) po[dt] = (f32x4){0.f, 0.f, 0.f, 0.f};
#pragma unroll
  for (int s = 0; s < 2; ++s) {
    bf16x8 bp = *reinterpret_cast<const bf16x8*>(&fus[w][c][s * 32 + quad * 8]);
#pragma unroll
    for (int dt = 0; dt < 4; ++dt) {
      bf16x8 av = *reinterpret_cast<const bf16x8*>(
          &tvTb[((size_t)bh * 64 + dt * 16 + c) * 64 + s * 32 + quad * 8]);
      po[dt] = __builtin_amdgcn_mfma_f32_16x16x32_bf16(av, bp, po[dt], 0, 0, 0);
    }
  }

  // phase 3: fusion [coarse | refined] in fus[n][k]
  {
    const u16* crow = co + ((size_t)bh * 4096 + n) * 64 + quad * 16;
    *reinterpret_cast<uint4*>(&fus[w][c][quad * 16])     = *reinterpret_cast<const uint4*>(crow);
    *reinterpret_cast<uint4*>(&fus[w][c][quad * 16 + 8]) = *reinterpret_cast<const uint4*>(crow + 8);
  }
#pragma unroll
  for (int dt = 0; dt < 4; ++dt) {
    ushort4 rw;
    rw.x = f2bs(po[dt][0] * inv); rw.y = f2bs(po[dt][1] * inv);
    rw.z = f2bs(po[dt][2] * inv); rw.w = f2bs(po[dt][3] * inv);
    *reinterpret_cast<ushort4*>(&fus[w][c][64 + dt * 16 + quad * 4]) = rw;
  }

  // phase 4: gate MFMA, K=128; A-frags from global gwb (16 KB, L2-hot)
  f32x4 ga[4];
#pragma unroll
  for (int ot = 0; ot < 4; ++ot) ga[ot] = (f32x4){0.f, 0.f, 0.f, 0.f};
#pragma unroll
  for (int s = 0; s < 4; ++s) {
    bf16x8 bf = *reinterpret_cast<const bf16x8*>(&fus[w][c][s * 32 + quad * 8]);
#pragma unroll
    for (int ot = 0; ot < 4; ++ot) {
      bf16x8 ag = *reinterpret_cast<const bf16x8*>(
          gwb + (ot * 16 + c) * 128 + s * 32 + quad * 8);
      ga[ot] = __builtin_amdgcn_mfma_f32_16x16x32_bf16(ag, bf, ga[ot], 0, 0, 0);
    }
  }

  // phase 5: combine + bilinear vpe add; write result over fus rows 0..63
  // (each element is read (coar) then written by the SAME lane — alias-safe)
  const int x = w * 16 + c;
  int jx = x >> 1, x0, x1; float wx0, wx1;
  if ((x & 1) == 0) { x0 = (jx > 0) ? jx - 1 : 0; x1 = jx; wx0 = 0.25f; wx1 = 0.75f; }
  else              { x0 = jx; x1 = (jx < 31) ? jx + 1 : 31; wx0 = 0.75f; wx1 = 0.25f; }
#pragma unroll
  for (int dt = 0; dt < 4; ++dt) {
    ushort4 ow;
    u16 tmp[4];
#pragma unroll
    for (int r = 0; r < 4; ++r) {
      int row = dt * 16 + quad * 4 + r;
      float ref = po[dt][r] * inv;
      float coar = bs2f(fus[w][c][row]);
      float g = 1.0f / (1.0f + __expf(-(ga[dt][r] + gbl[row])));
      float vv = wy0 * (wx0 * bs2f(vl[0][row][x0]) + wx1 * bs2f(vl[0][row][x1])) +
                 wy1 * (wx0 * bs2f(vl[1][row][x0]) + wx1 * bs2f(vl[1][row][x1]));
      tmp[r] = f2bs(g * ref + (1.0f - g) * coar + vv);
    }
    ow.x = tmp[0]; ow.y = tmp[1]; ow.z = tmp[2]; ow.w = tmp[3];
    *reinterpret_cast<ushort4*>(&fus[w][c][dt * 16 + quad * 4]) = ow;
  }

  // store: n-major rows (reads other lanes' fus rows — same wave, in-order DS)
  {
    int nl = lane >> 2, cs = (lane & 3) * 16;
    u16* dst = xsT + ((size_t)b * 4096 + n0 + w * 16 + nl) * 512 + h * 64 + cs;
    *reinterpret_cast<uint4*>(dst)     = *reinterpret_cast<const uint4*>(&fus[w][nl][cs]);
    *reinterpret_cast<uint4*>(dst + 8) = *reinterpret_cast<const uint4*>(&fus[w][nl][cs + 8]);
  }
}

extern "C" void kernel_launch(void* const* d_in, const int* in_sizes, int n_in,
                              void* d_out, int out_size, void* d_ws, size_t ws_size,
                              hipStream_t stream) {
  const void* x    = d_in[0];
  const void* up   = d_in[1];
  const void* gum  = d_in[2];
  const void* q_w  = d_in[3];
  const void* q_b  = d_in[4];
  const void* kv_w = d_in[5];
  const void* kv_b = d_in[6];
  const void* p_w  = d_in[7];
  const void* p_b  = d_in[8];
  const void* pe_w = d_in[9];
  const void* pe_b = d_in[10];
  const void* g_w  = d_in[11];
  const void* g_b  = d_in[12];

  float* ws    = (float*)d_ws;
  int*   dtf   = (int*)ws;                   // 16
  float* qsumP = ws + 16;                    // 16384
  float* heat  = qsumP + 16384;              // 2048
  int*   posb  = (int*)(heat + 2048);        // 1024 ints
  float* gbf   = (float*)(posb + 1024);      // 64
  u16*   gwb   = (u16*)(gbf + 64);           // 8192 u16
  u16*   tkb   = gwb + 8192;                 // 65536
  u16*   tvTb  = tkb + 65536;                // 65536
  u16*   qb    = tvTb + 65536;               // 4M
  u16*   kb    = qb + 4194304;               // 1M
  u16*   vb    = kb + 1048576;               // 1M
  u16*   vTb   = vb + 1048576;               // 1M
  u16*   xT    = vTb + 1048576;              // 4M
  u16*   upT   = xT + 4194304;               // 1M
  u16*   co    = upT + 1048576;              // 4M
  u16*   xsT   = co + 4194304;               // 4M
  u16*   vpe   = xsT + 4194304;              // 1M   (~36 MB total)

  dim3 blk(256);
  hipMemsetAsync(dtf, 0, 4, stream);
  detect_dtype<<<dim3(64), blk, 0, stream>>>((const uint4*)x, dtf);
  prep_gate<<<dim3(1), blk, 0, stream>>>(g_w, g_b, gwb, gbf, dtf);
  transpose_bf16<<<dim3(64, 8, 2), blk, 0, stream>>>(x, xT, 4096, dtf);
  transpose_bf16<<<dim3(16, 8, 2), blk, 0, stream>>>(up, upT, 1024, dtf);
  heat_kernel<<<dim3(2048), blk, 0, stream>>>(xT, heat);
  gemm_mfma<0><<<dim3(64, 8, 2), blk, 0, stream>>>(xT, q_w, q_b, qb, nullptr, nullptr, nullptr, 4096, dtf);
  gemm_mfma<1><<<dim3(16, 16, 2), blk, 0, stream>>>(upT, kv_w, kv_b, kb, vb, vTb, nullptr, 1024, dtf);
  qsum_partial<<<dim3(16, 16), blk, 0, stream>>>(qb, qsumP);
  topk_kernel<<<dim3(16), blk, 0, stream>>>(qsumP, kb, heat, gum, posb, dtf);
  gather_kv_mfma<<<dim3(16, 2), blk, 0, stream>>>(xT, kv_w, kv_b, posb, tkb, tvTb, dtf);
  coarse_attn_mfma<<<dim3(32, 16), blk, 0, stream>>>(qb, kb, vTb, co);
  dwconv_kernel<<<dim3(1024), blk, 0, stream>>>(vb, pe_w, pe_b, vpe, dtf);
  fine_mfma<<<dim3(64, 16), blk, 0, stream>>>(qb, tkb, tvTb, co, gwb, gbf, vpe, xsT);
  gemm_mfma<3><<<dim3(64, 8, 2), blk, 0, stream>>>(xsT, p_w, p_b, nullptr, nullptr, nullptr, d_out, 4096, dtf);
}

// Round 10
// 271.724 us; speedup vs baseline: 6.2040x; 1.0280x over previous
//
#include <hip/hip_runtime.h>
#include <hip/hip_bf16.h>
#include <cstdint>

typedef __hip_bfloat16 bf16;
typedef unsigned short u16;
typedef __attribute__((ext_vector_type(8))) short bf16x8;
typedef __attribute__((ext_vector_type(4))) float f32x4;

static __device__ __forceinline__ float bs2f(u16 s) {
  unsigned int u = ((unsigned int)s) << 16;
  float f;
  __builtin_memcpy(&f, &u, 4);
  return f;
}
static __device__ __forceinline__ u16 f2bs(float f) {
  bf16 h = __float2bfloat16(f);
  u16 s;
  __builtin_memcpy(&s, &h, 2);
  return s;
}
static __device__ __forceinline__ float ldf(const void* p, size_t i, int f32) {
  return f32 ? ((const float*)p)[i] : bs2f(((const u16*)p)[i]);
}

// ---------------------------------------------------------------------------
// dtype detection on a 256 KB sample of x.
// ---------------------------------------------------------------------------
__global__ __launch_bounds__(256) void detect_dtype(const uint4* __restrict__ xs,
                                                    int* __restrict__ flag) {
  int i = blockIdx.x * 256 + threadIdx.x;
  uint4 v = xs[i];
  bool hit = false;
#pragma unroll
  for (int j = 0; j < 4; ++j) {
    unsigned w = (j == 0) ? v.x : (j == 1) ? v.y : (j == 2) ? v.z : v.w;
    if ((w & 0x7F80u) == 0x7F80u) hit = true;
    if ((w & 0x7F800000u) == 0x7F800000u) hit = true;
  }
  unsigned long long mask = __ballot(hit);
  if (mask != 0ull && (threadIdx.x & 63) == 0) atomicOr(flag, 1);
}

// one-time gate weights conversion -> bf16 gwb[64][128], f32 gbf[64]
__global__ __launch_bounds__(256) void prep_gate(
    const void* __restrict__ gate_w, const void* __restrict__ gate_b,
    u16* __restrict__ gwb, float* __restrict__ gbf,
    const int* __restrict__ dtf) {
  const int f32 = *dtf;
  int t = threadIdx.x;
  for (int i = t; i < 8192; i += 256)
    gwb[i] = f32 ? f2bs(((const float*)gate_w)[i]) : ((const u16*)gate_w)[i];
  if (t < 64) gbf[t] = ldf(gate_b, t, f32);
}

// ---------------------------------------------------------------------------
// transpose [b][c=512][N] -> [b][N][512] bf16; optional fused heat partials
// (x only, N=4096): column sums of the staged tile -> atomicAdd heat[b][mu].
// ---------------------------------------------------------------------------
__global__ __launch_bounds__(256) void transpose_bf16(
    const void* __restrict__ src, u16* __restrict__ dst, int N,
    float* __restrict__ heat, const int* __restrict__ dtf) {
  const int f32 = *dtf;
  const int b = blockIdx.z, n0 = blockIdx.x * 64, c0 = blockIdx.y * 64;
  const int t = threadIdx.x;
  __shared__ __align__(16) u16 tile[64][72];
#pragma unroll
  for (int j = 0; j < 2; ++j) {
    int cc = (t >> 3) + j * 32;
    int nn = (t & 7) * 8;
    u16 tmp[8];
    if (f32) {
      const float* s4 = (const float*)src + ((size_t)(b * 512 + c0 + cc)) * N + n0 + nn;
#pragma unroll
      for (int u = 0; u < 8; ++u) tmp[u] = f2bs(s4[u]);
    } else {
      *reinterpret_cast<uint4*>(tmp) = *reinterpret_cast<const uint4*>(
          (const u16*)src + ((size_t)(b * 512 + c0 + cc)) * N + n0 + nn);
    }
    *reinterpret_cast<uint4*>(&tile[cc][nn]) = *reinterpret_cast<const uint4*>(tmp);
  }
  __syncthreads();
  if (heat != nullptr && t < 32) {
    float s = 0.f;
#pragma unroll 8
    for (int cc = 0; cc < 64; ++cc)
      s += bs2f(tile[cc][2 * t]) + bs2f(tile[cc][2 * t + 1]);
    int y = blockIdx.x;  // N=4096: block spans one spatial row
    atomicAdd(&heat[b * 1024 + (y >> 1) * 32 + t], s);
  }
#pragma unroll
  for (int j = 0; j < 2; ++j) {
    int nn = (t >> 3) + j * 32;
    int cc0 = (t & 7) * 8;
    u16 tmp[8];
#pragma unroll
    for (int u = 0; u < 8; ++u) tmp[u] = tile[cc0 + u][nn];
    *reinterpret_cast<uint4*>(&dst[((size_t)b * N + n0 + nn) * 512 + c0 + cc0]) =
        *reinterpret_cast<const uint4*>(tmp);
  }
}

// ---------------------------------------------------------------------------
// 128m x 64o MFMA conv1x1 GEMM, K=512, single-buffer 27.6 KB LDS, 4 waves,
// wave owns 2 m-tiles. MODE 0: q out [bh][m][64] + fused qsum atomics.
// MODE 3: proj out [b][o][m] dual-dtype (operands swapped).
// ---------------------------------------------------------------------------
template<int MODE>
__global__ __launch_bounds__(256) void gemm128(
    const u16* __restrict__ A, const void* __restrict__ W,
    const void* __restrict__ bias, u16* __restrict__ o0,
    void* __restrict__ ob, float* __restrict__ qsum, int M,
    const int* __restrict__ dtf) {
  const int f32 = *dtf;
  const int b = blockIdx.z, m0 = blockIdx.x * 128, oo0 = blockIdx.y * 64;
  const int t = threadIdx.x, w = t >> 6, lane = t & 63;
  const int quad = lane >> 4, c = lane & 15;
  __shared__ __align__(16) u16 As[128][72];
  __shared__ __align__(16) u16 Ws[64][72];
  f32x4 acc[2][4];
#pragma unroll
  for (int nt = 0; nt < 2; ++nt)
#pragma unroll
    for (int ot = 0; ot < 4; ++ot) acc[nt][ot] = (f32x4){0.f, 0.f, 0.f, 0.f};
  const u16* Ab = A + (size_t)b * M * 512;
  const int arow = t >> 1, acol = (t & 1) * 32;
  const int wrow = t >> 2, wcol = (t & 3) * 16;

  for (int k0 = 0; k0 < 512; k0 += 64) {
    __syncthreads();
    {
      const u16* ga = Ab + (size_t)(m0 + arow) * 512 + k0 + acol;
      uint4* ad = reinterpret_cast<uint4*>(&As[arow][acol]);
      const uint4* gs = reinterpret_cast<const uint4*>(ga);
      ad[0] = gs[0]; ad[1] = gs[1]; ad[2] = gs[2]; ad[3] = gs[3];
      if (f32) {
        const float* gw = (const float*)W + (size_t)(oo0 + wrow) * 512 + k0 + wcol;
#pragma unroll
        for (int e = 0; e < 16; ++e) Ws[wrow][wcol + e] = f2bs(gw[e]);
      } else {
        const u16* gw = (const u16*)W + (size_t)(oo0 + wrow) * 512 + k0 + wcol;
        *reinterpret_cast<uint4*>(&Ws[wrow][wcol])     = *reinterpret_cast<const uint4*>(gw);
        *reinterpret_cast<uint4*>(&Ws[wrow][wcol + 8]) = *reinterpret_cast<const uint4*>(gw + 8);
      }
    }
    __syncthreads();
#pragma unroll
    for (int ks = 0; ks < 2; ++ks) {
      bf16x8 av[2];
      av[0] = *reinterpret_cast<const bf16x8*>(&As[w * 32 + c][ks * 32 + quad * 8]);
      av[1] = *reinterpret_cast<const bf16x8*>(&As[w * 32 + 16 + c][ks * 32 + quad * 8]);
#pragma unroll
      for (int ot = 0; ot < 4; ++ot) {
        bf16x8 wv = *reinterpret_cast<const bf16x8*>(&Ws[ot * 16 + c][ks * 32 + quad * 8]);
#pragma unroll
        for (int nt = 0; nt < 2; ++nt) {
          if (MODE == 3)
            acc[nt][ot] = __builtin_amdgcn_mfma_f32_16x16x32_bf16(wv, av[nt], acc[nt][ot], 0, 0, 0);
          else
            acc[nt][ot] = __builtin_amdgcn_mfma_f32_16x16x32_bf16(av[nt], wv, acc[nt][ot], 0, 0, 0);
        }
      }
    }
  }

  if (MODE == 0) {
    const int h = oo0 >> 6, bh = b * 8 + h;
#pragma unroll
    for (int ot = 0; ot < 4; ++ot) {
      int o = oo0 + ot * 16 + c;
      int d = o & 63;
      float bv = ldf(bias, o, f32);
      float qs = 0.f;
#pragma unroll
      for (int nt = 0; nt < 2; ++nt)
#pragma unroll
        for (int r = 0; r < 4; ++r) {
          int m = m0 + w * 32 + nt * 16 + quad * 4 + r;
          u16 val = f2bs(acc[nt][ot][r] + bv);
          o0[((size_t)bh * M + m) * 64 + d] = val;
          qs += bs2f(val);
        }
      qs += __shfl_xor(qs, 16, 64);
      qs += __shfl_xor(qs, 32, 64);
      if (quad == 0) atomicAdd(&qsum[bh * 64 + d], qs);
    }
  } else {
#pragma unroll
    for (int ot = 0; ot < 4; ++ot)
#pragma unroll
      for (int r = 0; r < 4; ++r) {
        int o = oo0 + ot * 16 + quad * 4 + r;
        float bv = ldf(bias, o, f32);
#pragma unroll
        for (int nt = 0; nt < 2; ++nt) {
          int m = m0 + w * 32 + nt * 16 + c;
          float val = acc[nt][ot][r] + bv;
          size_t oi_ = ((size_t)(b * 512 + o)) * M + m;
          if (f32) ((float*)ob)[oi_] = val;
          else     ((u16*)ob)[oi_] = f2bs(val);
        }
      }
  }
}

// ---------------------------------------------------------------------------
// 64x64 MFMA conv1x1 GEMM for kv_up (M=1024): writes kb [bh][m][64] and
// vTb [bh][d][m].
// ---------------------------------------------------------------------------
__global__ __launch_bounds__(256) void gemm_kv(
    const u16* __restrict__ A, const void* __restrict__ W,
    const void* __restrict__ bias, u16* __restrict__ kb, u16* __restrict__ vTb,
    int M, const int* __restrict__ dtf) {
  const int f32 = *dtf;
  const int b = blockIdx.z, m0 = blockIdx.x * 64, oo0 = blockIdx.y * 64;
  const int t = threadIdx.x, w = t >> 6, lane = t & 63;
  const int quad = lane >> 4, c = lane & 15;
  __shared__ __align__(16) u16 As[64][72];
  __shared__ __align__(16) u16 Ws[64][72];
  f32x4 acc[4];
#pragma unroll
  for (int ot = 0; ot < 4; ++ot) acc[ot] = (f32x4){0.f, 0.f, 0.f, 0.f};
  const u16* Ab = A + (size_t)b * M * 512;
  const int srow = t >> 2, scol = (t & 3) * 16;

  for (int k0 = 0; k0 < 512; k0 += 64) {
    __syncthreads();
    {
      const u16* ga = Ab + (size_t)(m0 + srow) * 512 + k0 + scol;
      *reinterpret_cast<uint4*>(&As[srow][scol])     = *reinterpret_cast<const uint4*>(ga);
      *reinterpret_cast<uint4*>(&As[srow][scol + 8]) = *reinterpret_cast<const uint4*>(ga + 8);
      if (f32) {
        const float* gw = (const float*)W + (size_t)(oo0 + srow) * 512 + k0 + scol;
#pragma unroll
        for (int e = 0; e < 16; ++e) Ws[srow][scol + e] = f2bs(gw[e]);
      } else {
        const u16* gw = (const u16*)W + (size_t)(oo0 + srow) * 512 + k0 + scol;
        *reinterpret_cast<uint4*>(&Ws[srow][scol])     = *reinterpret_cast<const uint4*>(gw);
        *reinterpret_cast<uint4*>(&Ws[srow][scol + 8]) = *reinterpret_cast<const uint4*>(gw + 8);
      }
    }
    __syncthreads();
#pragma unroll
    for (int ks = 0; ks < 2; ++ks) {
      bf16x8 av = *reinterpret_cast<const bf16x8*>(&As[w * 16 + c][ks * 32 + quad * 8]);
#pragma unroll
      for (int ot = 0; ot < 4; ++ot) {
        bf16x8 wv = *reinterpret_cast<const bf16x8*>(&Ws[ot * 16 + c][ks * 32 + quad * 8]);
        acc[ot] = __builtin_amdgcn_mfma_f32_16x16x32_bf16(av, wv, acc[ot], 0, 0, 0);
      }
    }
  }

#pragma unroll
  for (int ot = 0; ot < 4; ++ot) {
    int o = oo0 + ot * 16 + c;
    float bv = ldf(bias, o, f32);
    int hh = o >> 7, jj = o & 127;
#pragma unroll
    for (int r = 0; r < 4; ++r) {
      int m = m0 + w * 16 + quad * 4 + r;
      u16 val = f2bs(acc[ot][r] + bv);
      if (jj < 64) kb[((size_t)(b * 8 + hh) * M + m) * 64 + jj] = val;
      else         vTb[((size_t)(b * 8 + hh) * 64 + (jj & 63)) * M + m] = val;
    }
  }
}

// scores -> top-16 coarse cells -> 64 full-res positions into posb
__global__ __launch_bounds__(256) void topk_kernel(
    const float* __restrict__ qsum, const u16* __restrict__ k,
    const float* __restrict__ heat, const void* __restrict__ gumbel,
    int* __restrict__ posb, const int* __restrict__ dtf) {
  const int f32 = *dtf;
  int bh = blockIdx.x, b = bh >> 3, t = threadIdx.x;
  __shared__ float qs[64];
  __shared__ float s[1024];
  __shared__ float rv[256];
  __shared__ int   ri[256];
  if (t < 64) qs[t] = qsum[bh * 64 + t];
  __syncthreads();
  for (int j = 0; j < 4; ++j) {
    int m = t + j * 256;
    const u16* kr = k + ((size_t)bh * 1024 + m) * 64;
    float dot = 0.f;
    for (int d = 0; d < 64; ++d) dot += qs[d] * bs2f(kr[d]);
    s[m] = dot * (0.125f / 4096.0f) * (heat[b * 1024 + m] * (1.0f / 2048.0f)) +
           ldf(gumbel, (size_t)bh * 1024 + m, f32);
  }
  __syncthreads();
  for (int it = 0; it < 16; ++it) {
    float bv = -1e30f; int bi = 0x7fffffff;
    for (int j = 0; j < 4; ++j) {
      int m = t + j * 256; float vv = s[m];
      if (vv > bv || (vv == bv && m < bi)) { bv = vv; bi = m; }
    }
    rv[t] = bv; ri[t] = bi; __syncthreads();
    for (int off = 128; off; off >>= 1) {
      if (t < off) {
        if (rv[t + off] > rv[t] || (rv[t + off] == rv[t] && ri[t + off] < ri[t])) {
          rv[t] = rv[t + off]; ri[t] = ri[t + off];
        }
      }
      __syncthreads();
    }
    if (t == 0) {
      int mi = ri[0]; s[mi] = -1e30f;
      int hy = (mi >> 5) * 2, wx = (mi & 31) * 2;
      posb[bh * 64 + it]      = hy * 64 + wx;
      posb[bh * 64 + 16 + it] = hy * 64 + wx + 1;
      posb[bh * 64 + 32 + it] = (hy + 1) * 64 + wx;
      posb[bh * 64 + 48 + it] = (hy + 1) * 64 + wx + 1;
    }
    __syncthreads();
  }
}

// ---------------------------------------------------------------------------
// gather_kv as MFMA GEMM (round-5 structure).
// ---------------------------------------------------------------------------
__global__ __launch_bounds__(256) void gather_kv_mfma(
    const u16* __restrict__ xT, const void* __restrict__ kv_w,
    const void* __restrict__ kv_b, const int* __restrict__ posb,
    u16* __restrict__ tkb, u16* __restrict__ tvTb,
    const int* __restrict__ dtf) {
  const int f32 = *dtf;
  const int bh = blockIdx.x, b = bh >> 3, h = bh & 7;
  const int half = blockIdx.y;
  const int t = threadIdx.x, w = t >> 6, lane = t & 63;
  const int quad = lane >> 4, c = lane & 15;
  __shared__ int pos[64];
  __shared__ __align__(16) u16 As[64][72];
  __shared__ __align__(16) u16 Ws[64][72];
  if (t < 64) pos[t] = posb[bh * 64 + t];
  __syncthreads();
  const int obase = h * 128 + half * 64;
  const int srow = t >> 2, scol = (t & 3) * 16;
  const int arow = pos[srow];
  f32x4 acc[4];
#pragma unroll
  for (int ot = 0; ot < 4; ++ot) acc[ot] = (f32x4){0.f, 0.f, 0.f, 0.f};

  for (int k0 = 0; k0 < 512; k0 += 64) {
    __syncthreads();
    {
      const u16* ga = xT + ((size_t)b * 4096 + arow) * 512 + k0 + scol;
      *reinterpret_cast<uint4*>(&As[srow][scol])     = *reinterpret_cast<const uint4*>(ga);
      *reinterpret_cast<uint4*>(&As[srow][scol + 8]) = *reinterpret_cast<const uint4*>(ga + 8);
      if (f32) {
        const float* gw = (const float*)kv_w + (size_t)(obase + srow) * 512 + k0 + scol;
#pragma unroll
        for (int e = 0; e < 16; ++e) Ws[srow][scol + e] = f2bs(gw[e]);
      } else {
        const u16* gw = (const u16*)kv_w + (size_t)(obase + srow) * 512 + k0 + scol;
        *reinterpret_cast<uint4*>(&Ws[srow][scol])     = *reinterpret_cast<const uint4*>(gw);
        *reinterpret_cast<uint4*>(&Ws[srow][scol + 8]) = *reinterpret_cast<const uint4*>(gw + 8);
      }
    }
    __syncthreads();
#pragma unroll
    for (int ks = 0; ks < 2; ++ks) {
      bf16x8 av = *reinterpret_cast<const bf16x8*>(&As[w * 16 + c][ks * 32 + quad * 8]);
#pragma unroll
      for (int ot = 0; ot < 4; ++ot) {
        bf16x8 wv = *reinterpret_cast<const bf16x8*>(&Ws[ot * 16 + c][ks * 32 + quad * 8]);
        acc[ot] = __builtin_amdgcn_mfma_f32_16x16x32_bf16(av, wv, acc[ot], 0, 0, 0);
      }
    }
  }

#pragma unroll
  for (int ot = 0; ot < 4; ++ot) {
    int d = ot * 16 + c;
    float bv = ldf(kv_b, obase + d, f32);
#pragma unroll
    for (int r = 0; r < 4; ++r) {
      int m = w * 16 + quad * 4 + r;
      u16 val = f2bs(acc[ot][r] + bv);
      if (half) tvTb[((size_t)bh * 64 + d) * 64 + m] = val;
      else      tkb[((size_t)bh * 64 + m) * 64 + d] = val;
    }
  }
}

// ---------------------------------------------------------------------------
// coarse attention: 128 n per block, double-buffered LDS staging (round 8).
// ---------------------------------------------------------------------------
__global__ __launch_bounds__(256) void coarse_attn_mfma(
    const u16* __restrict__ q, const u16* __restrict__ k,
    const u16* __restrict__ vT, u16* __restrict__ coarse) {
  const int bh = blockIdx.y;
  const int n0 = blockIdx.x * 128;
  const int t = threadIdx.x, w = t >> 6, lane = t & 63;
  const int quad = lane >> 4, c = lane & 15;
  __shared__ __align__(16) u16 Ks[2][64][72];
  __shared__ __align__(16) u16 Vt[2][64][72];
  __shared__ __align__(16) u16 Ps[4][2][16][72];

  bf16x8 bq[2][2];
#pragma unroll
  for (int nt = 0; nt < 2; ++nt) {
    const u16* qr = q + ((size_t)bh * 4096 + n0 + w * 32 + nt * 16 + c) * 64;
    bq[nt][0] = *reinterpret_cast<const bf16x8*>(qr + quad * 8);
    bq[nt][1] = *reinterpret_cast<const bf16x8*>(qr + 32 + quad * 8);
  }
  f32x4 po[2][4];
#pragma unroll
  for (int nt = 0; nt < 2; ++nt)
#pragma unroll
    for (int dt = 0; dt < 4; ++dt) po[nt][dt] = (f32x4){0.f, 0.f, 0.f, 0.f};
  float sume[2] = {0.f, 0.f};

  const u16* kbase = k + (size_t)bh * 65536;
  const u16* vbase = vT + (size_t)bh * 65536;
  const int srow = t >> 2, scol = (t & 3) * 16;

  uint4 kr0, kr1, vr0, vr1;
  {
    const u16* gk = kbase + (size_t)srow * 64 + scol;
    kr0 = *reinterpret_cast<const uint4*>(gk);
    kr1 = *reinterpret_cast<const uint4*>(gk + 8);
    const u16* gv = vbase + (size_t)srow * 1024 + scol;
    vr0 = *reinterpret_cast<const uint4*>(gv);
    vr1 = *reinterpret_cast<const uint4*>(gv + 8);
    *reinterpret_cast<uint4*>(&Ks[0][srow][scol])     = kr0;
    *reinterpret_cast<uint4*>(&Ks[0][srow][scol + 8]) = kr1;
    *reinterpret_cast<uint4*>(&Vt[0][srow][scol])     = vr0;
    *reinterpret_cast<uint4*>(&Vt[0][srow][scol + 8]) = vr1;
  }

  for (int ch = 0; ch < 16; ++ch) {
    __syncthreads();
    const int buf = ch & 1;
    if (ch + 1 < 16) {
      int m1 = (ch + 1) * 64;
      const u16* gk = kbase + (size_t)(m1 + srow) * 64 + scol;
      kr0 = *reinterpret_cast<const uint4*>(gk);
      kr1 = *reinterpret_cast<const uint4*>(gk + 8);
      const u16* gv = vbase + (size_t)srow * 1024 + m1 + scol;
      vr0 = *reinterpret_cast<const uint4*>(gv);
      vr1 = *reinterpret_cast<const uint4*>(gv + 8);
    }

    f32x4 st[2][4];
#pragma unroll
    for (int mt = 0; mt < 4; ++mt) {
      bf16x8 ak0 = *reinterpret_cast<const bf16x8*>(&Ks[buf][mt * 16 + c][quad * 8]);
      bf16x8 ak1 = *reinterpret_cast<const bf16x8*>(&Ks[buf][mt * 16 + c][32 + quad * 8]);
#pragma unroll
      for (int nt = 0; nt < 2; ++nt) {
        f32x4 acc = (f32x4){0.f, 0.f, 0.f, 0.f};
        acc = __builtin_amdgcn_mfma_f32_16x16x32_bf16(ak0, bq[nt][0], acc, 0, 0, 0);
        acc = __builtin_amdgcn_mfma_f32_16x16x32_bf16(ak1, bq[nt][1], acc, 0, 0, 0);
        st[nt][mt] = acc;
      }
    }
#pragma unroll
    for (int nt = 0; nt < 2; ++nt) {
      float cs = 0.f;
#pragma unroll
      for (int mt = 0; mt < 4; ++mt) {
        float e0 = __expf(st[nt][mt][0] * 0.125f);
        float e1 = __expf(st[nt][mt][1] * 0.125f);
        float e2 = __expf(st[nt][mt][2] * 0.125f);
        float e3 = __expf(st[nt][mt][3] * 0.125f);
        cs += (e0 + e1) + (e2 + e3);
        ushort4 pw;
        pw.x = f2bs(e0); pw.y = f2bs(e1); pw.z = f2bs(e2); pw.w = f2bs(e3);
        *reinterpret_cast<ushort4*>(&Ps[w][nt][c][mt * 16 + quad * 4]) = pw;
      }
      cs += __shfl_xor(cs, 16, 64);
      cs += __shfl_xor(cs, 32, 64);
      sume[nt] += cs;
    }
#pragma unroll
    for (int s = 0; s < 2; ++s) {
      bf16x8 bp0 = *reinterpret_cast<const bf16x8*>(&Ps[w][0][c][s * 32 + quad * 8]);
      bf16x8 bp1 = *reinterpret_cast<const bf16x8*>(&Ps[w][1][c][s * 32 + quad * 8]);
#pragma unroll
      for (int dt = 0; dt < 4; ++dt) {
        bf16x8 av = *reinterpret_cast<const bf16x8*>(&Vt[buf][dt * 16 + c][s * 32 + quad * 8]);
        po[0][dt] = __builtin_amdgcn_mfma_f32_16x16x32_bf16(av, bp0, po[0][dt], 0, 0, 0);
        po[1][dt] = __builtin_amdgcn_mfma_f32_16x16x32_bf16(av, bp1, po[1][dt], 0, 0, 0);
      }
    }

    if (ch + 1 < 16) {
      const int nb = buf ^ 1;
      *reinterpret_cast<uint4*>(&Ks[nb][srow][scol])     = kr0;
      *reinterpret_cast<uint4*>(&Ks[nb][srow][scol + 8]) = kr1;
      *reinterpret_cast<uint4*>(&Vt[nb][srow][scol])     = vr0;
      *reinterpret_cast<uint4*>(&Vt[nb][srow][scol + 8]) = vr1;
    }
  }

#pragma unroll
  for (int nt = 0; nt < 2; ++nt) {
    float inv = 1.0f / sume[nt];
    u16* orow = coarse + ((size_t)bh * 4096 + n0 + w * 32 + nt * 16 + c) * 64;
#pragma unroll
    for (int dt = 0; dt < 4; ++dt) {
      ushort4 r;
      r.x = f2bs(po[nt][dt][0] * inv); r.y = f2bs(po[nt][dt][1] * inv);
      r.z = f2bs(po[nt][dt][2] * inv); r.w = f2bs(po[nt][dt][3] * inv);
      *reinterpret_cast<ushort4*>(&orow[dt * 16 + quad * 4]) = r;
    }
  }
}

// depthwise 7x7 conv on vT (bf16, [bh][d][m] - contiguous rows) -> vpe bf16
__global__ __launch_bounds__(256) void dwconv_kernel(
    const u16* __restrict__ vT, const void* __restrict__ pe_w,
    const void* __restrict__ pe_b, u16* __restrict__ vpe,
    const int* __restrict__ dtf) {
  const int f32 = *dtf;
  int bc = blockIdx.x;
  int b = bc >> 9, c = bc & 511;
  int h = c >> 6, d = c & 63;
  int t = threadIdx.x;
  __shared__ float img[1024];
  __shared__ float wts[49];
  const u16* base = vT + ((size_t)(b * 8 + h) * 64 + d) * 1024;
  if (t < 128) {
    uint4 v4 = reinterpret_cast<const uint4*>(base)[t];
    u16 tmp[8];
    *reinterpret_cast<uint4*>(tmp) = v4;
#pragma unroll
    for (int e = 0; e < 8; ++e) img[t * 8 + e] = bs2f(tmp[e]);
  }
  if (t < 49) wts[t] = ldf(pe_w, c * 49 + t, f32);
  float bias = ldf(pe_b, c, f32);
  __syncthreads();
  for (int i = t; i < 1024; i += 256) {
    int y = i >> 5, xx = i & 31;
    float a = 0.f;
#pragma unroll
    for (int ky = 0; ky < 7; ++ky) {
      int yy = y + ky - 3;
      if ((unsigned)yy >= 32u) continue;
#pragma unroll
      for (int kx = 0; kx < 7; ++kx) {
        int xc = xx + kx - 3;
        if ((unsigned)xc >= 32u) continue;
        a += img[yy * 32 + xc] * wts[ky * 7 + kx];
      }
    }
    vpe[(size_t)bc * 1024 + i] = f2bs(a + bias);
  }
}

// ---------------------------------------------------------------------------
// fused fine attention + gate MFMA + combine + bilinear vpe add -> xsT bf16.
// (round-9 v2 structure: 28 KB LDS, one barrier)
// ---------------------------------------------------------------------------
__global__ __launch_bounds__(256) void fine_mfma(
    const u16* __restrict__ q, const u16* __restrict__ tkb,
    const u16* __restrict__ tvTb, const u16* __restrict__ co,
    const u16* __restrict__ gwb, const float* __restrict__ gbf,
    const u16* __restrict__ vpe, u16* __restrict__ xsT) {
  const int bh = blockIdx.y, b = bh >> 3, h = bh & 7;
  const int y = blockIdx.x;
  const int n0 = y * 64;
  const int t = threadIdx.x, w = t >> 6, lane = t & 63;
  const int quad = lane >> 4, c = lane & 15;

  __shared__ __align__(16) u16 fus[4][16][136];
  __shared__ __align__(16) u16 vl[2][64][40];
  __shared__ float gbl[64];

  int jy = y >> 1, y0, y1; float wy0, wy1;
  if ((y & 1) == 0) { y0 = (jy > 0) ? jy - 1 : 0; y1 = jy; wy0 = 0.25f; wy1 = 0.75f; }
  else              { y0 = jy; y1 = (jy < 31) ? jy + 1 : 31; wy0 = 0.75f; wy1 = 0.25f; }

  for (int idx = t; idx < 512; idx += 256) {
    int seg = idx & 3, ch = (idx >> 2) & 63, r = idx >> 8;
    int yy = r ? y1 : y0;
    const uint4* src = reinterpret_cast<const uint4*>(
        vpe + ((size_t)(b * 512 + h * 64 + ch)) * 1024 + yy * 32);
    *reinterpret_cast<uint4*>(&vl[r][ch][seg * 8]) = src[seg];
  }
  if (t < 64) gbl[t] = gbf[t];

  const int n = n0 + w * 16 + c;
  bf16x8 bq[2];
  {
    const u16* qr = q + ((size_t)bh * 4096 + n) * 64;
    bq[0] = *reinterpret_cast<const bf16x8*>(qr + quad * 8);
    bq[1] = *reinterpret_cast<const bf16x8*>(qr + 32 + quad * 8);
  }
  __syncthreads();

  f32x4 st[4];
#pragma unroll
  for (int mt = 0; mt < 4; ++mt) {
    f32x4 acc = (f32x4){0.f, 0.f, 0.f, 0.f};
#pragma unroll
    for (int s = 0; s < 2; ++s) {
      bf16x8 ak = *reinterpret_cast<const bf16x8*>(
          &tkb[((size_t)bh * 64 + mt * 16 + c) * 64 + s * 32 + quad * 8]);
      acc = __builtin_amdgcn_mfma_f32_16x16x32_bf16(ak, bq[s], acc, 0, 0, 0);
    }
    st[mt] = acc;
  }
  float sume = 0.f;
#pragma unroll
  for (int mt = 0; mt < 4; ++mt) {
    float e0 = __expf(st[mt][0] * 0.125f);
    float e1 = __expf(st[mt][1] * 0.125f);
    float e2 = __expf(st[mt][2] * 0.125f);
    float e3 = __expf(st[mt][3] * 0.125f);
    sume += (e0 + e1) + (e2 + e3);
    ushort4 pw;
    pw.x = f2bs(e0); pw.y = f2bs(e1); pw.z = f2bs(e2); pw.w = f2bs(e3);
    *reinterpret_cast<ushort4*>(&fus[w][c][mt * 16 + quad * 4]) = pw;
  }
  sume += __shfl_xor(sume, 16, 64);
  sume += __shfl_xor(sume, 32, 64);
  float inv = 1.0f / sume;

  f32x4 po[4];
#pragma unroll
  for (int dt = 0; dt < 4; ++dt) po[dt] = (f32x4){0.f, 0.f, 0.f, 0.f};
#pragma unroll
  for (int s = 0; s < 2; ++s) {
    bf16x8 bp = *reinterpret_cast<const bf16x8*>(&fus[w][c][s * 32 + quad * 8]);
#pragma unroll
    for (int dt = 0; dt < 4; ++dt) {
      bf16x8 av = *reinterpret_cast<const bf16x8*>(
          &tvTb[((size_t)bh * 64 + dt * 16 + c) * 64 + s * 32 + quad * 8]);
      po[dt] = __builtin_amdgcn_mfma_f32_16x16x32_bf16(av, bp, po[dt], 0, 0, 0);
    }
  }

  {
    const u16* crow = co + ((size_t)bh * 4096 + n) * 64 + quad * 16;
    *reinterpret_cast<uint4*>(&fus[w][c][quad * 16])     = *reinterpret_cast<const uint4*>(crow);
    *reinterpret_cast<uint4*>(&fus[w][c][quad * 16 + 8]) = *reinterpret_cast<const uint4*>(crow + 8);
  }
#pragma unroll
  for (int dt = 0; dt < 4; ++dt) {
    ushort4 rw;
    rw.x = f2bs(po[dt][0] * inv); rw.y = f2bs(po[dt][1] * inv);
    rw.z = f2bs(po[dt][2] * inv); rw.w = f2bs(po[dt][3] * inv);
    *reinterpret_cast<ushort4*>(&fus[w][c][64 + dt * 16 + quad * 4]) = rw;
  }

  f32x4 ga[4];
#pragma unroll
  for (int ot = 0; ot < 4; ++ot) ga[ot] = (f32x4){0.f, 0.f, 0.f, 0.f};
#pragma unroll
  for (int s = 0; s < 4; ++s) {
    bf16x8 bf = *reinterpret_cast<const bf16x8*>(&fus[w][c][s * 32 + quad * 8]);
#pragma unroll
    for (int ot = 0; ot < 4; ++ot) {
      bf16x8 ag = *reinterpret_cast<const bf16x8*>(
          gwb + (ot * 16 + c) * 128 + s * 32 + quad * 8);
      ga[ot] = __builtin_amdgcn_mfma_f32_16x16x32_bf16(ag, bf, ga[ot], 0, 0, 0);
    }
  }

  const int x = w * 16 + c;
  int jx = x >> 1, x0, x1; float wx0, wx1;
  if ((x & 1) == 0) { x0 = (jx > 0) ? jx - 1 : 0; x1 = jx; wx0 = 0.25f; wx1 = 0.75f; }
  else              { x0 = jx; x1 = (jx < 31) ? jx + 1 : 31; wx0 = 0.75f; wx1 = 0.25f; }
#pragma unroll
  for (int dt = 0; dt < 4; ++dt) {
    ushort4 ow;
    u16 tmp[4];
#pragma unroll
    for (int r = 0; r < 4; ++r) {
      int row = dt * 16 + quad * 4 + r;
      float ref = po[dt][r] * inv;
      float coar = bs2f(fus[w][c][row]);
      float g = 1.0f / (1.0f + __expf(-(ga[dt][r] + gbl[row])));
      float vv = wy0 * (wx0 * bs2f(vl[0][row][x0]) + wx1 * bs2f(vl[0][row][x1])) +
                 wy1 * (wx0 * bs2f(vl[1][row][x0]) + wx1 * bs2f(vl[1][row][x1]));
      tmp[r] = f2bs(g * ref + (1.0f - g) * coar + vv);
    }
    ow.x = tmp[0]; ow.y = tmp[1]; ow.z = tmp[2]; ow.w = tmp[3];
    *reinterpret_cast<ushort4*>(&fus[w][c][dt * 16 + quad * 4]) = ow;
  }

  {
    int nl = lane >> 2, cs = (lane & 3) * 16;
    u16* dst = xsT + ((size_t)b * 4096 + n0 + w * 16 + nl) * 512 + h * 64 + cs;
    *reinterpret_cast<uint4*>(dst)     = *reinterpret_cast<const uint4*>(&fus[w][nl][cs]);
    *reinterpret_cast<uint4*>(dst + 8) = *reinterpret_cast<const uint4*>(&fus[w][nl][cs + 8]);
  }
}

extern "C" void kernel_launch(void* const* d_in, const int* in_sizes, int n_in,
                              void* d_out, int out_size, void* d_ws, size_t ws_size,
                              hipStream_t stream) {
  const void* x    = d_in[0];
  const void* up   = d_in[1];
  const void* gum  = d_in[2];
  const void* q_w  = d_in[3];
  const void* q_b  = d_in[4];
  const void* kv_w = d_in[5];
  const void* kv_b = d_in[6];
  const void* p_w  = d_in[7];
  const void* p_b  = d_in[8];
  const void* pe_w = d_in[9];
  const void* pe_b = d_in[10];
  const void* g_w  = d_in[11];
  const void* g_b  = d_in[12];

  float* ws    = (float*)d_ws;
  int*   dtf   = (int*)ws;                   // 16 f
  float* qsum  = ws + 16;                    // 1024 f  [bh][64]
  float* heat  = qsum + 1024;                // 2048 f
  int*   posb  = (int*)(heat + 2048);        // 1024 ints
  float* gbf   = (float*)(posb + 1024);      // 64
  u16*   gwb   = (u16*)(gbf + 64);           // 8192 u16
  u16*   tkb   = gwb + 8192;                 // 65536
  u16*   tvTb  = tkb + 65536;                // 65536
  u16*   qb    = tvTb + 65536;               // 4M
  u16*   kb    = qb + 4194304;               // 1M
  u16*   vTb   = kb + 1048576;               // 1M
  u16*   xT    = vTb + 1048576;              // 4M
  u16*   upT   = xT + 4194304;               // 1M
  u16*   co    = upT + 1048576;              // 4M
  u16*   xsT   = co + 4194304;               // 4M
  u16*   vpe   = xsT + 4194304;              // 1M   (~34 MB total)

  dim3 blk(256);
  hipMemsetAsync(ws, 0, (16 + 1024 + 2048) * 4, stream);  // dtf + qsum + heat
  detect_dtype<<<dim3(64), blk, 0, stream>>>((const uint4*)x, dtf);
  prep_gate<<<dim3(1), blk, 0, stream>>>(g_w, g_b, gwb, gbf, dtf);
  transpose_bf16<<<dim3(64, 8, 2), blk, 0, stream>>>(x, xT, 4096, heat, dtf);
  transpose_bf16<<<dim3(16, 8, 2), blk, 0, stream>>>(up, upT, 1024, nullptr, dtf);
  gemm128<0><<<dim3(32, 8, 2), blk, 0, stream>>>(xT, q_w, q_b, qb, nullptr, qsum, 4096, dtf);
  gemm_kv<<<dim3(16, 16, 2), blk, 0, stream>>>(upT, kv_w, kv_b, kb, vTb, 1024, dtf);
  topk_kernel<<<dim3(16), blk, 0, stream>>>(qsum, kb, heat, gum, posb, dtf);
  gather_kv_mfma<<<dim3(16, 2), blk, 0, stream>>>(xT, kv_w, kv_b, posb, tkb, tvTb, dtf);
  coarse_attn_mfma<<<dim3(32, 16), blk, 0, stream>>>(qb, kb, vTb, co);
  dwconv_kernel<<<dim3(1024), blk, 0, stream>>>(vTb, pe_w, pe_b, vpe, dtf);
  fine_mfma<<<dim3(64, 16), blk, 0, stream>>>(qb, tkb, tvTb, co, gwb, gbf, vpe, xsT);
  gemm128<3><<<dim3(32, 8, 2), blk, 0, stream>>>(xsT, p_w, p_b, nullptr, d_out, nullptr, 4096, dtf);
}

// Round 11
// 263.905 us; speedup vs baseline: 6.3878x; 1.0296x over previous
//
#include <hip/hip_runtime.h>
#include <hip/hip_bf16.h>
#include <cstdint>

typedef __hip_bfloat16 bf16;
typedef unsigned short u16;
typedef __attribute__((ext_vector_type(8))) short bf16x8;
typedef __attribute__((ext_vector_type(4))) float f32x4;

static __device__ __forceinline__ float bs2f(u16 s) {
  unsigned int u = ((unsigned int)s) << 16;
  float f;
  __builtin_memcpy(&f, &u, 4);
  return f;
}
static __device__ __forceinline__ u16 f2bs(float f) {
  bf16 h = __float2bfloat16(f);
  u16 s;
  __builtin_memcpy(&s, &h, 2);
  return s;
}
static __device__ __forceinline__ float ldf(const void* p, size_t i, int f32) {
  return f32 ? ((const float*)p)[i] : bs2f(((const u16*)p)[i]);
}

// ---------------------------------------------------------------------------
// dtype detection on a 256 KB sample of x.
// ---------------------------------------------------------------------------
__global__ __launch_bounds__(256) void detect_dtype(const uint4* __restrict__ xs,
                                                    int* __restrict__ flag) {
  int i = blockIdx.x * 256 + threadIdx.x;
  uint4 v = xs[i];
  bool hit = false;
#pragma unroll
  for (int j = 0; j < 4; ++j) {
    unsigned w = (j == 0) ? v.x : (j == 1) ? v.y : (j == 2) ? v.z : v.w;
    if ((w & 0x7F80u) == 0x7F80u) hit = true;
    if ((w & 0x7F800000u) == 0x7F800000u) hit = true;
  }
  unsigned long long mask = __ballot(hit);
  if (mask != 0ull && (threadIdx.x & 63) == 0) atomicOr(flag, 1);
}

// one-time gate weights conversion -> bf16 gwb[64][128], f32 gbf[64]
__global__ __launch_bounds__(256) void prep_gate(
    const void* __restrict__ gate_w, const void* __restrict__ gate_b,
    u16* __restrict__ gwb, float* __restrict__ gbf,
    const int* __restrict__ dtf) {
  const int f32 = *dtf;
  int t = threadIdx.x;
  for (int i = t; i < 8192; i += 256)
    gwb[i] = f32 ? f2bs(((const float*)gate_w)[i]) : ((const u16*)gate_w)[i];
  if (t < 64) gbf[t] = ldf(gate_b, t, f32);
}

// ---------------------------------------------------------------------------
// transpose [b][c=512][N] -> [b][N][512] bf16; optional fused heat partials.
// ---------------------------------------------------------------------------
__global__ __launch_bounds__(256) void transpose_bf16(
    const void* __restrict__ src, u16* __restrict__ dst, int N,
    float* __restrict__ heat, const int* __restrict__ dtf) {
  const int f32 = *dtf;
  const int b = blockIdx.z, n0 = blockIdx.x * 64, c0 = blockIdx.y * 64;
  const int t = threadIdx.x;
  __shared__ __align__(16) u16 tile[64][72];
#pragma unroll
  for (int j = 0; j < 2; ++j) {
    int cc = (t >> 3) + j * 32;
    int nn = (t & 7) * 8;
    u16 tmp[8];
    if (f32) {
      const float* s4 = (const float*)src + ((size_t)(b * 512 + c0 + cc)) * N + n0 + nn;
#pragma unroll
      for (int u = 0; u < 8; ++u) tmp[u] = f2bs(s4[u]);
    } else {
      *reinterpret_cast<uint4*>(tmp) = *reinterpret_cast<const uint4*>(
          (const u16*)src + ((size_t)(b * 512 + c0 + cc)) * N + n0 + nn);
    }
    *reinterpret_cast<uint4*>(&tile[cc][nn]) = *reinterpret_cast<const uint4*>(tmp);
  }
  __syncthreads();
  if (heat != nullptr && t < 32) {
    float s = 0.f;
#pragma unroll 8
    for (int cc = 0; cc < 64; ++cc)
      s += bs2f(tile[cc][2 * t]) + bs2f(tile[cc][2 * t + 1]);
    int y = blockIdx.x;
    atomicAdd(&heat[b * 1024 + (y >> 1) * 32 + t], s);
  }
#pragma unroll
  for (int j = 0; j < 2; ++j) {
    int nn = (t >> 3) + j * 32;
    int cc0 = (t & 7) * 8;
    u16 tmp[8];
#pragma unroll
    for (int u = 0; u < 8; ++u) tmp[u] = tile[cc0 + u][nn];
    *reinterpret_cast<uint4*>(&dst[((size_t)b * N + n0 + nn) * 512 + c0 + cc0]) =
        *reinterpret_cast<const uint4*>(tmp);
  }
}

// ---------------------------------------------------------------------------
// 128m x 64o MFMA conv1x1 GEMM (round 10).
// ---------------------------------------------------------------------------
template<int MODE>
__global__ __launch_bounds__(256) void gemm128(
    const u16* __restrict__ A, const void* __restrict__ W,
    const void* __restrict__ bias, u16* __restrict__ o0,
    void* __restrict__ ob, float* __restrict__ qsum, int M,
    const int* __restrict__ dtf) {
  const int f32 = *dtf;
  const int b = blockIdx.z, m0 = blockIdx.x * 128, oo0 = blockIdx.y * 64;
  const int t = threadIdx.x, w = t >> 6, lane = t & 63;
  const int quad = lane >> 4, c = lane & 15;
  __shared__ __align__(16) u16 As[128][72];
  __shared__ __align__(16) u16 Ws[64][72];
  f32x4 acc[2][4];
#pragma unroll
  for (int nt = 0; nt < 2; ++nt)
#pragma unroll
    for (int ot = 0; ot < 4; ++ot) acc[nt][ot] = (f32x4){0.f, 0.f, 0.f, 0.f};
  const u16* Ab = A + (size_t)b * M * 512;
  const int arow = t >> 1, acol = (t & 1) * 32;
  const int wrow = t >> 2, wcol = (t & 3) * 16;

  for (int k0 = 0; k0 < 512; k0 += 64) {
    __syncthreads();
    {
      const u16* ga = Ab + (size_t)(m0 + arow) * 512 + k0 + acol;
      uint4* ad = reinterpret_cast<uint4*>(&As[arow][acol]);
      const uint4* gs = reinterpret_cast<const uint4*>(ga);
      ad[0] = gs[0]; ad[1] = gs[1]; ad[2] = gs[2]; ad[3] = gs[3];
      if (f32) {
        const float* gw = (const float*)W + (size_t)(oo0 + wrow) * 512 + k0 + wcol;
#pragma unroll
        for (int e = 0; e < 16; ++e) Ws[wrow][wcol + e] = f2bs(gw[e]);
      } else {
        const u16* gw = (const u16*)W + (size_t)(oo0 + wrow) * 512 + k0 + wcol;
        *reinterpret_cast<uint4*>(&Ws[wrow][wcol])     = *reinterpret_cast<const uint4*>(gw);
        *reinterpret_cast<uint4*>(&Ws[wrow][wcol + 8]) = *reinterpret_cast<const uint4*>(gw + 8);
      }
    }
    __syncthreads();
#pragma unroll
    for (int ks = 0; ks < 2; ++ks) {
      bf16x8 av[2];
      av[0] = *reinterpret_cast<const bf16x8*>(&As[w * 32 + c][ks * 32 + quad * 8]);
      av[1] = *reinterpret_cast<const bf16x8*>(&As[w * 32 + 16 + c][ks * 32 + quad * 8]);
#pragma unroll
      for (int ot = 0; ot < 4; ++ot) {
        bf16x8 wv = *reinterpret_cast<const bf16x8*>(&Ws[ot * 16 + c][ks * 32 + quad * 8]);
#pragma unroll
        for (int nt = 0; nt < 2; ++nt) {
          if (MODE == 3)
            acc[nt][ot] = __builtin_amdgcn_mfma_f32_16x16x32_bf16(wv, av[nt], acc[nt][ot], 0, 0, 0);
          else
            acc[nt][ot] = __builtin_amdgcn_mfma_f32_16x16x32_bf16(av[nt], wv, acc[nt][ot], 0, 0, 0);
        }
      }
    }
  }

  if (MODE == 0) {
    const int h = oo0 >> 6, bh = b * 8 + h;
#pragma unroll
    for (int ot = 0; ot < 4; ++ot) {
      int o = oo0 + ot * 16 + c;
      int d = o & 63;
      float bv = ldf(bias, o, f32);
      float qs = 0.f;
#pragma unroll
      for (int nt = 0; nt < 2; ++nt)
#pragma unroll
        for (int r = 0; r < 4; ++r) {
          int m = m0 + w * 32 + nt * 16 + quad * 4 + r;
          u16 val = f2bs(acc[nt][ot][r] + bv);
          o0[((size_t)bh * M + m) * 64 + d] = val;
          qs += bs2f(val);
        }
      qs += __shfl_xor(qs, 16, 64);
      qs += __shfl_xor(qs, 32, 64);
      if (quad == 0) atomicAdd(&qsum[bh * 64 + d], qs);
    }
  } else {
#pragma unroll
    for (int ot = 0; ot < 4; ++ot)
#pragma unroll
      for (int r = 0; r < 4; ++r) {
        int o = oo0 + ot * 16 + quad * 4 + r;
        float bv = ldf(bias, o, f32);
#pragma unroll
        for (int nt = 0; nt < 2; ++nt) {
          int m = m0 + w * 32 + nt * 16 + c;
          float val = acc[nt][ot][r] + bv;
          size_t oi_ = ((size_t)(b * 512 + o)) * M + m;
          if (f32) ((float*)ob)[oi_] = val;
          else     ((u16*)ob)[oi_] = f2bs(val);
        }
      }
  }
}

// ---------------------------------------------------------------------------
// 64x64 MFMA conv1x1 GEMM for kv_up: kb [bh][m][64], vTb [bh][d][m].
// ---------------------------------------------------------------------------
__global__ __launch_bounds__(256) void gemm_kv(
    const u16* __restrict__ A, const void* __restrict__ W,
    const void* __restrict__ bias, u16* __restrict__ kb, u16* __restrict__ vTb,
    int M, const int* __restrict__ dtf) {
  const int f32 = *dtf;
  const int b = blockIdx.z, m0 = blockIdx.x * 64, oo0 = blockIdx.y * 64;
  const int t = threadIdx.x, w = t >> 6, lane = t & 63;
  const int quad = lane >> 4, c = lane & 15;
  __shared__ __align__(16) u16 As[64][72];
  __shared__ __align__(16) u16 Ws[64][72];
  f32x4 acc[4];
#pragma unroll
  for (int ot = 0; ot < 4; ++ot) acc[ot] = (f32x4){0.f, 0.f, 0.f, 0.f};
  const u16* Ab = A + (size_t)b * M * 512;
  const int srow = t >> 2, scol = (t & 3) * 16;

  for (int k0 = 0; k0 < 512; k0 += 64) {
    __syncthreads();
    {
      const u16* ga = Ab + (size_t)(m0 + srow) * 512 + k0 + scol;
      *reinterpret_cast<uint4*>(&As[srow][scol])     = *reinterpret_cast<const uint4*>(ga);
      *reinterpret_cast<uint4*>(&As[srow][scol + 8]) = *reinterpret_cast<const uint4*>(ga + 8);
      if (f32) {
        const float* gw = (const float*)W + (size_t)(oo0 + srow) * 512 + k0 + scol;
#pragma unroll
        for (int e = 0; e < 16; ++e) Ws[srow][scol + e] = f2bs(gw[e]);
      } else {
        const u16* gw = (const u16*)W + (size_t)(oo0 + srow) * 512 + k0 + scol;
        *reinterpret_cast<uint4*>(&Ws[srow][scol])     = *reinterpret_cast<const uint4*>(gw);
        *reinterpret_cast<uint4*>(&Ws[srow][scol + 8]) = *reinterpret_cast<const uint4*>(gw + 8);
      }
    }
    __syncthreads();
#pragma unroll
    for (int ks = 0; ks < 2; ++ks) {
      bf16x8 av = *reinterpret_cast<const bf16x8*>(&As[w * 16 + c][ks * 32 + quad * 8]);
#pragma unroll
      for (int ot = 0; ot < 4; ++ot) {
        bf16x8 wv = *reinterpret_cast<const bf16x8*>(&Ws[ot * 16 + c][ks * 32 + quad * 8]);
        acc[ot] = __builtin_amdgcn_mfma_f32_16x16x32_bf16(av, wv, acc[ot], 0, 0, 0);
      }
    }
  }

#pragma unroll
  for (int ot = 0; ot < 4; ++ot) {
    int o = oo0 + ot * 16 + c;
    float bv = ldf(bias, o, f32);
    int hh = o >> 7, jj = o & 127;
#pragma unroll
    for (int r = 0; r < 4; ++r) {
      int m = m0 + w * 16 + quad * 4 + r;
      u16 val = f2bs(acc[ot][r] + bv);
      if (jj < 64) kb[((size_t)(b * 8 + hh) * M + m) * 64 + jj] = val;
      else         vTb[((size_t)(b * 8 + hh) * 64 + (jj & 63)) * M + m] = val;
    }
  }
}

// scores -> top-16 coarse cells -> 64 full-res positions into posb
__global__ __launch_bounds__(256) void topk_kernel(
    const float* __restrict__ qsum, const u16* __restrict__ k,
    const float* __restrict__ heat, const void* __restrict__ gumbel,
    int* __restrict__ posb, const int* __restrict__ dtf) {
  const int f32 = *dtf;
  int bh = blockIdx.x, b = bh >> 3, t = threadIdx.x;
  __shared__ float qs[64];
  __shared__ float s[1024];
  __shared__ float rv[256];
  __shared__ int   ri[256];
  if (t < 64) qs[t] = qsum[bh * 64 + t];
  __syncthreads();
  for (int j = 0; j < 4; ++j) {
    int m = t + j * 256;
    const u16* kr = k + ((size_t)bh * 1024 + m) * 64;
    float dot = 0.f;
    for (int d = 0; d < 64; ++d) dot += qs[d] * bs2f(kr[d]);
    s[m] = dot * (0.125f / 4096.0f) * (heat[b * 1024 + m] * (1.0f / 2048.0f)) +
           ldf(gumbel, (size_t)bh * 1024 + m, f32);
  }
  __syncthreads();
  for (int it = 0; it < 16; ++it) {
    float bv = -1e30f; int bi = 0x7fffffff;
    for (int j = 0; j < 4; ++j) {
      int m = t + j * 256; float vv = s[m];
      if (vv > bv || (vv == bv && m < bi)) { bv = vv; bi = m; }
    }
    rv[t] = bv; ri[t] = bi; __syncthreads();
    for (int off = 128; off; off >>= 1) {
      if (t < off) {
        if (rv[t + off] > rv[t] || (rv[t + off] == rv[t] && ri[t + off] < ri[t])) {
          rv[t] = rv[t + off]; ri[t] = ri[t + off];
        }
      }
      __syncthreads();
    }
    if (t == 0) {
      int mi = ri[0]; s[mi] = -1e30f;
      int hy = (mi >> 5) * 2, wx = (mi & 31) * 2;
      posb[bh * 64 + it]      = hy * 64 + wx;
      posb[bh * 64 + 16 + it] = hy * 64 + wx + 1;
      posb[bh * 64 + 32 + it] = (hy + 1) * 64 + wx;
      posb[bh * 64 + 48 + it] = (hy + 1) * 64 + wx + 1;
    }
    __syncthreads();
  }
}

// ---------------------------------------------------------------------------
// gather_kv as MFMA GEMM (round-5 structure).
// ---------------------------------------------------------------------------
__global__ __launch_bounds__(256) void gather_kv_mfma(
    const u16* __restrict__ xT, const void* __restrict__ kv_w,
    const void* __restrict__ kv_b, const int* __restrict__ posb,
    u16* __restrict__ tkb, u16* __restrict__ tvTb,
    const int* __restrict__ dtf) {
  const int f32 = *dtf;
  const int bh = blockIdx.x, b = bh >> 3, h = bh & 7;
  const int half = blockIdx.y;
  const int t = threadIdx.x, w = t >> 6, lane = t & 63;
  const int quad = lane >> 4, c = lane & 15;
  __shared__ int pos[64];
  __shared__ __align__(16) u16 As[64][72];
  __shared__ __align__(16) u16 Ws[64][72];
  if (t < 64) pos[t] = posb[bh * 64 + t];
  __syncthreads();
  const int obase = h * 128 + half * 64;
  const int srow = t >> 2, scol = (t & 3) * 16;
  const int arow = pos[srow];
  f32x4 acc[4];
#pragma unroll
  for (int ot = 0; ot < 4; ++ot) acc[ot] = (f32x4){0.f, 0.f, 0.f, 0.f};

  for (int k0 = 0; k0 < 512; k0 += 64) {
    __syncthreads();
    {
      const u16* ga = xT + ((size_t)b * 4096 + arow) * 512 + k0 + scol;
      *reinterpret_cast<uint4*>(&As[srow][scol])     = *reinterpret_cast<const uint4*>(ga);
      *reinterpret_cast<uint4*>(&As[srow][scol + 8]) = *reinterpret_cast<const uint4*>(ga + 8);
      if (f32) {
        const float* gw = (const float*)kv_w + (size_t)(obase + srow) * 512 + k0 + scol;
#pragma unroll
        for (int e = 0; e < 16; ++e) Ws[srow][scol + e] = f2bs(gw[e]);
      } else {
        const u16* gw = (const u16*)kv_w + (size_t)(obase + srow) * 512 + k0 + scol;
        *reinterpret_cast<uint4*>(&Ws[srow][scol])     = *reinterpret_cast<const uint4*>(gw);
        *reinterpret_cast<uint4*>(&Ws[srow][scol + 8]) = *reinterpret_cast<const uint4*>(gw + 8);
      }
    }
    __syncthreads();
#pragma unroll
    for (int ks = 0; ks < 2; ++ks) {
      bf16x8 av = *reinterpret_cast<const bf16x8*>(&As[w * 16 + c][ks * 32 + quad * 8]);
#pragma unroll
      for (int ot = 0; ot < 4; ++ot) {
        bf16x8 wv = *reinterpret_cast<const bf16x8*>(&Ws[ot * 16 + c][ks * 32 + quad * 8]);
        acc[ot] = __builtin_amdgcn_mfma_f32_16x16x32_bf16(av, wv, acc[ot], 0, 0, 0);
      }
    }
  }

#pragma unroll
  for (int ot = 0; ot < 4; ++ot) {
    int d = ot * 16 + c;
    float bv = ldf(kv_b, obase + d, f32);
#pragma unroll
    for (int r = 0; r < 4; ++r) {
      int m = w * 16 + quad * 4 + r;
      u16 val = f2bs(acc[ot][r] + bv);
      if (half) tvTb[((size_t)bh * 64 + d) * 64 + m] = val;
      else      tkb[((size_t)bh * 64 + m) * 64 + d] = val;
    }
  }
}

// depthwise 7x7 conv on vT -> vpe bf16
__global__ __launch_bounds__(256) void dwconv_kernel(
    const u16* __restrict__ vT, const void* __restrict__ pe_w,
    const void* __restrict__ pe_b, u16* __restrict__ vpe,
    const int* __restrict__ dtf) {
  const int f32 = *dtf;
  int bc = blockIdx.x;
  int b = bc >> 9, c = bc & 511;
  int h = c >> 6, d = c & 63;
  int t = threadIdx.x;
  __shared__ float img[1024];
  __shared__ float wts[49];
  const u16* base = vT + ((size_t)(b * 8 + h) * 64 + d) * 1024;
  if (t < 128) {
    uint4 v4 = reinterpret_cast<const uint4*>(base)[t];
    u16 tmp[8];
    *reinterpret_cast<uint4*>(tmp) = v4;
#pragma unroll
    for (int e = 0; e < 8; ++e) img[t * 8 + e] = bs2f(tmp[e]);
  }
  if (t < 49) wts[t] = ldf(pe_w, c * 49 + t, f32);
  float bias = ldf(pe_b, c, f32);
  __syncthreads();
  for (int i = t; i < 1024; i += 256) {
    int y = i >> 5, xx = i & 31;
    float a = 0.f;
#pragma unroll
    for (int ky = 0; ky < 7; ++ky) {
      int yy = y + ky - 3;
      if ((unsigned)yy >= 32u) continue;
#pragma unroll
      for (int kx = 0; kx < 7; ++kx) {
        int xc = xx + kx - 3;
        if ((unsigned)xc >= 32u) continue;
        a += img[yy * 32 + xc] * wts[ky * 7 + kx];
      }
    }
    vpe[(size_t)bc * 1024 + i] = f2bs(a + bias);
  }
}

// ---------------------------------------------------------------------------
// FUSED coarse+fine attention. Block = 128 n (grid 32 x 16bh), 4 waves.
// Phase A: coarse (round-8 double-buffered loop, verbatim math) -> po/sume regs.
// Barrier, LDS repartition, stage vpe rows {bx-1,bx,bx+1} + gate bias.
// Phase B per wave x nt: fine QK (tkb) -> exp -> P^T via fus -> PV (tvTb) ->
// fusion [f2bs(coarse)|refined] -> gate MFMA (gwb global) -> combine+bilinear
// -> store xsT. Same-wave LDS write->read without barrier (validated r3-r10).
// ---------------------------------------------------------------------------
__global__ __launch_bounds__(256) void attn_fused(
    const u16* __restrict__ q, const u16* __restrict__ k,
    const u16* __restrict__ vT, const u16* __restrict__ tkb,
    const u16* __restrict__ tvTb, const u16* __restrict__ gwb,
    const float* __restrict__ gbf, const u16* __restrict__ vpe,
    u16* __restrict__ xsT) {
  const int bh = blockIdx.y, b = bh >> 3, h = bh & 7;
  const int bx = blockIdx.x;
  const int n0 = bx * 128;
  const int t = threadIdx.x, w = t >> 6, lane = t & 63;
  const int quad = lane >> 4, c = lane & 15;

  __shared__ __align__(16) u16 lds[27648];   // 55.3 KB union
  u16* Ks = lds;              // [2][64][72]
  u16* Vt = lds + 9216;       // [2][64][72]
  u16* Ps = lds + 18432;      // [4*2][16][72]

  // ---- phase A: coarse ----
  bf16x8 bq[2][2];
#pragma unroll
  for (int nt = 0; nt < 2; ++nt) {
    const u16* qr = q + ((size_t)bh * 4096 + n0 + w * 32 + nt * 16 + c) * 64;
    bq[nt][0] = *reinterpret_cast<const bf16x8*>(qr + quad * 8);
    bq[nt][1] = *reinterpret_cast<const bf16x8*>(qr + 32 + quad * 8);
  }
  f32x4 po[2][4];
#pragma unroll
  for (int nt = 0; nt < 2; ++nt)
#pragma unroll
    for (int dt = 0; dt < 4; ++dt) po[nt][dt] = (f32x4){0.f, 0.f, 0.f, 0.f};
  float sume[2] = {0.f, 0.f};

  const u16* kbase = k + (size_t)bh * 65536;
  const u16* vbase = vT + (size_t)bh * 65536;
  const int srow = t >> 2, scol = (t & 3) * 16;

  uint4 kr0, kr1, vr0, vr1;
  {
    const u16* gk = kbase + (size_t)srow * 64 + scol;
    kr0 = *reinterpret_cast<const uint4*>(gk);
    kr1 = *reinterpret_cast<const uint4*>(gk + 8);
    const u16* gv = vbase + (size_t)srow * 1024 + scol;
    vr0 = *reinterpret_cast<const uint4*>(gv);
    vr1 = *reinterpret_cast<const uint4*>(gv + 8);
    *reinterpret_cast<uint4*>(&Ks[srow * 72 + scol])     = kr0;
    *reinterpret_cast<uint4*>(&Ks[srow * 72 + scol + 8]) = kr1;
    *reinterpret_cast<uint4*>(&Vt[srow * 72 + scol])     = vr0;
    *reinterpret_cast<uint4*>(&Vt[srow * 72 + scol + 8]) = vr1;
  }

  for (int ch = 0; ch < 16; ++ch) {
    __syncthreads();
    const int buf = ch & 1;
    if (ch + 1 < 16) {
      int m1 = (ch + 1) * 64;
      const u16* gk = kbase + (size_t)(m1 + srow) * 64 + scol;
      kr0 = *reinterpret_cast<const uint4*>(gk);
      kr1 = *reinterpret_cast<const uint4*>(gk + 8);
      const u16* gv = vbase + (size_t)srow * 1024 + m1 + scol;
      vr0 = *reinterpret_cast<const uint4*>(gv);
      vr1 = *reinterpret_cast<const uint4*>(gv + 8);
    }

    f32x4 st[2][4];
#pragma unroll
    for (int mt = 0; mt < 4; ++mt) {
      const u16* krow = &Ks[(buf * 64 + mt * 16 + c) * 72];
      bf16x8 ak0 = *reinterpret_cast<const bf16x8*>(krow + quad * 8);
      bf16x8 ak1 = *reinterpret_cast<const bf16x8*>(krow + 32 + quad * 8);
#pragma unroll
      for (int nt = 0; nt < 2; ++nt) {
        f32x4 acc = (f32x4){0.f, 0.f, 0.f, 0.f};
        acc = __builtin_amdgcn_mfma_f32_16x16x32_bf16(ak0, bq[nt][0], acc, 0, 0, 0);
        acc = __builtin_amdgcn_mfma_f32_16x16x32_bf16(ak1, bq[nt][1], acc, 0, 0, 0);
        st[nt][mt] = acc;
      }
    }
#pragma unroll
    for (int nt = 0; nt < 2; ++nt) {
      float cs = 0.f;
      u16* psw = &Ps[((w * 2 + nt) * 16 + c) * 72];
#pragma unroll
      for (int mt = 0; mt < 4; ++mt) {
        float e0 = __expf(st[nt][mt][0] * 0.125f);
        float e1 = __expf(st[nt][mt][1] * 0.125f);
        float e2 = __expf(st[nt][mt][2] * 0.125f);
        float e3 = __expf(st[nt][mt][3] * 0.125f);
        cs += (e0 + e1) + (e2 + e3);
        ushort4 pw;
        pw.x = f2bs(e0); pw.y = f2bs(e1); pw.z = f2bs(e2); pw.w = f2bs(e3);
        *reinterpret_cast<ushort4*>(psw + mt * 16 + quad * 4) = pw;
      }
      cs += __shfl_xor(cs, 16, 64);
      cs += __shfl_xor(cs, 32, 64);
      sume[nt] += cs;
    }
#pragma unroll
    for (int s = 0; s < 2; ++s) {
      bf16x8 bp0 = *reinterpret_cast<const bf16x8*>(&Ps[((w * 2 + 0) * 16 + c) * 72 + s * 32 + quad * 8]);
      bf16x8 bp1 = *reinterpret_cast<const bf16x8*>(&Ps[((w * 2 + 1) * 16 + c) * 72 + s * 32 + quad * 8]);
#pragma unroll
      for (int dt = 0; dt < 4; ++dt) {
        bf16x8 av = *reinterpret_cast<const bf16x8*>(&Vt[(buf * 64 + dt * 16 + c) * 72 + s * 32 + quad * 8]);
        po[0][dt] = __builtin_amdgcn_mfma_f32_16x16x32_bf16(av, bp0, po[0][dt], 0, 0, 0);
        po[1][dt] = __builtin_amdgcn_mfma_f32_16x16x32_bf16(av, bp1, po[1][dt], 0, 0, 0);
      }
    }

    if (ch + 1 < 16) {
      const int nb = buf ^ 1;
      *reinterpret_cast<uint4*>(&Ks[(nb * 64 + srow) * 72 + scol])     = kr0;
      *reinterpret_cast<uint4*>(&Ks[(nb * 64 + srow) * 72 + scol + 8]) = kr1;
      *reinterpret_cast<uint4*>(&Vt[(nb * 64 + srow) * 72 + scol])     = vr0;
      *reinterpret_cast<uint4*>(&Vt[(nb * 64 + srow) * 72 + scol + 8]) = vr1;
    }
  }

  __syncthreads();  // coarse LDS dead everywhere; repartition
  u16* fus = lds;                      // [4*2][16][136]
  u16* vl  = lds + 17408;              // [3][64][40]
  float* gbl = (float*)(lds + 25088);  // [64]

  for (int idx = t; idx < 768; idx += 256) {
    int seg = idx & 3, ch2 = (idx >> 2) & 63, r = idx >> 8;
    int vrow = bx - 1 + r;
    vrow = vrow < 0 ? 0 : (vrow > 31 ? 31 : vrow);
    const uint4* src = reinterpret_cast<const uint4*>(
        vpe + ((size_t)(b * 512 + h * 64 + ch2)) * 1024 + vrow * 32);
    *reinterpret_cast<uint4*>(&vl[(r * 64 + ch2) * 40 + seg * 8]) = src[seg];
  }
  if (t < 64) gbl[t] = gbf[t];
  __syncthreads();

  // ---- phase B: fine, per wave, nt = 0,1 ----
  for (int nt = 0; nt < 2; ++nt) {
    u16* fusw = &fus[((w * 2 + nt) * 16 + c) * 136];
    f32x4 st[4];
#pragma unroll
    for (int mt = 0; mt < 4; ++mt) {
      f32x4 acc = (f32x4){0.f, 0.f, 0.f, 0.f};
#pragma unroll
      for (int s = 0; s < 2; ++s) {
        bf16x8 ak = *reinterpret_cast<const bf16x8*>(
            &tkb[((size_t)bh * 64 + mt * 16 + c) * 64 + s * 32 + quad * 8]);
        acc = __builtin_amdgcn_mfma_f32_16x16x32_bf16(ak, bq[nt][s], acc, 0, 0, 0);
      }
      st[mt] = acc;
    }
    float sume2 = 0.f;
#pragma unroll
    for (int mt = 0; mt < 4; ++mt) {
      float e0 = __expf(st[mt][0] * 0.125f);
      float e1 = __expf(st[mt][1] * 0.125f);
      float e2 = __expf(st[mt][2] * 0.125f);
      float e3 = __expf(st[mt][3] * 0.125f);
      sume2 += (e0 + e1) + (e2 + e3);
      ushort4 pw;
      pw.x = f2bs(e0); pw.y = f2bs(e1); pw.z = f2bs(e2); pw.w = f2bs(e3);
      *reinterpret_cast<ushort4*>(fusw + mt * 16 + quad * 4) = pw;
    }
    sume2 += __shfl_xor(sume2, 16, 64);
    sume2 += __shfl_xor(sume2, 32, 64);
    float inv2 = 1.0f / sume2;

    f32x4 po2[4];
#pragma unroll
    for (int dt = 0; dt < 4; ++dt) po2[dt] = (f32x4){0.f, 0.f, 0.f, 0.f};
#pragma unroll
    for (int s = 0; s < 2; ++s) {
      bf16x8 bp = *reinterpret_cast<const bf16x8*>(fusw + s * 32 + quad * 8);
#pragma unroll
      for (int dt = 0; dt < 4; ++dt) {
        bf16x8 av = *reinterpret_cast<const bf16x8*>(
            &tvTb[((size_t)bh * 64 + dt * 16 + c) * 64 + s * 32 + quad * 8]);
        po2[dt] = __builtin_amdgcn_mfma_f32_16x16x32_bf16(av, bp, po2[dt], 0, 0, 0);
      }
    }

    // fusion [coarse | refined]
    float invc = 1.0f / sume[nt];
#pragma unroll
    for (int dt = 0; dt < 4; ++dt) {
      ushort4 cw, rw;
      cw.x = f2bs(po[nt][dt][0] * invc); cw.y = f2bs(po[nt][dt][1] * invc);
      cw.z = f2bs(po[nt][dt][2] * invc); cw.w = f2bs(po[nt][dt][3] * invc);
      rw.x = f2bs(po2[dt][0] * inv2);    rw.y = f2bs(po2[dt][1] * inv2);
      rw.z = f2bs(po2[dt][2] * inv2);    rw.w = f2bs(po2[dt][3] * inv2);
      *reinterpret_cast<ushort4*>(fusw + dt * 16 + quad * 4)      = cw;
      *reinterpret_cast<ushort4*>(fusw + 64 + dt * 16 + quad * 4) = rw;
    }

    // gate MFMA (K=128), A-frags from global gwb
    f32x4 ga[4];
#pragma unroll
    for (int ot = 0; ot < 4; ++ot) ga[ot] = (f32x4){0.f, 0.f, 0.f, 0.f};
#pragma unroll
    for (int s = 0; s < 4; ++s) {
      bf16x8 bf = *reinterpret_cast<const bf16x8*>(fusw + s * 32 + quad * 8);
#pragma unroll
      for (int ot = 0; ot < 4; ++ot) {
        bf16x8 ag = *reinterpret_cast<const bf16x8*>(
            gwb + (ot * 16 + c) * 128 + s * 32 + quad * 8);
        ga[ot] = __builtin_amdgcn_mfma_f32_16x16x32_bf16(ag, bf, ga[ot], 0, 0, 0);
      }
    }

    // combine + bilinear; overwrite fus rows 0..63 (same-lane read->write)
    const int ylocal = (w * 32 + nt * 16) >> 6;
    const int x = (w * 32 + nt * 16 + c) & 63;
    float wy0, wy1; int i0, i1;
    if (ylocal == 0) { wy0 = 0.25f; wy1 = 0.75f; i0 = (bx > 0) ? 0 : 1; i1 = 1; }
    else             { wy0 = 0.75f; wy1 = 0.25f; i0 = 1; i1 = (bx < 31) ? 2 : 1; }
    int jx = x >> 1, x0, x1; float wx0, wx1;
    if ((x & 1) == 0) { x0 = (jx > 0) ? jx - 1 : 0; x1 = jx; wx0 = 0.25f; wx1 = 0.75f; }
    else              { x0 = jx; x1 = (jx < 31) ? jx + 1 : 31; wx0 = 0.75f; wx1 = 0.25f; }
#pragma unroll
    for (int dt = 0; dt < 4; ++dt) {
      ushort4 ow;
      u16 tmp[4];
#pragma unroll
      for (int r = 0; r < 4; ++r) {
        int row = dt * 16 + quad * 4 + r;
        float ref = po2[dt][r] * inv2;
        float coar = bs2f(fusw[row]);
        float g = 1.0f / (1.0f + __expf(-(ga[dt][r] + gbl[row])));
        float vv = wy0 * (wx0 * bs2f(vl[(i0 * 64 + row) * 40 + x0]) +
                          wx1 * bs2f(vl[(i0 * 64 + row) * 40 + x1])) +
                   wy1 * (wx0 * bs2f(vl[(i1 * 64 + row) * 40 + x0]) +
                          wx1 * bs2f(vl[(i1 * 64 + row) * 40 + x1]));
        tmp[r] = f2bs(g * ref + (1.0f - g) * coar + vv);
      }
      ow.x = tmp[0]; ow.y = tmp[1]; ow.z = tmp[2]; ow.w = tmp[3];
      *reinterpret_cast<ushort4*>(fusw + dt * 16 + quad * 4) = ow;
    }

    // store n-major rows (same-wave cross-lane reads, in-order DS)
    {
      int nl = lane >> 2, cs = (lane & 3) * 16;
      const u16* srcrow = &fus[((w * 2 + nt) * 16 + nl) * 136 + cs];
      u16* dst = xsT + ((size_t)b * 4096 + n0 + w * 32 + nt * 16 + nl) * 512 + h * 64 + cs;
      *reinterpret_cast<uint4*>(dst)     = *reinterpret_cast<const uint4*>(srcrow);
      *reinterpret_cast<uint4*>(dst + 8) = *reinterpret_cast<const uint4*>(srcrow + 8);
    }
  }
}

extern "C" void kernel_launch(void* const* d_in, const int* in_sizes, int n_in,
                              void* d_out, int out_size, void* d_ws, size_t ws_size,
                              hipStream_t stream) {
  const void* x    = d_in[0];
  const void* up   = d_in[1];
  const void* gum  = d_in[2];
  const void* q_w  = d_in[3];
  const void* q_b  = d_in[4];
  const void* kv_w = d_in[5];
  const void* kv_b = d_in[6];
  const void* p_w  = d_in[7];
  const void* p_b  = d_in[8];
  const void* pe_w = d_in[9];
  const void* pe_b = d_in[10];
  const void* g_w  = d_in[11];
  const void* g_b  = d_in[12];

  float* ws    = (float*)d_ws;
  int*   dtf   = (int*)ws;                   // 16 f
  float* qsum  = ws + 16;                    // 1024 f
  float* heat  = qsum + 1024;                // 2048 f
  int*   posb  = (int*)(heat + 2048);        // 1024 ints
  float* gbf   = (float*)(posb + 1024);      // 64
  u16*   gwb   = (u16*)(gbf + 64);           // 8192 u16
  u16*   tkb   = gwb + 8192;                 // 65536
  u16*   tvTb  = tkb + 65536;                // 65536
  u16*   qb    = tvTb + 65536;               // 4M
  u16*   kb    = qb + 4194304;               // 1M
  u16*   vTb   = kb + 1048576;               // 1M
  u16*   xT    = vTb + 1048576;              // 4M
  u16*   upT   = xT + 4194304;               // 1M
  u16*   xsT   = upT + 1048576;              // 4M
  u16*   vpe   = xsT + 4194304;              // 1M   (~26 MB total)

  dim3 blk(256);
  hipMemsetAsync(ws, 0, (16 + 1024 + 2048) * 4, stream);
  detect_dtype<<<dim3(64), blk, 0, stream>>>((const uint4*)x, dtf);
  prep_gate<<<dim3(1), blk, 0, stream>>>(g_w, g_b, gwb, gbf, dtf);
  transpose_bf16<<<dim3(64, 8, 2), blk, 0, stream>>>(x, xT, 4096, heat, dtf);
  transpose_bf16<<<dim3(16, 8, 2), blk, 0, stream>>>(up, upT, 1024, nullptr, dtf);
  gemm128<0><<<dim3(32, 8, 2), blk, 0, stream>>>(xT, q_w, q_b, qb, nullptr, qsum, 4096, dtf);
  gemm_kv<<<dim3(16, 16, 2), blk, 0, stream>>>(upT, kv_w, kv_b, kb, vTb, 1024, dtf);
  topk_kernel<<<dim3(16), blk, 0, stream>>>(qsum, kb, heat, gum, posb, dtf);
  gather_kv_mfma<<<dim3(16, 2), blk, 0, stream>>>(xT, kv_w, kv_b, posb, tkb, tvTb, dtf);
  dwconv_kernel<<<dim3(1024), blk, 0, stream>>>(vTb, pe_w, pe_b, vpe, dtf);
  attn_fused<<<dim3(32, 16), blk, 0, stream>>>(qb, kb, vTb, tkb, tvTb, gwb, gbf, vpe, xsT);
  gemm128<3><<<dim3(32, 8, 2), blk, 0, stream>>>(xsT, p_w, p_b, nullptr, d_out, nullptr, 4096, dtf);
}